// Round 4
// baseline (3328.455 us; speedup 1.0000x reference)
//
#include <hip/hip_runtime.h>
#include <math.h>

// ---------------- problem constants ----------------
#define PH   4
#define CHN  8
#define ZT   8
#define ZE   6          // effective z slices: z in [1,7)
#define HG   320
#define WG   320
#define HW2  102400     // 320*320
#define NKP  4096
#define LSTR 321        // LDS line stride (pad +1)
#define NTH  320        // FFT block size (5 waves)

constexpr float GAMMA_C = 0.1f;
constexpr float TAU_C   = 0.2f;
constexpr float EPS_C   = 0.01f;
constexpr float INV_N   = 1.0f / 786432.0f;   // PH*CHN*ZE*NKP
#define TWO_PI_F 6.28318530717958647692f

// compile-time twiddle tables for the small DFTs (exact, better than sincosf)
constexpr float W16R[16] = { 1.f,  0.92387953f,  0.70710678f,  0.38268343f,  0.f, -0.38268343f, -0.70710678f, -0.92387953f,
                            -1.f, -0.92387953f, -0.70710678f, -0.38268343f,  0.f,  0.38268343f,  0.70710678f,  0.92387953f};
constexpr float W16I[16] = { 0.f, -0.38268343f, -0.70710678f, -0.92387953f, -1.f, -0.92387953f, -0.70710678f, -0.38268343f,
                             0.f,  0.38268343f,  0.70710678f,  0.92387953f,  1.f,  0.92387953f,  0.70710678f,  0.38268343f};
constexpr float W20R[20] = { 1.f,  0.95105652f,  0.80901699f,  0.58778525f,  0.30901699f,  0.f,
                            -0.30901699f, -0.58778525f, -0.80901699f, -0.95105652f, -1.f, -0.95105652f,
                            -0.80901699f, -0.58778525f, -0.30901699f,  0.f,  0.30901699f,  0.58778525f,
                             0.80901699f,  0.95105652f};
constexpr float W20I[20] = { 0.f, -0.30901699f, -0.58778525f, -0.80901699f, -0.95105652f, -1.f,
                            -0.95105652f, -0.80901699f, -0.58778525f, -0.30901699f,  0.f,  0.30901699f,
                             0.58778525f,  0.80901699f,  0.95105652f,  1.f,  0.95105652f,  0.80901699f,
                             0.58778525f,  0.30901699f};

// ---------------- complex helpers ----------------
__device__ __forceinline__ float2 cmul(float2 a, float2 b){
  return make_float2(a.x*b.x - a.y*b.y, a.x*b.y + a.y*b.x);
}
__device__ __forceinline__ void cmac(float2& d, float2 a, float2 b){
  d.x = fmaf(a.x, b.x, fmaf(-a.y, b.y, d.x));
  d.y = fmaf(a.x, b.y, fmaf( a.y, b.x, d.y));
}

__device__ __forceinline__ void corners(float gy, float gx, int& y0, int& x0, int& y1, int& x1,
                                        float& w00, float& w01, float& w10, float& w11){
  float y0f = floorf(gy), x0f = floorf(gx);
  float wy = gy - y0f, wx = gx - x0f;
  y0 = (int)y0f; x0 = (int)x0f;
  y1 = min(y0 + 1, HG - 1); x1 = min(x0 + 1, WG - 1);
  w00 = (1.f - wy) * (1.f - wx);
  w01 = (1.f - wy) * wx;
  w10 = wy * (1.f - wx);
  w11 = wy * wx;
}

// ---------------- twiddles: inter-stage table in global, copied to LDS per block ----
__global__ void k_twid(float2* __restrict__ w320g){
  int i = threadIdx.x;
  if (i < 320){
    float s, c;
    sincosf(-TWO_PI_F * (float)i / 320.0f, &s, &c);
    w320g[i] = make_float2(c, s);
  }
}
__device__ __forceinline__ void load_w320(float2* w320, const float2* __restrict__ w320g, int tid){
  if (tid < 320) w320[tid] = w320g[tid];
}

// ---------------- 320-pt FFT: 16 lines per block, 4-step N1=20 x N2=16 ----------------
// Forward DFT twiddles (e^{-2pi i}); backward/transpose uses the SAME direction
// (formal transpose of the symmetric DFT matrix) per JAX's bilinear VJP convention.
// Block = 320 threads: step 1 is exactly one (line,n1) task per thread.
__device__ void fft320_lines(float2* __restrict__ ld, const float2* __restrict__ w320, int tid){
  // step 1: task (line, n1): 16-pt DFT over n2 strided 20, then inter-stage twiddle W320^{n1*k2}.
  // In-place safe per task (read set == write set, loaded to regs first).
  if (tid < 320){
    int line = tid / 20;
    int n1   = tid - line * 20;
    float2* L = ld + line * LSTR;
    float2 a[16];
    #pragma unroll
    for (int n2 = 0; n2 < 16; n2++) a[n2] = L[n1 + 20 * n2];
    #pragma unroll
    for (int k2 = 0; k2 < 16; k2++){
      float2 acc = make_float2(0.f, 0.f);
      #pragma unroll
      for (int n2 = 0; n2 < 16; n2++){
        const int j = (n2 * k2) & 15;                       // compile-time
        cmac(acc, a[n2], make_float2(W16R[j], W16I[j]));    // constants in regs, no LDS
      }
      acc = cmul(acc, w320[n1 * k2]);        // inter-stage twiddle (runtime idx -> LDS)
      L[n1 + 20 * k2] = acc;
    }
  }
  __syncthreads();
  // step 2: task (line, k2): 20-pt DFT over n1. 256 tasks; threads >=256 idle but hit barriers.
  {
    bool act = tid < 256;
    int line = tid >> 4;
    int k2   = tid & 15;
    float2 b[20];
    if (act){
      float2* L = ld + line * LSTR;
      #pragma unroll
      for (int n1 = 0; n1 < 20; n1++) b[n1] = L[n1 + 20 * k2];
    }
    __syncthreads();
    if (act){
      float2* L = ld + line * LSTR;
      #pragma unroll
      for (int k1 = 0; k1 < 20; k1++){
        float2 acc = make_float2(0.f, 0.f);
        #pragma unroll
        for (int n1 = 0; n1 < 20; n1++){
          const int j = (n1 * k1) % 20;                     // compile-time
          cmac(acc, b[n1], make_float2(W20R[j], W20I[j]));
        }
        L[k2 + 16 * k1] = acc;
      }
    }
  }
  __syncthreads();
}

// ---------------- kernels ----------------
__global__ __launch_bounds__(256) void k_init(const float2* __restrict__ img0, float2* __restrict__ x, int n){
  int i = blockIdx.x * 256 + threadIdx.x;
  if (i < n){
    float2 v = img0[i];
    v.x = isnan(v.x) ? 0.f : fminf(fmaxf(v.x, -3.4028235e38f), 3.4028235e38f);
    v.y = isnan(v.y) ? 0.f : fminf(fmaxf(v.y, -3.4028235e38f), 3.4028235e38f);
    x[i] = v;
  }
}

__global__ __launch_bounds__(256) void k_warp(const float2* __restrict__ x, const float* __restrict__ mvf,
                                              float2* __restrict__ warped){
  int gid = blockIdx.x * 256 + threadIdx.x;          // over PH*ZE*HW2
  int hw = gid % HW2;
  int pz = gid / HW2;
  int zz = pz % ZE, p = pz / ZE, z = zz + 1;
  int h = hw / WG, w = hw - h * WG;
  const float* mv = mvf + ((size_t)(p * 2 + 0) * ZT + z) * HW2;
  float fy = mv[hw];
  float fx = mv[(size_t)ZT * HW2 + hw];
  float gy = fminf(fmaxf((float)h + fy, 0.f), 319.f);
  float gx = fminf(fmaxf((float)w + fx, 0.f), 319.f);
  int y0, x0, y1, x1; float w00, w01, w10, w11;
  corners(gy, gx, y0, x0, y1, x1, w00, w01, w10, w11);
  const float2* xs = x + (size_t)(p * ZT + z) * HW2;
  float2 v00 = xs[y0 * WG + x0], v01 = xs[y0 * WG + x1];
  float2 v10 = xs[y1 * WG + x0], v11 = xs[y1 * WG + x1];
  float2 o;
  o.x = v00.x * w00 + v01.x * w01 + v10.x * w10 + v11.x * w11;
  o.y = v00.y * w00 + v01.y * w01 + v10.y * w10 + v11.y * w11;
  warped[gid] = o;
}

// row FFT forward, fused: in = warped*csm*(-1)^(h+w)
__global__ __launch_bounds__(NTH) void k_fft_row_fwd(const float2* __restrict__ warped, const float2* __restrict__ csm,
                                                     float2* __restrict__ F, const float2* __restrict__ w320g, int p){
  __shared__ float2 ld[16 * LSTR];
  __shared__ float2 w320[320];
  int tid = threadIdx.x;
  load_w320(w320, w320g, tid);
  int bid = blockIdx.x;                     // c*120 + zz*20 + rg
  int rg = bid % 20; int t = bid / 20; int zz = t % ZE; int c = t / ZE; int z = zz + 1;
  const float2* wr = warped + ((size_t)(p * ZE + zz)) * HW2 + (size_t)rg * 16 * WG;
  const float2* cs = csm + ((size_t)(c * ZT + z)) * HW2 + (size_t)rg * 16 * WG;
  for (int i = tid; i < 16 * WG; i += NTH){
    int line = i / WG; int w = i - line * WG;
    float2 v = cmul(wr[i], cs[i]);
    int h = rg * 16 + line;
    float sgn = ((h + w) & 1) ? -1.f : 1.f;
    ld[line * LSTR + w] = make_float2(v.x * sgn, v.y * sgn);
  }
  __syncthreads();
  fft320_lines(ld, w320, tid);
  float2* out = F + ((size_t)(c * ZE + zz)) * HW2 + (size_t)rg * 16 * WG;
  for (int i = tid; i < 16 * WG; i += NTH){
    int line = i / WG; int w = i - line * WG;
    out[i] = ld[line * LSTR + w];
  }
}

// column FFT, in place (forward pass)
__global__ __launch_bounds__(NTH) void k_fft_col(float2* __restrict__ F, const float2* __restrict__ w320g){
  __shared__ float2 ld[16 * LSTR];
  __shared__ float2 w320[320];
  int tid = threadIdx.x;
  load_w320(w320, w320g, tid);
  int bid = blockIdx.x;                     // slice*20 + cg, slice = c*ZE+zz
  int cg = bid % 20; int s = bid / 20;
  float2* Fs = F + (size_t)s * HW2 + cg * 16;
  for (int i = tid; i < 5120; i += NTH){
    int h = i >> 4; int col = i & 15;
    ld[col * LSTR + h] = Fs[h * WG + col];
  }
  __syncthreads();
  fft320_lines(ld, w320, tid);
  for (int i = tid; i < 5120; i += NTH){
    int h = i >> 4; int col = i & 15;
    Fs[h * WG + col] = ld[col * LSTR + h];
  }
}

__global__ __launch_bounds__(256) void k_sample(const float2* __restrict__ F, const float* __restrict__ traj,
                                                float2* __restrict__ est, unsigned int* __restrict__ dmax, int p){
  int gid = blockIdx.x * 256 + threadIdx.x;     // over CHN*ZE*NKP
  int k = gid & (NKP - 1);
  int t = gid >> 12;
  int zz = t % ZE; int c = t / ZE;
  float ty = traj[(p * 2 + 0) * NKP + k];
  float tx = traj[(p * 2 + 1) * NKP + k];
  float gy = fminf(fmaxf((ty / TWO_PI_F + 0.5f) * 320.f, 0.f), 319.f);
  float gx = fminf(fmaxf((tx / TWO_PI_F + 0.5f) * 320.f, 0.f), 319.f);
  int y0, x0, y1, x1; float w00, w01, w10, w11;
  corners(gy, gx, y0, x0, y1, x1, w00, w01, w10, w11);
  const float2* Fs = F + (size_t)(c * ZE + zz) * HW2;
  float2 v00 = Fs[y0 * WG + x0], v01 = Fs[y0 * WG + x1];
  float2 v10 = Fs[y1 * WG + x0], v11 = Fs[y1 * WG + x1];
  float2 e;
  e.x = v00.x * w00 + v01.x * w01 + v10.x * w10 + v11.x * w11;
  e.y = v00.y * w00 + v01.y * w01 + v10.y * w10 + v11.y * w11;
  est[((size_t)(p * CHN + c) * ZE + zz) * NKP + k] = e;
  float d2 = e.x * e.x + e.y * e.y;
  for (int off = 32; off > 0; off >>= 1) d2 = fmaxf(d2, __shfl_down(d2, off, 64));
  if ((threadIdx.x & 63) == 0) atomicMax(dmax, __float_as_uint(d2));   // d2 >= 0: uint order ok
}

// est -> cotangent: G = (w^2/N) * conj(est - y)   (conj = JAX bilinear-VJP convention)
__global__ __launch_bounds__(256) void k_weights(float2* __restrict__ est, const float2* __restrict__ kdata,
                                                 const unsigned int* __restrict__ dmax){
  int gid = blockIdx.x * 256 + threadIdx.x;     // over PH*CHN*ZE*NKP
  int k = gid & (NKP - 1);
  int t = gid >> 12;                            // (p*CHN+c)*ZE + zz
  int zz = t % ZE; int pc = t / ZE; int z = zz + 1;
  float md = sqrtf(__uint_as_float(*dmax));
  float2 e = est[gid];
  float det = sqrtf(e.x * e.x + e.y * e.y);
  float wv = 1.0f / (det / md + EPS_C);
  float sc = wv * wv * INV_N;
  float2 y = kdata[((size_t)pc * ZT + z) * NKP + k];
  est[gid] = make_float2(sc * (e.x - y.x), -sc * (e.y - y.y));
}

// backward: fused { zero-grid + k-space corner scatter (LDS atomics) + column DFT^T } per 16-col group
__global__ __launch_bounds__(NTH) void k_fft_col_scatter(const float2* __restrict__ G, const float* __restrict__ traj,
                                                         float2* __restrict__ F, const float2* __restrict__ w320g, int p){
  __shared__ float2 ld[16 * LSTR];
  __shared__ float2 w320[320];
  int tid = threadIdx.x;
  load_w320(w320, w320g, tid);
  int bid = blockIdx.x;                     // s*20 + cg, s = c*ZE+zz
  int cg = bid % 20; int s = bid / 20; int zz = s % ZE; int c = s / ZE;
  for (int i = tid; i < 16 * LSTR; i += NTH) ld[i] = make_float2(0.f, 0.f);
  __syncthreads();
  int cbase = cg * 16;
  const float* tyb = traj + (p * 2 + 0) * NKP;
  const float* txb = traj + (p * 2 + 1) * NKP;
  const float2* Gs = G + ((size_t)(p * CHN + c) * ZE + zz) * NKP;
  for (int k = tid; k < NKP; k += NTH){
    float gy = fminf(fmaxf((tyb[k] / TWO_PI_F + 0.5f) * 320.f, 0.f), 319.f);
    float gx = fminf(fmaxf((txb[k] / TWO_PI_F + 0.5f) * 320.f, 0.f), 319.f);
    int y0, x0, y1, x1; float w00, w01, w10, w11;
    corners(gy, gx, y0, x0, y1, x1, w00, w01, w10, w11);
    float2 gv = Gs[k];
    int c0 = x0 - cbase, c1 = x1 - cbase;
    if ((unsigned)c0 < 16u){
      atomicAdd(&ld[c0 * LSTR + y0].x, gv.x * w00); atomicAdd(&ld[c0 * LSTR + y0].y, gv.y * w00);
      atomicAdd(&ld[c0 * LSTR + y1].x, gv.x * w10); atomicAdd(&ld[c0 * LSTR + y1].y, gv.y * w10);
    }
    if ((unsigned)c1 < 16u){
      atomicAdd(&ld[c1 * LSTR + y0].x, gv.x * w01); atomicAdd(&ld[c1 * LSTR + y0].y, gv.y * w01);
      atomicAdd(&ld[c1 * LSTR + y1].x, gv.x * w11); atomicAdd(&ld[c1 * LSTR + y1].y, gv.y * w11);
    }
  }
  __syncthreads();
  fft320_lines(ld, w320, tid);
  float2* Fs = F + (size_t)s * HW2 + cbase;
  for (int i = tid; i < 5120; i += NTH){
    int h = i >> 4; int col = i & 15;
    Fs[h * WG + col] = ld[col * LSTR + h];
  }
}

// transpose row pass, fused epilogue: *(-1)^(h+w), *csm (NO conj: formal transpose), sum over coils
__global__ __launch_bounds__(NTH) void k_fft_row_bwd(const float2* __restrict__ F, const float2* __restrict__ csm,
                                                     float2* __restrict__ gwarped, const float2* __restrict__ w320g, int p){
  __shared__ float2 ld[16 * LSTR];
  __shared__ float2 w320[320];
  int tid = threadIdx.x;
  load_w320(w320, w320g, tid);
  int bid = blockIdx.x;                    // zz*160 + rp
  int rp = bid % 160; int zz = bid / 160; int z = zz + 1;
  for (int i = tid; i < 16 * WG; i += NTH){
    int line = i / WG; int w = i - line * WG;
    int c = line & 7; int hh = line >> 3;
    ld[line * LSTR + w] = F[((size_t)(c * ZE + zz)) * HW2 + (size_t)(rp * 2 + hh) * WG + w];
  }
  __syncthreads();
  fft320_lines(ld, w320, tid);
  for (int i = tid; i < 2 * WG; i += NTH){
    int hh = i / WG; int w = i - hh * WG;
    int h = rp * 2 + hh;
    float2 acc = make_float2(0.f, 0.f);
    #pragma unroll
    for (int c = 0; c < 8; c++){
      float2 u  = ld[(hh * 8 + c) * LSTR + w];
      float2 cv = csm[((size_t)(c * ZT + z)) * HW2 + (size_t)h * WG + w];
      cmac(acc, u, cv);
    }
    float sgn = ((h + w) & 1) ? -1.f : 1.f;
    gwarped[((size_t)(p * ZE + zz)) * HW2 + (size_t)h * WG + w] = make_float2(acc.x * sgn, acc.y * sgn);
  }
}

// LDS-tiled warp adjoint (unchanged from round 3)
#define TR 16
#define HA 8
#define LROWS (TR + 2*HA)   // 32 rows; LDS = 32*320*2*4B = 81920 B
__global__ __launch_bounds__(512) void k_warpadj(const float2* __restrict__ gw, const float* __restrict__ mvf,
                                                 float* __restrict__ gdc){
  __shared__ float lt[LROWS * WG * 2];
  int tid = threadIdx.x;
  int bid = blockIdx.x;                    // pz*20 + tile
  int tile = bid % 20; int pz = bid / 20;
  int zz = pz % ZE, p = pz / ZE, z = zz + 1;
  int r0 = tile * TR;
  for (int i = tid; i < LROWS * WG * 2; i += 512) lt[i] = 0.f;
  __syncthreads();
  const float* mvy = mvf + ((size_t)(p * 2 + 0) * ZT + z) * HW2;
  const float* mvx = mvy + (size_t)ZT * HW2;
  const float2* g = gw + (size_t)pz * HW2;
  float* gs = gdc + (size_t)pz * HW2 * 2;
  const int lo = r0 - HA;
  for (int i = tid; i < TR * WG; i += 512){
    int hh = i / WG;
    int h = r0 + hh; int w = i - hh * WG;
    int hw = h * WG + w;
    float fy = mvy[hw];
    float fx = mvx[hw];
    float gy = fminf(fmaxf((float)h + fy, 0.f), 319.f);
    float gx = fminf(fmaxf((float)w + fx, 0.f), 319.f);
    int y0, x0, y1, x1; float w00, w01, w10, w11;
    corners(gy, gx, y0, x0, y1, x1, w00, w01, w10, w11);
    float2 gv = g[hw];
    int ry0 = y0 - lo, ry1 = y1 - lo;
    if ((unsigned)ry0 < (unsigned)LROWS){
      atomicAdd(&lt[(ry0 * WG + x0) * 2 + 0], gv.x * w00); atomicAdd(&lt[(ry0 * WG + x0) * 2 + 1], gv.y * w00);
      atomicAdd(&lt[(ry0 * WG + x1) * 2 + 0], gv.x * w01); atomicAdd(&lt[(ry0 * WG + x1) * 2 + 1], gv.y * w01);
    } else {
      atomicAdd(&gs[(y0 * WG + x0) * 2 + 0], gv.x * w00); atomicAdd(&gs[(y0 * WG + x0) * 2 + 1], gv.y * w00);
      atomicAdd(&gs[(y0 * WG + x1) * 2 + 0], gv.x * w01); atomicAdd(&gs[(y0 * WG + x1) * 2 + 1], gv.y * w01);
    }
    if ((unsigned)ry1 < (unsigned)LROWS){
      atomicAdd(&lt[(ry1 * WG + x0) * 2 + 0], gv.x * w10); atomicAdd(&lt[(ry1 * WG + x0) * 2 + 1], gv.y * w10);
      atomicAdd(&lt[(ry1 * WG + x1) * 2 + 0], gv.x * w11); atomicAdd(&lt[(ry1 * WG + x1) * 2 + 1], gv.y * w11);
    } else {
      atomicAdd(&gs[(y1 * WG + x0) * 2 + 0], gv.x * w10); atomicAdd(&gs[(y1 * WG + x0) * 2 + 1], gv.y * w10);
      atomicAdd(&gs[(y1 * WG + x1) * 2 + 0], gv.x * w11); atomicAdd(&gs[(y1 * WG + x1) * 2 + 1], gv.y * w11);
    }
  }
  __syncthreads();
  for (int i = tid; i < LROWS * WG; i += 512){
    int rr = i / WG; int w = i - rr * WG;
    int h = lo + rr;
    if ((unsigned)h < (unsigned)HG){
      float vx = lt[i * 2 + 0], vy = lt[i * 2 + 1];
      if (vx != 0.f) atomicAdd(&gs[(h * WG + w) * 2 + 0], vx);
      if (vy != 0.f) atomicAdd(&gs[(h * WG + w) * 2 + 1], vy);
    }
  }
}

// TV gradient (natural real-pair grad), stored CONJUGATED to match jax.grad convention
__global__ __launch_bounds__(256) void k_tv(const float2* __restrict__ x, float2* __restrict__ gtv){
  int gid = blockIdx.x * 256 + threadIdx.x;     // PH*ZE*HW2
  int hw = gid % HW2;
  int pz = gid / HW2;
  int zz = pz % ZE, p = pz / ZE, z = zz + 1;
  int h = hw / WG, w = hw - h * WG;
  const float2* xs = x + (size_t)(p * ZT + z) * HW2;
  float2 xc = xs[hw];
  float tre = 0.f, tim = 0.f;
  if (h > 0){
    float2 n = xs[hw - WG];
    float dr = xc.x - n.x, di = xc.y - n.y;
    float r = sqrtf(dr * dr + di * di + 1e-8f);
    tre += dr / r; tim += di / r;
  }
  if (h < HG - 1){
    float2 n = xs[hw + WG];
    float dr = n.x - xc.x, di = n.y - xc.y;
    float r = sqrtf(dr * dr + di * di + 1e-8f);
    tre -= dr / r; tim -= di / r;
  }
  if (w > 0){
    float2 n = xs[hw - 1];
    float dr = xc.x - n.x, di = xc.y - n.y;
    float r = sqrtf(dr * dr + di * di + 1e-8f);
    tre += dr / r; tim += di / r;
  }
  if (w < WG - 1){
    float2 n = xs[hw + 1];
    float dr = n.x - xc.x, di = n.y - xc.y;
    float r = sqrtf(dr * dr + di * di + 1e-8f);
    tre -= dr / r; tim -= di / r;
  }
  gtv[gid] = make_float2(tre, -tim);
}

__global__ __launch_bounds__(256) void k_update(float2* __restrict__ x, const float2* __restrict__ gdc,
                                                const float2* __restrict__ gtv, const float* __restrict__ stdp){
  int gid = blockIdx.x * 256 + threadIdx.x;     // PH*ZE*HW2
  int hw = gid % HW2;
  int pz = gid / HW2;
  int zz = pz % ZE, p = pz / ZE;
  float s = stdp[0];
  size_t xi = (size_t)(p * ZT + zz + 1) * HW2 + hw;
  float2 xv = x[xi];
  float2 gd = gdc[gid], gt = gtv[gid];
  xv.x -= GAMMA_C * gd.x + TAU_C * s * gt.x;
  xv.y -= GAMMA_C * gd.y + TAU_C * s * gt.y;
  x[xi] = xv;
}

// ---------------- host ----------------
extern "C" void kernel_launch(void* const* d_in, const int* in_sizes, int n_in,
                              void* d_out, int out_size, void* d_ws, size_t ws_size,
                              hipStream_t stream) {
  const float2* kdata = (const float2*)d_in[0];   // (PH,CHN,ZT,NK) complex
  const float*  traj  = (const float*) d_in[1];   // (PH,2,NK)
  const float2* img0  = (const float2*)d_in[2];   // (PH,ZT,H,W) complex
  const float*  mvf   = (const float*) d_in[3];   // (PH,2,ZT,H,W)
  const float2* csm   = (const float2*)d_in[4];   // (CHN,ZT,H,W) complex
  const float*  stdp  = (const float*) d_in[5];   // (1,)
  float2* x = (float2*)d_out;                     // x lives in d_out (same layout as output)

  // workspace layout (bytes): total ~85 MB
  char* ws = (char*)d_ws;
  const size_t F_B  = (size_t)CHN * ZE * HW2 * 8;        // 39,321,600
  const size_t W_B  = (size_t)PH * ZE * HW2 * 8;         // 19,660,800
  const size_t E_B  = (size_t)PH * CHN * ZE * NKP * 8;   //  6,291,456
  float2* F      = (float2*)(ws);
  float2* warped = (float2*)(ws + F_B);                  // also reused for gwarped, then gtv
  float2* gdc    = (float2*)(ws + F_B + W_B);
  float2* est    = (float2*)(ws + F_B + 2 * W_B);
  unsigned int* dmax = (unsigned int*)(ws + F_B + 2 * W_B + E_B);
  float2* w320g  = (float2*)(ws + F_B + 2 * W_B + E_B + 256);

  k_init<<<12800, 256, 0, stream>>>(img0, x, PH * ZT * HW2);
  k_twid<<<1, 320, 0, stream>>>(w320g);

  for (int it = 0; it < 3; it++){
    k_warp<<<9600, 256, 0, stream>>>(x, mvf, warped);
    hipMemsetAsync(dmax, 0, 4, stream);
    for (int p = 0; p < PH; p++){
      k_fft_row_fwd<<<960, NTH, 0, stream>>>(warped, csm, F, w320g, p);
      k_fft_col    <<<960, NTH, 0, stream>>>(F, w320g);
      k_sample     <<<768, 256, 0, stream>>>(F, traj, est, dmax, p);
    }
    k_weights<<<3072, 256, 0, stream>>>(est, kdata, dmax);
    for (int p = 0; p < PH; p++){
      k_fft_col_scatter<<<960, NTH, 0, stream>>>(est, traj, F, w320g, p);
      k_fft_row_bwd    <<<960, NTH, 0, stream>>>(F, csm, warped, w320g, p);   // warped <- gwarped
    }
    hipMemsetAsync(gdc, 0, W_B, stream);
    k_warpadj<<<480, 512, 0, stream>>>(warped, mvf, (float*)gdc);
    k_tv     <<<9600, 256, 0, stream>>>(x, warped);                    // warped <- gtv
    k_update <<<9600, 256, 0, stream>>>(x, gdc, warped, stdp);
  }
}

// Round 5
// 2548.591 us; speedup vs baseline: 1.3060x; 1.3060x over previous
//
#include <hip/hip_runtime.h>
#include <math.h>

// ---------------- problem constants ----------------
#define PH   4
#define CHN  8
#define ZT   8
#define ZE   6          // effective z slices: z in [1,7)
#define HG   320
#define WG   320
#define HW2  102400     // 320*320
#define NKP  4096
#define LSTR 321        // LDS line stride (pad +1)

constexpr float GAMMA_C = 0.1f;
constexpr float TAU_C   = 0.2f;
constexpr float EPS_C   = 0.01f;
constexpr float INV_N   = 1.0f / 786432.0f;   // PH*CHN*ZE*NKP
#define TWO_PI_F 6.28318530717958647692f

// W5^j = e^{-2*pi*i*j/5}
constexpr float W5R[5] = { 1.f,  0.30901699f, -0.80901699f, -0.80901699f,  0.30901699f};
constexpr float W5I[5] = { 0.f, -0.95105652f, -0.58778525f,  0.58778525f,  0.95105652f};

// ---------------- complex helpers ----------------
__device__ __forceinline__ float2 cmul(float2 a, float2 b){
  return make_float2(a.x*b.x - a.y*b.y, a.x*b.y + a.y*b.x);
}
__device__ __forceinline__ void cmac(float2& d, float2 a, float2 b){
  d.x = fmaf(a.x, b.x, fmaf(-a.y, b.y, d.x));
  d.y = fmaf(a.x, b.y, fmaf( a.y, b.x, d.y));
}

__device__ __forceinline__ void corners(float gy, float gx, int& y0, int& x0, int& y1, int& x1,
                                        float& w00, float& w01, float& w10, float& w11){
  float y0f = floorf(gy), x0f = floorf(gx);
  float wy = gy - y0f, wx = gx - x0f;
  y0 = (int)y0f; x0 = (int)x0f;
  y1 = min(y0 + 1, HG - 1); x1 = min(x0 + 1, WG - 1);
  w00 = (1.f - wy) * (1.f - wx);
  w01 = (1.f - wy) * wx;
  w10 = wy * (1.f - wx);
  w11 = wy * wx;
}

// ---------------- in-register 320-pt FFT: one wave per line, N = 5 x 64 ----------------
// x[n], n = 64q + l (lane l). y_l[r] = sum_q x[64q+l] W5^{qr}; z_l[r] = W320^{lr} y_l[r];
// X[5m+r] = DFT64_lanes(z[r])[m]. DIF butterflies leave lane l holding m = bitrev6(l),
// so lane l stores X[5*br6(l)+r] -> un-permuted via a small LDS segment (F stays natural).
// Same direction everywhere (DFT matrix symmetric => transpose == forward), as rounds 1-4.
struct FT {
  float2 t1, t2, t3, t4;         // W320^{l*r}, r=1..4
  float2 tw0, tw1, tw2, tw3, tw4; // butterfly stage twiddles
  int br5, lane;
};

__device__ __forceinline__ FT ft_init(){
  FT f; int l = (int)(threadIdx.x & 63); f.lane = l;
  sincosf(-TWO_PI_F * (float)l * (1.0f/320.0f), &f.t1.y, &f.t1.x);
  f.t2 = cmul(f.t1, f.t1); f.t3 = cmul(f.t2, f.t1); f.t4 = cmul(f.t2, f.t2);
  sincosf(-TWO_PI_F * (float)(l & 31) * (1.0f/64.0f), &f.tw0.y, &f.tw0.x);
  sincosf(-TWO_PI_F * (float)(l & 15) * (1.0f/32.0f), &f.tw1.y, &f.tw1.x);
  sincosf(-TWO_PI_F * (float)(l &  7) * (1.0f/16.0f), &f.tw2.y, &f.tw2.x);
  sincosf(-TWO_PI_F * (float)(l &  3) * (1.0f/ 8.0f), &f.tw3.y, &f.tw3.x);
  f.tw4 = (l & 1) ? make_float2(0.f, -1.f) : make_float2(1.f, 0.f);
  int br = ((l&1)<<5) | ((l&2)<<3) | ((l&4)<<1) | ((l&8)>>1) | ((l&16)>>3) | ((l&32)>>5);
  f.br5 = 5 * br;
  return f;
}

template<int H>
__device__ __forceinline__ void bfly(float2& v, float2 tw, int lane){
  float px = __shfl_xor(v.x, H, 64);
  float py = __shfl_xor(v.y, H, 64);
  bool up = (lane & H) != 0;
  float ax = up ? px : v.x, ay = up ? py : v.y;
  float bx = up ? v.x : px, by = up ? v.y : py;
  float dx = ax - bx,  dy = ay - by;
  float mx = fmaf(dx, tw.x, -dy * tw.y);
  float my = fmaf(dx, tw.y,  dy * tw.x);
  v.x = up ? mx : (ax + bx);
  v.y = up ? my : (ay + by);
}

// a[5] in registers -> seg[0..319] natural-order spectrum (seg is wave-private or column-private)
__device__ __forceinline__ void fft320w(const float2 a[5], const FT& f, float2* __restrict__ seg){
  float2 z[5];
  #pragma unroll
  for (int r = 0; r < 5; r++){
    float2 acc = a[0];
    #pragma unroll
    for (int q = 1; q < 5; q++){
      const int j = (q * r) % 5;
      cmac(acc, a[q], make_float2(W5R[j], W5I[j]));
    }
    z[r] = acc;
  }
  z[1] = cmul(z[1], f.t1); z[2] = cmul(z[2], f.t2);
  z[3] = cmul(z[3], f.t3); z[4] = cmul(z[4], f.t4);
  #pragma unroll
  for (int r = 0; r < 5; r++){
    float2 v = z[r];
    bfly<32>(v, f.tw0, f.lane);
    bfly<16>(v, f.tw1, f.lane);
    bfly< 8>(v, f.tw2, f.lane);
    bfly< 4>(v, f.tw3, f.lane);
    bfly< 2>(v, f.tw4, f.lane);
    {
      float px = __shfl_xor(v.x, 1, 64);
      float py = __shfl_xor(v.y, 1, 64);
      bool up = (f.lane & 1) != 0;
      float ax = up ? px : v.x, ay = up ? py : v.y;
      float bx = up ? v.x : px, by = up ? v.y : py;
      v.x = up ? (ax - bx) : (ax + bx);
      v.y = up ? (ay - by) : (ay + by);
    }
    seg[f.br5 + r] = v;
  }
}

// ---------------- kernels ----------------
__global__ __launch_bounds__(256) void k_init(const float2* __restrict__ img0, float2* __restrict__ x, int n){
  int i = blockIdx.x * 256 + threadIdx.x;
  if (i < n){
    float2 v = img0[i];
    v.x = isnan(v.x) ? 0.f : fminf(fmaxf(v.x, -3.4028235e38f), 3.4028235e38f);
    v.y = isnan(v.y) ? 0.f : fminf(fmaxf(v.y, -3.4028235e38f), 3.4028235e38f);
    x[i] = v;
  }
}

__global__ __launch_bounds__(256) void k_warp(const float2* __restrict__ x, const float* __restrict__ mvf,
                                              float2* __restrict__ warped){
  int gid = blockIdx.x * 256 + threadIdx.x;          // over PH*ZE*HW2
  int hw = gid % HW2;
  int pz = gid / HW2;
  int zz = pz % ZE, p = pz / ZE, z = zz + 1;
  int h = hw / WG, w = hw - h * WG;
  const float* mv = mvf + ((size_t)(p * 2 + 0) * ZT + z) * HW2;
  float fy = mv[hw];
  float fx = mv[(size_t)ZT * HW2 + hw];
  float gy = fminf(fmaxf((float)h + fy, 0.f), 319.f);
  float gx = fminf(fmaxf((float)w + fx, 0.f), 319.f);
  int y0, x0, y1, x1; float w00, w01, w10, w11;
  corners(gy, gx, y0, x0, y1, x1, w00, w01, w10, w11);
  const float2* xs = x + (size_t)(p * ZT + z) * HW2;
  float2 v00 = xs[y0 * WG + x0], v01 = xs[y0 * WG + x1];
  float2 v10 = xs[y1 * WG + x0], v11 = xs[y1 * WG + x1];
  float2 o;
  o.x = v00.x * w00 + v01.x * w01 + v10.x * w10 + v11.x * w11;
  o.y = v00.y * w00 + v01.y * w01 + v10.y * w10 + v11.y * w11;
  warped[gid] = o;
}

// row FFT forward: one wave per (c,zz,h) line; in = warped*csm*(-1)^(h+w) loaded straight to regs
__global__ __launch_bounds__(256) void k_fft_row_fwd(const float2* __restrict__ warped, const float2* __restrict__ csm,
                                                     float2* __restrict__ F, int p){
  __shared__ float2 seg[4 * LSTR];
  FT f = ft_init();
  int wid = threadIdx.x >> 6, l = f.lane;
  int lineid = blockIdx.x * 4 + wid;                 // < CHN*ZE*HG = 15360
  int c = lineid / (ZE * HG); int rem = lineid - c * (ZE * HG);
  int zz = rem / HG; int h = rem - zz * HG; int z = zz + 1;
  const float2* wr = warped + ((size_t)(p * ZE + zz)) * HW2 + (size_t)h * WG;
  const float2* cs = csm + ((size_t)(c * ZT + z)) * HW2 + (size_t)h * WG;
  float sgn = ((h + l) & 1) ? -1.f : 1.f;            // (-1)^(h + 64q + l), 64q even
  float2 a[5];
  #pragma unroll
  for (int q = 0; q < 5; q++){
    float2 v = cmul(wr[64 * q + l], cs[64 * q + l]);
    a[q] = make_float2(v.x * sgn, v.y * sgn);
  }
  float2* sg = seg + wid * LSTR;
  fft320w(a, f, sg);
  __syncthreads();
  float2* out = F + ((size_t)(c * ZE + zz)) * HW2 + (size_t)h * WG;
  #pragma unroll
  for (int q = 0; q < 5; q++) out[64 * q + l] = sg[64 * q + l];
}

// column FFT, in place: stage 16 cols to LDS, per-wave in-register FFT per column
__global__ __launch_bounds__(256) void k_fft_col(float2* __restrict__ F){
  __shared__ float2 ld[16 * LSTR];
  FT f = ft_init();
  int tid = threadIdx.x; int wid = tid >> 6, l = f.lane;
  int cg = blockIdx.x % 20; int s = blockIdx.x / 20;
  float2* Fs = F + (size_t)s * HW2 + cg * 16;
  for (int i = tid; i < 5120; i += 256){ int h = i >> 4, col = i & 15; ld[col * LSTR + h] = Fs[h * WG + col]; }
  __syncthreads();
  #pragma unroll
  for (int cc = 0; cc < 4; cc++){
    float2* base = ld + (wid * 4 + cc) * LSTR;
    float2 a[5];
    #pragma unroll
    for (int q = 0; q < 5; q++) a[q] = base[64 * q + l];
    fft320w(a, f, base);
  }
  __syncthreads();
  for (int i = tid; i < 5120; i += 256){ int h = i >> 4, col = i & 15; Fs[h * WG + col] = ld[col * LSTR + h]; }
}

__global__ __launch_bounds__(256) void k_sample(const float2* __restrict__ F, const float* __restrict__ traj,
                                                float2* __restrict__ est, unsigned int* __restrict__ dmax, int p){
  int gid = blockIdx.x * 256 + threadIdx.x;     // over CHN*ZE*NKP
  int k = gid & (NKP - 1);
  int t = gid >> 12;
  int zz = t % ZE; int c = t / ZE;
  float ty = traj[(p * 2 + 0) * NKP + k];
  float tx = traj[(p * 2 + 1) * NKP + k];
  float gy = fminf(fmaxf((ty / TWO_PI_F + 0.5f) * 320.f, 0.f), 319.f);
  float gx = fminf(fmaxf((tx / TWO_PI_F + 0.5f) * 320.f, 0.f), 319.f);
  int y0, x0, y1, x1; float w00, w01, w10, w11;
  corners(gy, gx, y0, x0, y1, x1, w00, w01, w10, w11);
  const float2* Fs = F + (size_t)(c * ZE + zz) * HW2;
  float2 v00 = Fs[y0 * WG + x0], v01 = Fs[y0 * WG + x1];
  float2 v10 = Fs[y1 * WG + x0], v11 = Fs[y1 * WG + x1];
  float2 e;
  e.x = v00.x * w00 + v01.x * w01 + v10.x * w10 + v11.x * w11;
  e.y = v00.y * w00 + v01.y * w01 + v10.y * w10 + v11.y * w11;
  est[((size_t)(p * CHN + c) * ZE + zz) * NKP + k] = e;
  float d2 = e.x * e.x + e.y * e.y;
  for (int off = 32; off > 0; off >>= 1) d2 = fmaxf(d2, __shfl_down(d2, off, 64));
  if ((threadIdx.x & 63) == 0) atomicMax(dmax, __float_as_uint(d2));   // d2 >= 0: uint order ok
}

// est -> cotangent: G = (w^2/N) * conj(est - y)   (conj = JAX bilinear-VJP convention)
__global__ __launch_bounds__(256) void k_weights(float2* __restrict__ est, const float2* __restrict__ kdata,
                                                 const unsigned int* __restrict__ dmax){
  int gid = blockIdx.x * 256 + threadIdx.x;     // over PH*CHN*ZE*NKP
  int k = gid & (NKP - 1);
  int t = gid >> 12;                            // (p*CHN+c)*ZE + zz
  int zz = t % ZE; int pc = t / ZE; int z = zz + 1;
  float md = sqrtf(__uint_as_float(*dmax));
  float2 e = est[gid];
  float det = sqrtf(e.x * e.x + e.y * e.y);
  float wv = 1.0f / (det / md + EPS_C);
  float sc = wv * wv * INV_N;
  float2 y = kdata[((size_t)pc * ZT + z) * NKP + k];
  est[gid] = make_float2(sc * (e.x - y.x), -sc * (e.y - y.y));
}

// backward: fused { zero tile + k-space corner scatter (LDS atomics) + per-wave column DFT^T }
__global__ __launch_bounds__(256) void k_fft_col_scatter(const float2* __restrict__ G, const float* __restrict__ traj,
                                                         float2* __restrict__ F, int p){
  __shared__ float2 ld[16 * LSTR];
  FT f = ft_init();
  int tid = threadIdx.x; int wid = tid >> 6, l = f.lane;
  int cg = blockIdx.x % 20; int s = blockIdx.x / 20; int zz = s % ZE; int c = s / ZE;
  for (int i = tid; i < 16 * LSTR; i += 256) ld[i] = make_float2(0.f, 0.f);
  __syncthreads();
  int cbase = cg * 16;
  const float* tyb = traj + (p * 2 + 0) * NKP;
  const float* txb = traj + (p * 2 + 1) * NKP;
  const float2* Gs = G + ((size_t)(p * CHN + c) * ZE + zz) * NKP;
  for (int k = tid; k < NKP; k += 256){
    float gy = fminf(fmaxf((tyb[k] / TWO_PI_F + 0.5f) * 320.f, 0.f), 319.f);
    float gx = fminf(fmaxf((txb[k] / TWO_PI_F + 0.5f) * 320.f, 0.f), 319.f);
    int y0, x0, y1, x1; float w00, w01, w10, w11;
    corners(gy, gx, y0, x0, y1, x1, w00, w01, w10, w11);
    float2 gv = Gs[k];
    int c0 = x0 - cbase, c1 = x1 - cbase;
    if ((unsigned)c0 < 16u){
      atomicAdd(&ld[c0 * LSTR + y0].x, gv.x * w00); atomicAdd(&ld[c0 * LSTR + y0].y, gv.y * w00);
      atomicAdd(&ld[c0 * LSTR + y1].x, gv.x * w10); atomicAdd(&ld[c0 * LSTR + y1].y, gv.y * w10);
    }
    if ((unsigned)c1 < 16u){
      atomicAdd(&ld[c1 * LSTR + y0].x, gv.x * w01); atomicAdd(&ld[c1 * LSTR + y0].y, gv.y * w01);
      atomicAdd(&ld[c1 * LSTR + y1].x, gv.x * w11); atomicAdd(&ld[c1 * LSTR + y1].y, gv.y * w11);
    }
  }
  __syncthreads();
  #pragma unroll
  for (int cc = 0; cc < 4; cc++){
    float2* base = ld + (wid * 4 + cc) * LSTR;
    float2 a[5];
    #pragma unroll
    for (int q = 0; q < 5; q++) a[q] = base[64 * q + l];
    fft320w(a, f, base);
  }
  __syncthreads();
  float2* Fs = F + (size_t)s * HW2 + cbase;
  for (int i = tid; i < 5120; i += 256){ int h = i >> 4, col = i & 15; Fs[h * WG + col] = ld[col * LSTR + h]; }
}

// transpose row pass: 8 waves = 8 coils of one (zz,h) row; epilogue *(-1)^(h+w), *csm, coil sum
__global__ __launch_bounds__(512) void k_fft_row_bwd(const float2* __restrict__ F, const float2* __restrict__ csm,
                                                     float2* __restrict__ gwarped, int p){
  __shared__ float2 seg[8 * LSTR];
  FT f = ft_init();
  int tid = threadIdx.x; int c = tid >> 6, l = f.lane;
  int zz = blockIdx.x / HG; int h = blockIdx.x - zz * HG; int z = zz + 1;
  const float2* Fl = F + ((size_t)(c * ZE + zz)) * HW2 + (size_t)h * WG;
  float2 a[5];
  #pragma unroll
  for (int q = 0; q < 5; q++) a[q] = Fl[64 * q + l];
  fft320w(a, f, seg + c * LSTR);
  __syncthreads();
  if (tid < WG){
    int w = tid;
    float2 acc = make_float2(0.f, 0.f);
    #pragma unroll
    for (int cc = 0; cc < 8; cc++){
      cmac(acc, seg[cc * LSTR + w], csm[((size_t)(cc * ZT + z)) * HW2 + (size_t)h * WG + w]);
    }
    float sg = ((h + w) & 1) ? -1.f : 1.f;
    gwarped[((size_t)(p * ZE + zz)) * HW2 + (size_t)h * WG + w] = make_float2(acc.x * sg, acc.y * sg);
  }
}

// LDS-tiled warp adjoint (unchanged from round 3/4)
#define TR 16
#define HA 8
#define LROWS (TR + 2*HA)   // 32 rows; LDS = 32*320*2*4B = 81920 B
__global__ __launch_bounds__(512) void k_warpadj(const float2* __restrict__ gw, const float* __restrict__ mvf,
                                                 float* __restrict__ gdc){
  __shared__ float lt[LROWS * WG * 2];
  int tid = threadIdx.x;
  int bid = blockIdx.x;                    // pz*20 + tile
  int tile = bid % 20; int pz = bid / 20;
  int zz = pz % ZE, p = pz / ZE, z = zz + 1;
  int r0 = tile * TR;
  for (int i = tid; i < LROWS * WG * 2; i += 512) lt[i] = 0.f;
  __syncthreads();
  const float* mvy = mvf + ((size_t)(p * 2 + 0) * ZT + z) * HW2;
  const float* mvx = mvy + (size_t)ZT * HW2;
  const float2* g = gw + (size_t)pz * HW2;
  float* gs = gdc + (size_t)pz * HW2 * 2;
  const int lo = r0 - HA;
  for (int i = tid; i < TR * WG; i += 512){
    int hh = i / WG;
    int h = r0 + hh; int w = i - hh * WG;
    int hw = h * WG + w;
    float fy = mvy[hw];
    float fx = mvx[hw];
    float gy = fminf(fmaxf((float)h + fy, 0.f), 319.f);
    float gx = fminf(fmaxf((float)w + fx, 0.f), 319.f);
    int y0, x0, y1, x1; float w00, w01, w10, w11;
    corners(gy, gx, y0, x0, y1, x1, w00, w01, w10, w11);
    float2 gv = g[hw];
    int ry0 = y0 - lo, ry1 = y1 - lo;
    if ((unsigned)ry0 < (unsigned)LROWS){
      atomicAdd(&lt[(ry0 * WG + x0) * 2 + 0], gv.x * w00); atomicAdd(&lt[(ry0 * WG + x0) * 2 + 1], gv.y * w00);
      atomicAdd(&lt[(ry0 * WG + x1) * 2 + 0], gv.x * w01); atomicAdd(&lt[(ry0 * WG + x1) * 2 + 1], gv.y * w01);
    } else {
      atomicAdd(&gs[(y0 * WG + x0) * 2 + 0], gv.x * w00); atomicAdd(&gs[(y0 * WG + x0) * 2 + 1], gv.y * w00);
      atomicAdd(&gs[(y0 * WG + x1) * 2 + 0], gv.x * w01); atomicAdd(&gs[(y0 * WG + x1) * 2 + 1], gv.y * w01);
    }
    if ((unsigned)ry1 < (unsigned)LROWS){
      atomicAdd(&lt[(ry1 * WG + x0) * 2 + 0], gv.x * w10); atomicAdd(&lt[(ry1 * WG + x0) * 2 + 1], gv.y * w10);
      atomicAdd(&lt[(ry1 * WG + x1) * 2 + 0], gv.x * w11); atomicAdd(&lt[(ry1 * WG + x1) * 2 + 1], gv.y * w11);
    } else {
      atomicAdd(&gs[(y1 * WG + x0) * 2 + 0], gv.x * w10); atomicAdd(&gs[(y1 * WG + x0) * 2 + 1], gv.y * w10);
      atomicAdd(&gs[(y1 * WG + x1) * 2 + 0], gv.x * w11); atomicAdd(&gs[(y1 * WG + x1) * 2 + 1], gv.y * w11);
    }
  }
  __syncthreads();
  for (int i = tid; i < LROWS * WG; i += 512){
    int rr = i / WG; int w = i - rr * WG;
    int h = lo + rr;
    if ((unsigned)h < (unsigned)HG){
      float vx = lt[i * 2 + 0], vy = lt[i * 2 + 1];
      if (vx != 0.f) atomicAdd(&gs[(h * WG + w) * 2 + 0], vx);
      if (vy != 0.f) atomicAdd(&gs[(h * WG + w) * 2 + 1], vy);
    }
  }
}

// TV gradient (natural real-pair grad), stored CONJUGATED to match jax.grad convention
__global__ __launch_bounds__(256) void k_tv(const float2* __restrict__ x, float2* __restrict__ gtv){
  int gid = blockIdx.x * 256 + threadIdx.x;     // PH*ZE*HW2
  int hw = gid % HW2;
  int pz = gid / HW2;
  int zz = pz % ZE, p = pz / ZE, z = zz + 1;
  int h = hw / WG, w = hw - h * WG;
  const float2* xs = x + (size_t)(p * ZT + z) * HW2;
  float2 xc = xs[hw];
  float tre = 0.f, tim = 0.f;
  if (h > 0){
    float2 n = xs[hw - WG];
    float dr = xc.x - n.x, di = xc.y - n.y;
    float r = sqrtf(dr * dr + di * di + 1e-8f);
    tre += dr / r; tim += di / r;
  }
  if (h < HG - 1){
    float2 n = xs[hw + WG];
    float dr = n.x - xc.x, di = n.y - xc.y;
    float r = sqrtf(dr * dr + di * di + 1e-8f);
    tre -= dr / r; tim -= di / r;
  }
  if (w > 0){
    float2 n = xs[hw - 1];
    float dr = xc.x - n.x, di = xc.y - n.y;
    float r = sqrtf(dr * dr + di * di + 1e-8f);
    tre += dr / r; tim += di / r;
  }
  if (w < WG - 1){
    float2 n = xs[hw + 1];
    float dr = n.x - xc.x, di = n.y - xc.y;
    float r = sqrtf(dr * dr + di * di + 1e-8f);
    tre -= dr / r; tim -= di / r;
  }
  gtv[gid] = make_float2(tre, -tim);
}

__global__ __launch_bounds__(256) void k_update(float2* __restrict__ x, const float2* __restrict__ gdc,
                                                const float2* __restrict__ gtv, const float* __restrict__ stdp){
  int gid = blockIdx.x * 256 + threadIdx.x;     // PH*ZE*HW2
  int hw = gid % HW2;
  int pz = gid / HW2;
  int zz = pz % ZE, p = pz / ZE;
  float s = stdp[0];
  size_t xi = (size_t)(p * ZT + zz + 1) * HW2 + hw;
  float2 xv = x[xi];
  float2 gd = gdc[gid], gt = gtv[gid];
  xv.x -= GAMMA_C * gd.x + TAU_C * s * gt.x;
  xv.y -= GAMMA_C * gd.y + TAU_C * s * gt.y;
  x[xi] = xv;
}

// ---------------- host ----------------
extern "C" void kernel_launch(void* const* d_in, const int* in_sizes, int n_in,
                              void* d_out, int out_size, void* d_ws, size_t ws_size,
                              hipStream_t stream) {
  const float2* kdata = (const float2*)d_in[0];   // (PH,CHN,ZT,NK) complex
  const float*  traj  = (const float*) d_in[1];   // (PH,2,NK)
  const float2* img0  = (const float2*)d_in[2];   // (PH,ZT,H,W) complex
  const float*  mvf   = (const float*) d_in[3];   // (PH,2,ZT,H,W)
  const float2* csm   = (const float2*)d_in[4];   // (CHN,ZT,H,W) complex
  const float*  stdp  = (const float*) d_in[5];   // (1,)
  float2* x = (float2*)d_out;                     // x lives in d_out (same layout as output)

  // workspace layout (bytes): total ~85 MB
  char* ws = (char*)d_ws;
  const size_t F_B  = (size_t)CHN * ZE * HW2 * 8;        // 39,321,600
  const size_t W_B  = (size_t)PH * ZE * HW2 * 8;         // 19,660,800
  const size_t E_B  = (size_t)PH * CHN * ZE * NKP * 8;   //  6,291,456
  float2* F      = (float2*)(ws);
  float2* warped = (float2*)(ws + F_B);                  // also reused for gwarped, then gtv
  float2* gdc    = (float2*)(ws + F_B + W_B);
  float2* est    = (float2*)(ws + F_B + 2 * W_B);
  unsigned int* dmax = (unsigned int*)(ws + F_B + 2 * W_B + E_B);

  k_init<<<12800, 256, 0, stream>>>(img0, x, PH * ZT * HW2);

  for (int it = 0; it < 3; it++){
    k_warp<<<9600, 256, 0, stream>>>(x, mvf, warped);
    hipMemsetAsync(dmax, 0, 4, stream);
    for (int p = 0; p < PH; p++){
      k_fft_row_fwd<<<3840, 256, 0, stream>>>(warped, csm, F, p);
      k_fft_col    <<< 960, 256, 0, stream>>>(F);
      k_sample     <<< 768, 256, 0, stream>>>(F, traj, est, dmax, p);
    }
    k_weights<<<3072, 256, 0, stream>>>(est, kdata, dmax);
    for (int p = 0; p < PH; p++){
      k_fft_col_scatter<<< 960, 256, 0, stream>>>(est, traj, F, p);
      k_fft_row_bwd    <<<1920, 512, 0, stream>>>(F, csm, warped, p);   // warped <- gwarped
    }
    hipMemsetAsync(gdc, 0, W_B, stream);
    k_warpadj<<<480, 512, 0, stream>>>(warped, mvf, (float*)gdc);
    k_tv     <<<9600, 256, 0, stream>>>(x, warped);                    // warped <- gtv
    k_update <<<9600, 256, 0, stream>>>(x, gdc, warped, stdp);
  }
}

// Round 6
// 2472.733 us; speedup vs baseline: 1.3461x; 1.0307x over previous
//
#include <hip/hip_runtime.h>
#include <math.h>

// ---------------- problem constants ----------------
#define PH   4
#define CHN  8
#define ZT   8
#define ZE   6          // effective z slices: z in [1,7)
#define HG   320
#define WG   320
#define HW2  102400     // 320*320
#define NKP  4096
#define LSTR 321        // LDS line stride (pad +1)
#define FBCAP 131072u   // fallback list capacity (entries)

constexpr float GAMMA_C = 0.1f;
constexpr float TAU_C   = 0.2f;
constexpr float EPS_C   = 0.01f;
constexpr float INV_N   = 1.0f / 786432.0f;   // PH*CHN*ZE*NKP
#define TWO_PI_F 6.28318530717958647692f

// W5^j = e^{-2*pi*i*j/5}
constexpr float W5R[5] = { 1.f,  0.30901699f, -0.80901699f, -0.80901699f,  0.30901699f};
constexpr float W5I[5] = { 0.f, -0.95105652f, -0.58778525f,  0.58778525f,  0.95105652f};

// ---------------- complex helpers ----------------
__device__ __forceinline__ float2 cmul(float2 a, float2 b){
  return make_float2(a.x*b.x - a.y*b.y, a.x*b.y + a.y*b.x);
}
__device__ __forceinline__ void cmac(float2& d, float2 a, float2 b){
  d.x = fmaf(a.x, b.x, fmaf(-a.y, b.y, d.x));
  d.y = fmaf(a.x, b.y, fmaf( a.y, b.x, d.y));
}

__device__ __forceinline__ void corners(float gy, float gx, int& y0, int& x0, int& y1, int& x1,
                                        float& w00, float& w01, float& w10, float& w11){
  float y0f = floorf(gy), x0f = floorf(gx);
  float wy = gy - y0f, wx = gx - x0f;
  y0 = (int)y0f; x0 = (int)x0f;
  y1 = min(y0 + 1, HG - 1); x1 = min(x0 + 1, WG - 1);
  w00 = (1.f - wy) * (1.f - wx);
  w01 = (1.f - wy) * wx;
  w10 = wy * (1.f - wx);
  w11 = wy * wx;
}

// ---------------- in-register 320-pt FFT: one wave per line, N = 5 x 64 ----------------
// x[n], n = 64q + l (lane l). y_l[r] = sum_q x[64q+l] W5^{qr}; z_l[r] = W320^{lr} y_l[r];
// X[5m+r] = DFT64_lanes(z[r])[m]. DIF butterflies leave lane l holding m = bitrev6(l),
// so lane l stores X[5*br6(l)+r] -> un-permuted via a small LDS segment (F stays natural).
// Same direction everywhere (DFT matrix symmetric => transpose == forward), as rounds 1-5.
struct FT {
  float2 t1, t2, t3, t4;         // W320^{l*r}, r=1..4
  float2 tw0, tw1, tw2, tw3, tw4; // butterfly stage twiddles
  int br5, lane;
};

__device__ __forceinline__ FT ft_init(){
  FT f; int l = (int)(threadIdx.x & 63); f.lane = l;
  sincosf(-TWO_PI_F * (float)l * (1.0f/320.0f), &f.t1.y, &f.t1.x);
  f.t2 = cmul(f.t1, f.t1); f.t3 = cmul(f.t2, f.t1); f.t4 = cmul(f.t2, f.t2);
  sincosf(-TWO_PI_F * (float)(l & 31) * (1.0f/64.0f), &f.tw0.y, &f.tw0.x);
  sincosf(-TWO_PI_F * (float)(l & 15) * (1.0f/32.0f), &f.tw1.y, &f.tw1.x);
  sincosf(-TWO_PI_F * (float)(l &  7) * (1.0f/16.0f), &f.tw2.y, &f.tw2.x);
  sincosf(-TWO_PI_F * (float)(l &  3) * (1.0f/ 8.0f), &f.tw3.y, &f.tw3.x);
  f.tw4 = (l & 1) ? make_float2(0.f, -1.f) : make_float2(1.f, 0.f);
  int br = ((l&1)<<5) | ((l&2)<<3) | ((l&4)<<1) | ((l&8)>>1) | ((l&16)>>3) | ((l&32)>>5);
  f.br5 = 5 * br;
  return f;
}

template<int H>
__device__ __forceinline__ void bfly(float2& v, float2 tw, int lane){
  float px = __shfl_xor(v.x, H, 64);
  float py = __shfl_xor(v.y, H, 64);
  bool up = (lane & H) != 0;
  float ax = up ? px : v.x, ay = up ? py : v.y;
  float bx = up ? v.x : px, by = up ? v.y : py;
  float dx = ax - bx,  dy = ay - by;
  float mx = fmaf(dx, tw.x, -dy * tw.y);
  float my = fmaf(dx, tw.y,  dy * tw.x);
  v.x = up ? mx : (ax + bx);
  v.y = up ? my : (ay + by);
}

// a[5] in registers -> seg[0..319] natural-order spectrum
__device__ __forceinline__ void fft320w(const float2 a[5], const FT& f, float2* __restrict__ seg){
  float2 z[5];
  #pragma unroll
  for (int r = 0; r < 5; r++){
    float2 acc = a[0];
    #pragma unroll
    for (int q = 1; q < 5; q++){
      const int j = (q * r) % 5;
      cmac(acc, a[q], make_float2(W5R[j], W5I[j]));
    }
    z[r] = acc;
  }
  z[1] = cmul(z[1], f.t1); z[2] = cmul(z[2], f.t2);
  z[3] = cmul(z[3], f.t3); z[4] = cmul(z[4], f.t4);
  #pragma unroll
  for (int r = 0; r < 5; r++){
    float2 v = z[r];
    bfly<32>(v, f.tw0, f.lane);
    bfly<16>(v, f.tw1, f.lane);
    bfly< 8>(v, f.tw2, f.lane);
    bfly< 4>(v, f.tw3, f.lane);
    bfly< 2>(v, f.tw4, f.lane);
    {
      float px = __shfl_xor(v.x, 1, 64);
      float py = __shfl_xor(v.y, 1, 64);
      bool up = (f.lane & 1) != 0;
      float ax = up ? px : v.x, ay = up ? py : v.y;
      float bx = up ? v.x : px, by = up ? v.y : py;
      v.x = up ? (ax - bx) : (ax + bx);
      v.y = up ? (ay - by) : (ay + by);
    }
    seg[f.br5 + r] = v;
  }
}

// ---------------- kernels ----------------
__global__ __launch_bounds__(256) void k_init(const float2* __restrict__ img0, float2* __restrict__ x, int n){
  int i = blockIdx.x * 256 + threadIdx.x;
  if (i < n){
    float2 v = img0[i];
    v.x = isnan(v.x) ? 0.f : fminf(fmaxf(v.x, -3.4028235e38f), 3.4028235e38f);
    v.y = isnan(v.y) ? 0.f : fminf(fmaxf(v.y, -3.4028235e38f), 3.4028235e38f);
    x[i] = v;
  }
}

__global__ __launch_bounds__(256) void k_warp(const float2* __restrict__ x, const float* __restrict__ mvf,
                                              float2* __restrict__ warped){
  int gid = blockIdx.x * 256 + threadIdx.x;          // over PH*ZE*HW2
  int hw = gid % HW2;
  int pz = gid / HW2;
  int zz = pz % ZE, p = pz / ZE, z = zz + 1;
  int h = hw / WG, w = hw - h * WG;
  const float* mv = mvf + ((size_t)(p * 2 + 0) * ZT + z) * HW2;
  float fy = mv[hw];
  float fx = mv[(size_t)ZT * HW2 + hw];
  float gy = fminf(fmaxf((float)h + fy, 0.f), 319.f);
  float gx = fminf(fmaxf((float)w + fx, 0.f), 319.f);
  int y0, x0, y1, x1; float w00, w01, w10, w11;
  corners(gy, gx, y0, x0, y1, x1, w00, w01, w10, w11);
  const float2* xs = x + (size_t)(p * ZT + z) * HW2;
  float2 v00 = xs[y0 * WG + x0], v01 = xs[y0 * WG + x1];
  float2 v10 = xs[y1 * WG + x0], v11 = xs[y1 * WG + x1];
  float2 o;
  o.x = v00.x * w00 + v01.x * w01 + v10.x * w10 + v11.x * w11;
  o.y = v00.y * w00 + v01.y * w01 + v10.y * w10 + v11.y * w11;
  warped[gid] = o;
}

// row FFT forward: one wave per (c,zz,h) line; in = warped*csm*(-1)^(h+w) loaded straight to regs
__global__ __launch_bounds__(256) void k_fft_row_fwd(const float2* __restrict__ warped, const float2* __restrict__ csm,
                                                     float2* __restrict__ F, int p){
  __shared__ float2 seg[4 * LSTR];
  FT f = ft_init();
  int wid = threadIdx.x >> 6, l = f.lane;
  int lineid = blockIdx.x * 4 + wid;                 // < CHN*ZE*HG = 15360
  int c = lineid / (ZE * HG); int rem = lineid - c * (ZE * HG);
  int zz = rem / HG; int h = rem - zz * HG; int z = zz + 1;
  const float2* wr = warped + ((size_t)(p * ZE + zz)) * HW2 + (size_t)h * WG;
  const float2* cs = csm + ((size_t)(c * ZT + z)) * HW2 + (size_t)h * WG;
  float sgn = ((h + l) & 1) ? -1.f : 1.f;            // (-1)^(h + 64q + l), 64q even
  float2 a[5];
  #pragma unroll
  for (int q = 0; q < 5; q++){
    float2 v = cmul(wr[64 * q + l], cs[64 * q + l]);
    a[q] = make_float2(v.x * sgn, v.y * sgn);
  }
  float2* sg = seg + wid * LSTR;
  fft320w(a, f, sg);
  __syncthreads();
  float2* out = F + ((size_t)(c * ZE + zz)) * HW2 + (size_t)h * WG;
  #pragma unroll
  for (int q = 0; q < 5; q++) out[64 * q + l] = sg[64 * q + l];
}

// column FFT, in place: stage 16 cols to LDS, per-wave in-register FFT per column
__global__ __launch_bounds__(256) void k_fft_col(float2* __restrict__ F){
  __shared__ float2 ld[16 * LSTR];
  FT f = ft_init();
  int tid = threadIdx.x; int wid = tid >> 6, l = f.lane;
  int cg = blockIdx.x % 20; int s = blockIdx.x / 20;
  float2* Fs = F + (size_t)s * HW2 + cg * 16;
  for (int i = tid; i < 5120; i += 256){ int h = i >> 4, col = i & 15; ld[col * LSTR + h] = Fs[h * WG + col]; }
  __syncthreads();
  #pragma unroll
  for (int cc = 0; cc < 4; cc++){
    float2* base = ld + (wid * 4 + cc) * LSTR;
    float2 a[5];
    #pragma unroll
    for (int q = 0; q < 5; q++) a[q] = base[64 * q + l];
    fft320w(a, f, base);
  }
  __syncthreads();
  for (int i = tid; i < 5120; i += 256){ int h = i >> 4, col = i & 15; Fs[h * WG + col] = ld[col * LSTR + h]; }
}

__global__ __launch_bounds__(256) void k_sample(const float2* __restrict__ F, const float* __restrict__ traj,
                                                float2* __restrict__ est, unsigned int* __restrict__ dmax, int p){
  int gid = blockIdx.x * 256 + threadIdx.x;     // over CHN*ZE*NKP
  int k = gid & (NKP - 1);
  int t = gid >> 12;
  int zz = t % ZE; int c = t / ZE;
  float ty = traj[(p * 2 + 0) * NKP + k];
  float tx = traj[(p * 2 + 1) * NKP + k];
  float gy = fminf(fmaxf((ty / TWO_PI_F + 0.5f) * 320.f, 0.f), 319.f);
  float gx = fminf(fmaxf((tx / TWO_PI_F + 0.5f) * 320.f, 0.f), 319.f);
  int y0, x0, y1, x1; float w00, w01, w10, w11;
  corners(gy, gx, y0, x0, y1, x1, w00, w01, w10, w11);
  const float2* Fs = F + (size_t)(c * ZE + zz) * HW2;
  float2 v00 = Fs[y0 * WG + x0], v01 = Fs[y0 * WG + x1];
  float2 v10 = Fs[y1 * WG + x0], v11 = Fs[y1 * WG + x1];
  float2 e;
  e.x = v00.x * w00 + v01.x * w01 + v10.x * w10 + v11.x * w11;
  e.y = v00.y * w00 + v01.y * w01 + v10.y * w10 + v11.y * w11;
  est[((size_t)(p * CHN + c) * ZE + zz) * NKP + k] = e;
  float d2 = e.x * e.x + e.y * e.y;
  for (int off = 32; off > 0; off >>= 1) d2 = fmaxf(d2, __shfl_down(d2, off, 64));
  if ((threadIdx.x & 63) == 0) atomicMax(dmax, __float_as_uint(d2));   // d2 >= 0: uint order ok
}

// est -> cotangent: G = (w^2/N) * conj(est - y)   (conj = JAX bilinear-VJP convention)
__global__ __launch_bounds__(256) void k_weights(float2* __restrict__ est, const float2* __restrict__ kdata,
                                                 const unsigned int* __restrict__ dmax){
  int gid = blockIdx.x * 256 + threadIdx.x;     // over PH*CHN*ZE*NKP
  int k = gid & (NKP - 1);
  int t = gid >> 12;                            // (p*CHN+c)*ZE + zz
  int zz = t % ZE; int pc = t / ZE; int z = zz + 1;
  float md = sqrtf(__uint_as_float(*dmax));
  float2 e = est[gid];
  float det = sqrtf(e.x * e.x + e.y * e.y);
  float wv = 1.0f / (det / md + EPS_C);
  float sc = wv * wv * INV_N;
  float2 y = kdata[((size_t)pc * ZT + z) * NKP + k];
  est[gid] = make_float2(sc * (e.x - y.x), -sc * (e.y - y.y));
}

// backward: fused { zero tile + k-space corner scatter (LDS atomics) + per-wave column DFT^T }
__global__ __launch_bounds__(256) void k_fft_col_scatter(const float2* __restrict__ G, const float* __restrict__ traj,
                                                         float2* __restrict__ F, int p){
  __shared__ float2 ld[16 * LSTR];
  FT f = ft_init();
  int tid = threadIdx.x; int wid = tid >> 6, l = f.lane;
  int cg = blockIdx.x % 20; int s = blockIdx.x / 20; int zz = s % ZE; int c = s / ZE;
  for (int i = tid; i < 16 * LSTR; i += 256) ld[i] = make_float2(0.f, 0.f);
  __syncthreads();
  int cbase = cg * 16;
  const float* tyb = traj + (p * 2 + 0) * NKP;
  const float* txb = traj + (p * 2 + 1) * NKP;
  const float2* Gs = G + ((size_t)(p * CHN + c) * ZE + zz) * NKP;
  for (int k = tid; k < NKP; k += 256){
    float gy = fminf(fmaxf((tyb[k] / TWO_PI_F + 0.5f) * 320.f, 0.f), 319.f);
    float gx = fminf(fmaxf((txb[k] / TWO_PI_F + 0.5f) * 320.f, 0.f), 319.f);
    int y0, x0, y1, x1; float w00, w01, w10, w11;
    corners(gy, gx, y0, x0, y1, x1, w00, w01, w10, w11);
    float2 gv = Gs[k];
    int c0 = x0 - cbase, c1 = x1 - cbase;
    if ((unsigned)c0 < 16u){
      atomicAdd(&ld[c0 * LSTR + y0].x, gv.x * w00); atomicAdd(&ld[c0 * LSTR + y0].y, gv.y * w00);
      atomicAdd(&ld[c0 * LSTR + y1].x, gv.x * w10); atomicAdd(&ld[c0 * LSTR + y1].y, gv.y * w10);
    }
    if ((unsigned)c1 < 16u){
      atomicAdd(&ld[c1 * LSTR + y0].x, gv.x * w01); atomicAdd(&ld[c1 * LSTR + y0].y, gv.y * w01);
      atomicAdd(&ld[c1 * LSTR + y1].x, gv.x * w11); atomicAdd(&ld[c1 * LSTR + y1].y, gv.y * w11);
    }
  }
  __syncthreads();
  #pragma unroll
  for (int cc = 0; cc < 4; cc++){
    float2* base = ld + (wid * 4 + cc) * LSTR;
    float2 a[5];
    #pragma unroll
    for (int q = 0; q < 5; q++) a[q] = base[64 * q + l];
    fft320w(a, f, base);
  }
  __syncthreads();
  float2* Fs = F + (size_t)s * HW2 + cbase;
  for (int i = tid; i < 5120; i += 256){ int h = i >> 4, col = i & 15; Fs[h * WG + col] = ld[col * LSTR + h]; }
}

// transpose row pass: 8 waves = 8 coils of one (zz,h) row; epilogue *(-1)^(h+w), *csm, coil sum
__global__ __launch_bounds__(512) void k_fft_row_bwd(const float2* __restrict__ F, const float2* __restrict__ csm,
                                                     float2* __restrict__ gwarped, int p){
  __shared__ float2 seg[8 * LSTR];
  FT f = ft_init();
  int tid = threadIdx.x; int c = tid >> 6, l = f.lane;
  int zz = blockIdx.x / HG; int h = blockIdx.x - zz * HG; int z = zz + 1;
  const float2* Fl = F + ((size_t)(c * ZE + zz)) * HW2 + (size_t)h * WG;
  float2 a[5];
  #pragma unroll
  for (int q = 0; q < 5; q++) a[q] = Fl[64 * q + l];
  fft320w(a, f, seg + c * LSTR);
  __syncthreads();
  if (tid < WG){
    int w = tid;
    float2 acc = make_float2(0.f, 0.f);
    #pragma unroll
    for (int cc = 0; cc < 8; cc++){
      cmac(acc, seg[cc * LSTR + w], csm[((size_t)(cc * ZT + z)) * HW2 + (size_t)h * WG + w]);
    }
    float sg = ((h + w) & 1) ? -1.f : 1.f;
    gwarped[((size_t)(p * ZE + zz)) * HW2 + (size_t)h * WG + w] = make_float2(acc.x * sg, acc.y * sg);
  }
}

// TV gradient (natural real-pair grad), stored CONJUGATED to match jax.grad convention
__global__ __launch_bounds__(256) void k_tv(const float2* __restrict__ x, float2* __restrict__ gtv){
  int gid = blockIdx.x * 256 + threadIdx.x;     // PH*ZE*HW2
  int hw = gid % HW2;
  int pz = gid / HW2;
  int zz = pz % ZE, p = pz / ZE, z = zz + 1;
  int h = hw / WG, w = hw - h * WG;
  const float2* xs = x + (size_t)(p * ZT + z) * HW2;
  float2 xc = xs[hw];
  float tre = 0.f, tim = 0.f;
  if (h > 0){
    float2 n = xs[hw - WG];
    float dr = xc.x - n.x, di = xc.y - n.y;
    float r = sqrtf(dr * dr + di * di + 1e-8f);
    tre += dr / r; tim += di / r;
  }
  if (h < HG - 1){
    float2 n = xs[hw + WG];
    float dr = n.x - xc.x, di = n.y - xc.y;
    float r = sqrtf(dr * dr + di * di + 1e-8f);
    tre -= dr / r; tim -= di / r;
  }
  if (w > 0){
    float2 n = xs[hw - 1];
    float dr = xc.x - n.x, di = xc.y - n.y;
    float r = sqrtf(dr * dr + di * di + 1e-8f);
    tre += dr / r; tim += di / r;
  }
  if (w < WG - 1){
    float2 n = xs[hw + 1];
    float dr = n.x - xc.x, di = n.y - xc.y;
    float r = sqrtf(dr * dr + di * di + 1e-8f);
    tre -= dr / r; tim -= di / r;
  }
  gtv[gid] = make_float2(tre, -tim);
}

// ---------------- gather-tiled warp adjoint + fused gradient update ----------------
// Block owns target rows [R, R+16) of one (p,zz) image EXCLUSIVELY; scans source rows
// [R-8, R+24) and accumulates bilinear-corner contributions that land in its range into a
// 40 KB LDS tile (LDS atomics only). Then applies x -= GAMMA*gdc + TAU*s*gtv with plain
// coalesced stores. Exactly-once: pair (source h, corner y) handled by the block owning y
// iff h in [Ry-8, Ry+24); the unique block owning h AS TARGET pushes the complement
// (P ~ 6e-5) to a fallback list, applied post-hoc by k_fixup (update is linear in gdc).
#define TRG 16
#define HAG 8
__global__ __launch_bounds__(512) void k_warpadj_update(const float2* __restrict__ gw, const float* __restrict__ mvf,
                                                        const float2* __restrict__ gtv, const float* __restrict__ stdp,
                                                        float2* __restrict__ x,
                                                        uint4* __restrict__ fb, unsigned int* __restrict__ fbcnt){
  __shared__ float lt[TRG * WG * 2];   // 40960 B
  int tid = threadIdx.x;
  int bid = blockIdx.x;                    // pz*20 + tile
  int tile = bid % 20; int pz = bid / 20;
  int zz = pz % ZE, p = pz / ZE, z = zz + 1;
  int R = tile * TRG;
  for (int i = tid; i < TRG * WG * 2; i += 512) lt[i] = 0.f;
  __syncthreads();
  const float* mvy = mvf + ((size_t)(p * 2 + 0) * ZT + z) * HW2;
  const float* mvx = mvy + (size_t)ZT * HW2;
  const float2* g = gw + (size_t)pz * HW2;
  const size_t xbase = (size_t)(p * ZT + z) * HW2;
  int wlo = max(R - HAG, 0), whi = min(R + TRG + HAG, HG);
  int nrows = whi - wlo;
  for (int i = tid; i < nrows * WG; i += 512){
    int hh = i / WG; int w = i - hh * WG;
    int h = wlo + hh;
    int hw = h * WG + w;
    float fy = mvy[hw];
    float fx = mvx[hw];
    float gy = fminf(fmaxf((float)h + fy, 0.f), 319.f);
    float gx = fminf(fmaxf((float)w + fx, 0.f), 319.f);
    int y0, x0, y1, x1; float w00, w01, w10, w11;
    corners(gy, gx, y0, x0, y1, x1, w00, w01, w10, w11);
    float2 gv = g[hw];
    bool owner = (h >= R) && (h < R + TRG);
    #define PROC(Y, XC, WT) { \
      int ry = (Y) - R; \
      if ((unsigned)ry < (unsigned)TRG){ \
        atomicAdd(&lt[(ry * WG + (XC)) * 2 + 0], gv.x * (WT)); \
        atomicAdd(&lt[(ry * WG + (XC)) * 2 + 1], gv.y * (WT)); \
      } else if (owner){ \
        int Ry = (Y) & ~(TRG - 1); \
        if (h < Ry - HAG || h >= Ry + TRG + HAG){ \
          unsigned slot = atomicAdd(fbcnt, 1u); \
          if (slot < FBCAP) fb[slot] = make_uint4((unsigned)(xbase + (size_t)(Y) * WG + (XC)), \
                                                  __float_as_uint(gv.x * (WT)), __float_as_uint(gv.y * (WT)), 0u); \
        } \
      } \
    }
    PROC(y0, x0, w00); PROC(y0, x1, w01); PROC(y1, x0, w10); PROC(y1, x1, w11);
    #undef PROC
  }
  __syncthreads();
  float s = stdp[0];
  const float2* gt = gtv + (size_t)pz * HW2;
  for (int i = tid; i < TRG * WG; i += 512){
    int yy = i / WG; int w = i - yy * WG;
    int hw = (R + yy) * WG + w;
    float2 xv = x[xbase + hw];
    float2 tv = gt[hw];
    xv.x -= GAMMA_C * lt[i * 2 + 0] + TAU_C * s * tv.x;
    xv.y -= GAMMA_C * lt[i * 2 + 1] + TAU_C * s * tv.y;
    x[xbase + hw] = xv;
  }
}

// apply rare out-of-halo contributions: x[idx] -= GAMMA * val (runs after k_warpadj_update)
__global__ __launch_bounds__(256) void k_fixup(const uint4* __restrict__ fb, const unsigned int* __restrict__ fbcnt,
                                               float2* __restrict__ x){
  unsigned n = *fbcnt; if (n > FBCAP) n = FBCAP;
  for (unsigned i = blockIdx.x * 256 + threadIdx.x; i < n; i += gridDim.x * 256){
    uint4 e = fb[i];
    atomicAdd(&x[e.x].x, -GAMMA_C * __uint_as_float(e.y));
    atomicAdd(&x[e.x].y, -GAMMA_C * __uint_as_float(e.z));
  }
}

// ---------------- host ----------------
extern "C" void kernel_launch(void* const* d_in, const int* in_sizes, int n_in,
                              void* d_out, int out_size, void* d_ws, size_t ws_size,
                              hipStream_t stream) {
  const float2* kdata = (const float2*)d_in[0];   // (PH,CHN,ZT,NK) complex
  const float*  traj  = (const float*) d_in[1];   // (PH,2,NK)
  const float2* img0  = (const float2*)d_in[2];   // (PH,ZT,H,W) complex
  const float*  mvf   = (const float*) d_in[3];   // (PH,2,ZT,H,W)
  const float2* csm   = (const float2*)d_in[4];   // (CHN,ZT,H,W) complex
  const float*  stdp  = (const float*) d_in[5];   // (1,)
  float2* x = (float2*)d_out;                     // x lives in d_out (same layout as output)

  // workspace layout (bytes): total ~68 MB
  char* ws = (char*)d_ws;
  const size_t F_B  = (size_t)CHN * ZE * HW2 * 8;        // 39,321,600
  const size_t W_B  = (size_t)PH * ZE * HW2 * 8;         // 19,660,800
  const size_t E_B  = (size_t)PH * CHN * ZE * NKP * 8;   //  6,291,456
  float2* F      = (float2*)(ws);
  float2* warped = (float2*)(ws + F_B);                  // also holds gwarped
  float2* est    = (float2*)(ws + F_B + W_B);
  float2* gtvb   = (float2*)(ws + F_B + W_B + E_B);      // TV gradient buffer
  unsigned int* dmax  = (unsigned int*)(ws + F_B + 2 * W_B + E_B);
  unsigned int* fbcnt = (unsigned int*)(ws + F_B + 2 * W_B + E_B + 64);
  uint4* fb           = (uint4*)(ws + F_B + 2 * W_B + E_B + 128);   // 2 MB

  k_init<<<12800, 256, 0, stream>>>(img0, x, PH * ZT * HW2);

  for (int it = 0; it < 3; it++){
    k_warp<<<9600, 256, 0, stream>>>(x, mvf, warped);
    hipMemsetAsync(dmax, 0, 4, stream);
    for (int p = 0; p < PH; p++){
      k_fft_row_fwd<<<3840, 256, 0, stream>>>(warped, csm, F, p);
      k_fft_col    <<< 960, 256, 0, stream>>>(F);
      k_sample     <<< 768, 256, 0, stream>>>(F, traj, est, dmax, p);
    }
    k_weights<<<3072, 256, 0, stream>>>(est, kdata, dmax);
    for (int p = 0; p < PH; p++){
      k_fft_col_scatter<<< 960, 256, 0, stream>>>(est, traj, F, p);
      k_fft_row_bwd    <<<1920, 512, 0, stream>>>(F, csm, warped, p);   // warped <- gwarped
    }
    k_tv<<<9600, 256, 0, stream>>>(x, gtvb);
    hipMemsetAsync(fbcnt, 0, 4, stream);
    k_warpadj_update<<<480, 512, 0, stream>>>(warped, mvf, gtvb, stdp, x, fb, fbcnt);
    k_fixup<<<16, 256, 0, stream>>>(fb, fbcnt, x);
  }
}

// Round 7
// 2025.302 us; speedup vs baseline: 1.6434x; 1.2209x over previous
//
#include <hip/hip_runtime.h>
#include <math.h>

// ---------------- problem constants ----------------
#define PH   4
#define CHN  8
#define ZT   8
#define ZE   6          // effective z slices: z in [1,7)
#define HG   320
#define WG   320
#define HW2  102400     // 320*320
#define NKP  4096
#define LSTR 321        // LDS line stride (pad +1)
#define FBCAP 131072u   // fallback list capacity (entries)

constexpr float GAMMA_C = 0.1f;
constexpr float TAU_C   = 0.2f;
constexpr float EPS_C   = 0.01f;
constexpr float INV_N   = 1.0f / 786432.0f;   // PH*CHN*ZE*NKP
#define TWO_PI_F 6.28318530717958647692f

// W5^j = e^{-2*pi*i*j/5}
constexpr float W5R[5] = { 1.f,  0.30901699f, -0.80901699f, -0.80901699f,  0.30901699f};
constexpr float W5I[5] = { 0.f, -0.95105652f, -0.58778525f,  0.58778525f,  0.95105652f};

// ---------------- complex helpers ----------------
__device__ __forceinline__ float2 cmul(float2 a, float2 b){
  return make_float2(a.x*b.x - a.y*b.y, a.x*b.y + a.y*b.x);
}
__device__ __forceinline__ void cmac(float2& d, float2 a, float2 b){
  d.x = fmaf(a.x, b.x, fmaf(-a.y, b.y, d.x));
  d.y = fmaf(a.x, b.y, fmaf( a.y, b.x, d.y));
}

__device__ __forceinline__ void corners(float gy, float gx, int& y0, int& x0, int& y1, int& x1,
                                        float& w00, float& w01, float& w10, float& w11){
  float y0f = floorf(gy), x0f = floorf(gx);
  float wy = gy - y0f, wx = gx - x0f;
  y0 = (int)y0f; x0 = (int)x0f;
  y1 = min(y0 + 1, HG - 1); x1 = min(x0 + 1, WG - 1);
  w00 = (1.f - wy) * (1.f - wx);
  w01 = (1.f - wy) * wx;
  w10 = wy * (1.f - wx);
  w11 = wy * wx;
}

// ---------------- in-register 320-pt FFT: one wave per line, N = 5 x 64 ----------------
// (unchanged from round 5/6 — verified). Lane l stores X[5*br6(l)+r]; un-permuted via LDS seg.
struct FT {
  float2 t1, t2, t3, t4;
  float2 tw0, tw1, tw2, tw3, tw4;
  int br5, lane;
};

__device__ __forceinline__ FT ft_init(){
  FT f; int l = (int)(threadIdx.x & 63); f.lane = l;
  sincosf(-TWO_PI_F * (float)l * (1.0f/320.0f), &f.t1.y, &f.t1.x);
  f.t2 = cmul(f.t1, f.t1); f.t3 = cmul(f.t2, f.t1); f.t4 = cmul(f.t2, f.t2);
  sincosf(-TWO_PI_F * (float)(l & 31) * (1.0f/64.0f), &f.tw0.y, &f.tw0.x);
  sincosf(-TWO_PI_F * (float)(l & 15) * (1.0f/32.0f), &f.tw1.y, &f.tw1.x);
  sincosf(-TWO_PI_F * (float)(l &  7) * (1.0f/16.0f), &f.tw2.y, &f.tw2.x);
  sincosf(-TWO_PI_F * (float)(l &  3) * (1.0f/ 8.0f), &f.tw3.y, &f.tw3.x);
  f.tw4 = (l & 1) ? make_float2(0.f, -1.f) : make_float2(1.f, 0.f);
  int br = ((l&1)<<5) | ((l&2)<<3) | ((l&4)<<1) | ((l&8)>>1) | ((l&16)>>3) | ((l&32)>>5);
  f.br5 = 5 * br;
  return f;
}

template<int H>
__device__ __forceinline__ void bfly(float2& v, float2 tw, int lane){
  float px = __shfl_xor(v.x, H, 64);
  float py = __shfl_xor(v.y, H, 64);
  bool up = (lane & H) != 0;
  float ax = up ? px : v.x, ay = up ? py : v.y;
  float bx = up ? v.x : px, by = up ? v.y : py;
  float dx = ax - bx,  dy = ay - by;
  float mx = fmaf(dx, tw.x, -dy * tw.y);
  float my = fmaf(dx, tw.y,  dy * tw.x);
  v.x = up ? mx : (ax + bx);
  v.y = up ? my : (ay + by);
}

__device__ __forceinline__ void fft320w(const float2 a[5], const FT& f, float2* __restrict__ seg){
  float2 z[5];
  #pragma unroll
  for (int r = 0; r < 5; r++){
    float2 acc = a[0];
    #pragma unroll
    for (int q = 1; q < 5; q++){
      const int j = (q * r) % 5;
      cmac(acc, a[q], make_float2(W5R[j], W5I[j]));
    }
    z[r] = acc;
  }
  z[1] = cmul(z[1], f.t1); z[2] = cmul(z[2], f.t2);
  z[3] = cmul(z[3], f.t3); z[4] = cmul(z[4], f.t4);
  #pragma unroll
  for (int r = 0; r < 5; r++){
    float2 v = z[r];
    bfly<32>(v, f.tw0, f.lane);
    bfly<16>(v, f.tw1, f.lane);
    bfly< 8>(v, f.tw2, f.lane);
    bfly< 4>(v, f.tw3, f.lane);
    bfly< 2>(v, f.tw4, f.lane);
    {
      float px = __shfl_xor(v.x, 1, 64);
      float py = __shfl_xor(v.y, 1, 64);
      bool up = (f.lane & 1) != 0;
      float ax = up ? px : v.x, ay = up ? py : v.y;
      float bx = up ? v.x : px, by = up ? v.y : py;
      v.x = up ? (ax - bx) : (ax + bx);
      v.y = up ? (ay - by) : (ay + by);
    }
    seg[f.br5 + r] = v;
  }
}

// ---------------- kernels ----------------
__global__ __launch_bounds__(256) void k_init(const float2* __restrict__ img0, float2* __restrict__ x, int n){
  int i = blockIdx.x * 256 + threadIdx.x;
  if (i < n){
    float2 v = img0[i];
    v.x = isnan(v.x) ? 0.f : fminf(fmaxf(v.x, -3.4028235e38f), 3.4028235e38f);
    v.y = isnan(v.y) ? 0.f : fminf(fmaxf(v.y, -3.4028235e38f), 3.4028235e38f);
    x[i] = v;
  }
}

// fused: warped = bilinear-warp(x, mvf); gtv = conj(TV-grad(x))   (both read the SAME pre-update x)
__global__ __launch_bounds__(256) void k_warp_tv(const float2* __restrict__ x, const float* __restrict__ mvf,
                                                 float2* __restrict__ warped, float2* __restrict__ gtv){
  int gid = blockIdx.x * 256 + threadIdx.x;          // over PH*ZE*HW2
  int hw = gid % HW2;
  int pz = gid / HW2;
  int zz = pz % ZE, p = pz / ZE, z = zz + 1;
  int h = hw / WG, w = hw - h * WG;
  const float* mv = mvf + ((size_t)(p * 2 + 0) * ZT + z) * HW2;
  float fy = mv[hw];
  float fx = mv[(size_t)ZT * HW2 + hw];
  float gy = fminf(fmaxf((float)h + fy, 0.f), 319.f);
  float gx = fminf(fmaxf((float)w + fx, 0.f), 319.f);
  int y0, x0, y1, x1; float w00, w01, w10, w11;
  corners(gy, gx, y0, x0, y1, x1, w00, w01, w10, w11);
  const float2* xs = x + (size_t)(p * ZT + z) * HW2;
  float2 v00 = xs[y0 * WG + x0], v01 = xs[y0 * WG + x1];
  float2 v10 = xs[y1 * WG + x0], v11 = xs[y1 * WG + x1];
  float2 o;
  o.x = v00.x * w00 + v01.x * w01 + v10.x * w10 + v11.x * w11;
  o.y = v00.y * w00 + v01.y * w01 + v10.y * w10 + v11.y * w11;
  warped[gid] = o;
  // TV gradient
  float2 xc = xs[hw];
  float tre = 0.f, tim = 0.f;
  if (h > 0){
    float2 n = xs[hw - WG];
    float dr = xc.x - n.x, di = xc.y - n.y;
    float r = sqrtf(dr * dr + di * di + 1e-8f);
    tre += dr / r; tim += di / r;
  }
  if (h < HG - 1){
    float2 n = xs[hw + WG];
    float dr = n.x - xc.x, di = n.y - xc.y;
    float r = sqrtf(dr * dr + di * di + 1e-8f);
    tre -= dr / r; tim -= di / r;
  }
  if (w > 0){
    float2 n = xs[hw - 1];
    float dr = xc.x - n.x, di = xc.y - n.y;
    float r = sqrtf(dr * dr + di * di + 1e-8f);
    tre += dr / r; tim += di / r;
  }
  if (w < WG - 1){
    float2 n = xs[hw + 1];
    float dr = n.x - xc.x, di = n.y - xc.y;
    float r = sqrtf(dr * dr + di * di + 1e-8f);
    tre -= dr / r; tim -= di / r;
  }
  gtv[gid] = make_float2(tre, -tim);
}

// row FFT forward, phases batched: lineid over np*CHN*ZE*HG
__global__ __launch_bounds__(256) void k_fft_row_fwd(const float2* __restrict__ warped, const float2* __restrict__ csm,
                                                     float2* __restrict__ F, int p0){
  __shared__ float2 seg[4 * LSTR];
  FT f = ft_init();
  int wid = threadIdx.x >> 6, l = f.lane;
  int lineid = blockIdx.x * 4 + wid;
  int pp = lineid / (CHN * ZE * HG); int rem = lineid - pp * (CHN * ZE * HG);
  int c = rem / (ZE * HG); rem -= c * (ZE * HG);
  int zz = rem / HG; int h = rem - zz * HG; int z = zz + 1;
  int p = p0 + pp;
  const float2* wr = warped + ((size_t)(p * ZE + zz)) * HW2 + (size_t)h * WG;
  const float2* cs = csm + ((size_t)(c * ZT + z)) * HW2 + (size_t)h * WG;
  float sgn = ((h + l) & 1) ? -1.f : 1.f;
  float2 a[5];
  #pragma unroll
  for (int q = 0; q < 5; q++){
    float2 v = cmul(wr[64 * q + l], cs[64 * q + l]);
    a[q] = make_float2(v.x * sgn, v.y * sgn);
  }
  float2* sg = seg + wid * LSTR;
  fft320w(a, f, sg);
  __syncthreads();
  float2* out = F + ((size_t)((pp * CHN + c) * ZE + zz)) * HW2 + (size_t)h * WG;
  #pragma unroll
  for (int q = 0; q < 5; q++) out[64 * q + l] = sg[64 * q + l];
}

// column FFT, in place; slice index local to this dispatch's F window
__global__ __launch_bounds__(256) void k_fft_col(float2* __restrict__ F){
  __shared__ float2 ld[16 * LSTR];
  FT f = ft_init();
  int tid = threadIdx.x; int wid = tid >> 6, l = f.lane;
  int cg = blockIdx.x % 20; int s = blockIdx.x / 20;
  float2* Fs = F + (size_t)s * HW2 + cg * 16;
  for (int i = tid; i < 5120; i += 256){ int h = i >> 4, col = i & 15; ld[col * LSTR + h] = Fs[h * WG + col]; }
  __syncthreads();
  #pragma unroll
  for (int cc = 0; cc < 4; cc++){
    float2* base = ld + (wid * 4 + cc) * LSTR;
    float2 a[5];
    #pragma unroll
    for (int q = 0; q < 5; q++) a[q] = base[64 * q + l];
    fft320w(a, f, base);
  }
  __syncthreads();
  for (int i = tid; i < 5120; i += 256){ int h = i >> 4, col = i & 15; Fs[h * WG + col] = ld[col * LSTR + h]; }
}

__global__ __launch_bounds__(256) void k_sample(const float2* __restrict__ F, const float* __restrict__ traj,
                                                float2* __restrict__ est, unsigned int* __restrict__ dmax, int p0){
  int gid = blockIdx.x * 256 + threadIdx.x;     // over np*CHN*ZE*NKP
  int k = gid & (NKP - 1);
  int t = gid >> 12;                            // local slice (pp,c,zz)
  int zz = t % ZE; int t2 = t / ZE; int c = t2 % CHN; int pp = t2 / CHN;
  int p = p0 + pp;
  float ty = traj[(p * 2 + 0) * NKP + k];
  float tx = traj[(p * 2 + 1) * NKP + k];
  float gy = fminf(fmaxf((ty / TWO_PI_F + 0.5f) * 320.f, 0.f), 319.f);
  float gx = fminf(fmaxf((tx / TWO_PI_F + 0.5f) * 320.f, 0.f), 319.f);
  int y0, x0, y1, x1; float w00, w01, w10, w11;
  corners(gy, gx, y0, x0, y1, x1, w00, w01, w10, w11);
  const float2* Fs = F + (size_t)t * HW2;
  float2 v00 = Fs[y0 * WG + x0], v01 = Fs[y0 * WG + x1];
  float2 v10 = Fs[y1 * WG + x0], v11 = Fs[y1 * WG + x1];
  float2 e;
  e.x = v00.x * w00 + v01.x * w01 + v10.x * w10 + v11.x * w11;
  e.y = v00.y * w00 + v01.y * w01 + v10.y * w10 + v11.y * w11;
  est[((size_t)(p0 * CHN * ZE) + t) * NKP + k] = e;
  float d2 = e.x * e.x + e.y * e.y;
  for (int off = 32; off > 0; off >>= 1) d2 = fmaxf(d2, __shfl_down(d2, off, 64));
  if ((threadIdx.x & 63) == 0) atomicMax(dmax, __float_as_uint(d2));
}

// est -> cotangent: G = (w^2/N) * conj(est - y)
__global__ __launch_bounds__(256) void k_weights(float2* __restrict__ est, const float2* __restrict__ kdata,
                                                 const unsigned int* __restrict__ dmax){
  int gid = blockIdx.x * 256 + threadIdx.x;     // over PH*CHN*ZE*NKP
  int k = gid & (NKP - 1);
  int t = gid >> 12;
  int zz = t % ZE; int pc = t / ZE; int z = zz + 1;
  float md = sqrtf(__uint_as_float(*dmax));
  float2 e = est[gid];
  float det = sqrtf(e.x * e.x + e.y * e.y);
  float wv = 1.0f / (det / md + EPS_C);
  float sc = wv * wv * INV_N;
  float2 y = kdata[((size_t)pc * ZT + z) * NKP + k];
  est[gid] = make_float2(sc * (e.x - y.x), -sc * (e.y - y.y));
}

// backward: fused { zero tile + k-space corner scatter (LDS atomics) + per-wave column DFT^T }
__global__ __launch_bounds__(256) void k_fft_col_scatter(const float2* __restrict__ G, const float* __restrict__ traj,
                                                         float2* __restrict__ F, int p0){
  __shared__ float2 ld[16 * LSTR];
  FT f = ft_init();
  int tid = threadIdx.x; int wid = tid >> 6, l = f.lane;
  int cg = blockIdx.x % 20; int sl = blockIdx.x / 20;       // local slice
  int s2 = sl / ZE; int pp = s2 / CHN;
  int p = p0 + pp;
  for (int i = tid; i < 16 * LSTR; i += 256) ld[i] = make_float2(0.f, 0.f);
  __syncthreads();
  int cbase = cg * 16;
  const float* tyb = traj + (p * 2 + 0) * NKP;
  const float* txb = traj + (p * 2 + 1) * NKP;
  const float2* Gs = G + ((size_t)(p0 * CHN * ZE) + sl) * NKP;
  for (int k = tid; k < NKP; k += 256){
    float gy = fminf(fmaxf((tyb[k] / TWO_PI_F + 0.5f) * 320.f, 0.f), 319.f);
    float gx = fminf(fmaxf((txb[k] / TWO_PI_F + 0.5f) * 320.f, 0.f), 319.f);
    int y0, x0, y1, x1; float w00, w01, w10, w11;
    corners(gy, gx, y0, x0, y1, x1, w00, w01, w10, w11);
    float2 gv = Gs[k];
    int c0 = x0 - cbase, c1 = x1 - cbase;
    if ((unsigned)c0 < 16u){
      atomicAdd(&ld[c0 * LSTR + y0].x, gv.x * w00); atomicAdd(&ld[c0 * LSTR + y0].y, gv.y * w00);
      atomicAdd(&ld[c0 * LSTR + y1].x, gv.x * w10); atomicAdd(&ld[c0 * LSTR + y1].y, gv.y * w10);
    }
    if ((unsigned)c1 < 16u){
      atomicAdd(&ld[c1 * LSTR + y0].x, gv.x * w01); atomicAdd(&ld[c1 * LSTR + y0].y, gv.y * w01);
      atomicAdd(&ld[c1 * LSTR + y1].x, gv.x * w11); atomicAdd(&ld[c1 * LSTR + y1].y, gv.y * w11);
    }
  }
  __syncthreads();
  #pragma unroll
  for (int cc = 0; cc < 4; cc++){
    float2* base = ld + (wid * 4 + cc) * LSTR;
    float2 a[5];
    #pragma unroll
    for (int q = 0; q < 5; q++) a[q] = base[64 * q + l];
    fft320w(a, f, base);
  }
  __syncthreads();
  float2* Fs = F + (size_t)sl * HW2 + cbase;
  for (int i = tid; i < 5120; i += 256){ int h = i >> 4, col = i & 15; Fs[h * WG + col] = ld[col * LSTR + h]; }
}

// transpose row pass: 8 waves = 8 coils of one (pp,zz,h) row; epilogue *(-1)^(h+w), *csm, coil sum
__global__ __launch_bounds__(512) void k_fft_row_bwd(const float2* __restrict__ F, const float2* __restrict__ csm,
                                                     float2* __restrict__ gwarped, int p0){
  __shared__ float2 seg[8 * LSTR];
  FT f = ft_init();
  int tid = threadIdx.x; int c = tid >> 6, l = f.lane;
  int bid = blockIdx.x;                          // over np*ZE*HG
  int h = bid % HG; int b2 = bid / HG;
  int zz = b2 % ZE; int pp = b2 / ZE;
  int p = p0 + pp; int z = zz + 1;
  const float2* Fl = F + ((size_t)((pp * CHN + c) * ZE + zz)) * HW2 + (size_t)h * WG;
  float2 a[5];
  #pragma unroll
  for (int q = 0; q < 5; q++) a[q] = Fl[64 * q + l];
  fft320w(a, f, seg + c * LSTR);
  __syncthreads();
  if (tid < WG){
    int w = tid;
    float2 acc = make_float2(0.f, 0.f);
    #pragma unroll
    for (int cc = 0; cc < 8; cc++){
      cmac(acc, seg[cc * LSTR + w], csm[((size_t)(cc * ZT + z)) * HW2 + (size_t)h * WG + w]);
    }
    float sg = ((h + w) & 1) ? -1.f : 1.f;
    gwarped[((size_t)(p * ZE + zz)) * HW2 + (size_t)h * WG + w] = make_float2(acc.x * sg, acc.y * sg);
  }
}

// ---------------- gather-tiled warp adjoint + fused gradient update ----------------
// TRG=8 rows/block (LDS 20 KB) -> 960 blocks; explicit prefetch pipelining of mv/g loads.
#define TRG 8
#define HAG 8
__global__ __launch_bounds__(512) void k_warpadj_update(const float2* __restrict__ gw, const float* __restrict__ mvf,
                                                        const float2* __restrict__ gtv, const float* __restrict__ stdp,
                                                        float2* __restrict__ x,
                                                        uint4* __restrict__ fb, unsigned int* __restrict__ fbcnt){
  __shared__ float lt[TRG * WG * 2];   // 20480 B
  int tid = threadIdx.x;
  int bid = blockIdx.x;                    // pz*40 + tile
  int tile = bid % 40; int pz = bid / 40;
  int zz = pz % ZE, p = pz / ZE, z = zz + 1;
  int R = tile * TRG;
  for (int i = tid; i < TRG * WG * 2; i += 512) lt[i] = 0.f;
  __syncthreads();
  const float* mvy = mvf + ((size_t)(p * 2 + 0) * ZT + z) * HW2;
  const float* mvx = mvy + (size_t)ZT * HW2;
  const float2* g = gw + (size_t)pz * HW2;
  const size_t xbase = (size_t)(p * ZT + z) * HW2;
  int wlo = max(R - HAG, 0), whi = min(R + TRG + HAG, HG);
  int npx = (whi - wlo) * WG;
  int base0 = wlo * WG;
  // software-pipelined scan
  int i = tid;
  float fy = 0.f, fx = 0.f; float2 gv = make_float2(0.f, 0.f);
  if (i < npx){ fy = mvy[base0 + i]; fx = mvx[base0 + i]; gv = g[base0 + i]; }
  while (i < npx){
    int inx = i + 512;
    float fy2 = 0.f, fx2 = 0.f; float2 gv2 = make_float2(0.f, 0.f);
    if (inx < npx){ fy2 = mvy[base0 + inx]; fx2 = mvx[base0 + inx]; gv2 = g[base0 + inx]; }
    int hh = i / WG; int w = i - hh * WG;
    int h = wlo + hh;
    float gy = fminf(fmaxf((float)h + fy, 0.f), 319.f);
    float gx = fminf(fmaxf((float)w + fx, 0.f), 319.f);
    int y0, x0, y1, x1; float w00, w01, w10, w11;
    corners(gy, gx, y0, x0, y1, x1, w00, w01, w10, w11);
    bool owner = (h >= R) && (h < R + TRG);
    #define PROC(Y, XC, WT) { \
      int ry = (Y) - R; \
      if ((unsigned)ry < (unsigned)TRG){ \
        atomicAdd(&lt[(ry * WG + (XC)) * 2 + 0], gv.x * (WT)); \
        atomicAdd(&lt[(ry * WG + (XC)) * 2 + 1], gv.y * (WT)); \
      } else if (owner){ \
        int Ry = (Y) & ~(TRG - 1); \
        if (h < Ry - HAG || h >= Ry + TRG + HAG){ \
          unsigned slot = atomicAdd(fbcnt, 1u); \
          if (slot < FBCAP) fb[slot] = make_uint4((unsigned)(xbase + (size_t)(Y) * WG + (XC)), \
                                                  __float_as_uint(gv.x * (WT)), __float_as_uint(gv.y * (WT)), 0u); \
        } \
      } \
    }
    PROC(y0, x0, w00); PROC(y0, x1, w01); PROC(y1, x0, w10); PROC(y1, x1, w11);
    #undef PROC
    i = inx; fy = fy2; fx = fx2; gv = gv2;
  }
  __syncthreads();
  float s = stdp[0];
  const float2* gt = gtv + (size_t)pz * HW2;
  for (int i2 = tid; i2 < TRG * WG; i2 += 512){
    int yy = i2 / WG; int w = i2 - yy * WG;
    int hw = (R + yy) * WG + w;
    float2 xv = x[xbase + hw];
    float2 tv = gt[hw];
    xv.x -= GAMMA_C * lt[i2 * 2 + 0] + TAU_C * s * tv.x;
    xv.y -= GAMMA_C * lt[i2 * 2 + 1] + TAU_C * s * tv.y;
    x[xbase + hw] = xv;
  }
}

// apply rare out-of-halo contributions: x[idx] -= GAMMA * val
__global__ __launch_bounds__(256) void k_fixup(const uint4* __restrict__ fb, const unsigned int* __restrict__ fbcnt,
                                               float2* __restrict__ x){
  unsigned n = *fbcnt; if (n > FBCAP) n = FBCAP;
  for (unsigned i = blockIdx.x * 256 + threadIdx.x; i < n; i += gridDim.x * 256){
    uint4 e = fb[i];
    atomicAdd(&x[e.x].x, -GAMMA_C * __uint_as_float(e.y));
    atomicAdd(&x[e.x].y, -GAMMA_C * __uint_as_float(e.z));
  }
}

// ---------------- host ----------------
extern "C" void kernel_launch(void* const* d_in, const int* in_sizes, int n_in,
                              void* d_out, int out_size, void* d_ws, size_t ws_size,
                              hipStream_t stream) {
  const float2* kdata = (const float2*)d_in[0];
  const float*  traj  = (const float*) d_in[1];
  const float2* img0  = (const float2*)d_in[2];
  const float*  mvf   = (const float*) d_in[3];
  const float2* csm   = (const float2*)d_in[4];
  const float*  stdp  = (const float*) d_in[5];
  float2* x = (float2*)d_out;

  const size_t F_B  = (size_t)CHN * ZE * HW2 * 8;        // 39,321,600
  const size_t W_B  = (size_t)PH * ZE * HW2 * 8;         // 19,660,800
  const size_t E_B  = (size_t)PH * CHN * ZE * NKP * 8;   //  6,291,456
  const size_t FB_B = (size_t)FBCAP * 16;                //  2,097,152

  // big path: F holds all 4 phases (157 MB); small path: per-phase loop (39 MB)
  size_t need_big = 4 * F_B + 2 * W_B + E_B + 512 + FB_B;   // ~205 MB
  const int NP = (ws_size >= need_big) ? 4 : 1;

  char* cur = (char*)d_ws;
  float2* F      = (float2*)cur;  cur += (size_t)NP * F_B;
  float2* warped = (float2*)cur;  cur += W_B;              // also holds gwarped
  float2* est    = (float2*)cur;  cur += E_B;
  float2* gtvb   = (float2*)cur;  cur += W_B;
  unsigned int* dmax  = (unsigned int*)cur; cur += 128;
  unsigned int* fbcnt = (unsigned int*)cur; cur += 128;
  uint4* fb           = (uint4*)cur;

  k_init<<<12800, 256, 0, stream>>>(img0, x, PH * ZT * HW2);

  for (int it = 0; it < 3; it++){
    k_warp_tv<<<9600, 256, 0, stream>>>(x, mvf, warped, gtvb);
    hipMemsetAsync(dmax, 0, 4, stream);
    for (int p0 = 0; p0 < PH; p0 += NP){
      k_fft_row_fwd<<<NP * 3840, 256, 0, stream>>>(warped, csm, F, p0);
      k_fft_col    <<<NP *  960, 256, 0, stream>>>(F);
      k_sample     <<<NP *  768, 256, 0, stream>>>(F, traj, est, dmax, p0);
    }
    k_weights<<<3072, 256, 0, stream>>>(est, kdata, dmax);
    for (int p0 = 0; p0 < PH; p0 += NP){
      k_fft_col_scatter<<<NP *  960, 256, 0, stream>>>(est, traj, F, p0);
      k_fft_row_bwd    <<<NP * 1920, 512, 0, stream>>>(F, csm, warped, p0);
    }
    hipMemsetAsync(fbcnt, 0, 4, stream);
    k_warpadj_update<<<960, 512, 0, stream>>>(warped, mvf, gtvb, stdp, x, fb, fbcnt);
    k_fixup<<<16, 256, 0, stream>>>(fb, fbcnt, x);
  }
}

// Round 8
// 1988.172 us; speedup vs baseline: 1.6741x; 1.0187x over previous
//
#include <hip/hip_runtime.h>
#include <math.h>

// ---------------- problem constants ----------------
#define PH   4
#define CHN  8
#define ZT   8
#define ZE   6          // effective z slices: z in [1,7)
#define HG   320
#define WG   320
#define HW2  102400     // 320*320
#define NKP  4096
#define LSTR 321        // LDS line stride (pad +1)
#define FBCAP 131072u   // fallback list capacity (entries)

constexpr float GAMMA_C = 0.1f;
constexpr float TAU_C   = 0.2f;
constexpr float EPS_C   = 0.01f;
constexpr float INV_N   = 1.0f / 786432.0f;   // PH*CHN*ZE*NKP
#define TWO_PI_F 6.28318530717958647692f

// W5^j = e^{-2*pi*i*j/5}
constexpr float W5R[5] = { 1.f,  0.30901699f, -0.80901699f, -0.80901699f,  0.30901699f};
constexpr float W5I[5] = { 0.f, -0.95105652f, -0.58778525f,  0.58778525f,  0.95105652f};

// ---------------- complex helpers ----------------
__device__ __forceinline__ float2 cmul(float2 a, float2 b){
  return make_float2(a.x*b.x - a.y*b.y, a.x*b.y + a.y*b.x);
}
__device__ __forceinline__ void cmac(float2& d, float2 a, float2 b){
  d.x = fmaf(a.x, b.x, fmaf(-a.y, b.y, d.x));
  d.y = fmaf(a.x, b.y, fmaf( a.y, b.x, d.y));
}

__device__ __forceinline__ void corners(float gy, float gx, int& y0, int& x0, int& y1, int& x1,
                                        float& w00, float& w01, float& w10, float& w11){
  float y0f = floorf(gy), x0f = floorf(gx);
  float wy = gy - y0f, wx = gx - x0f;
  y0 = (int)y0f; x0 = (int)x0f;
  y1 = min(y0 + 1, HG - 1); x1 = min(x0 + 1, WG - 1);
  w00 = (1.f - wy) * (1.f - wx);
  w01 = (1.f - wy) * wx;
  w10 = wy * (1.f - wx);
  w11 = wy * wx;
}

__device__ __forceinline__ void traj_to_grid(float ty, float tx, float& gy, float& gx){
  gy = fminf(fmaxf((ty / TWO_PI_F + 0.5f) * 320.f, 0.f), 319.f);
  gx = fminf(fmaxf((tx / TWO_PI_F + 0.5f) * 320.f, 0.f), 319.f);
}

// ---------------- in-register 320-pt FFT: one wave per line, N = 5 x 64 ----------------
// (verified rounds 5-7). Lane l stores X[5*br6(l)+r]; un-permuted via LDS seg.
struct FT {
  float2 t1, t2, t3, t4;
  float2 tw0, tw1, tw2, tw3, tw4;
  int br5, lane;
};

__device__ __forceinline__ FT ft_init(){
  FT f; int l = (int)(threadIdx.x & 63); f.lane = l;
  sincosf(-TWO_PI_F * (float)l * (1.0f/320.0f), &f.t1.y, &f.t1.x);
  f.t2 = cmul(f.t1, f.t1); f.t3 = cmul(f.t2, f.t1); f.t4 = cmul(f.t2, f.t2);
  sincosf(-TWO_PI_F * (float)(l & 31) * (1.0f/64.0f), &f.tw0.y, &f.tw0.x);
  sincosf(-TWO_PI_F * (float)(l & 15) * (1.0f/32.0f), &f.tw1.y, &f.tw1.x);
  sincosf(-TWO_PI_F * (float)(l &  7) * (1.0f/16.0f), &f.tw2.y, &f.tw2.x);
  sincosf(-TWO_PI_F * (float)(l &  3) * (1.0f/ 8.0f), &f.tw3.y, &f.tw3.x);
  f.tw4 = (l & 1) ? make_float2(0.f, -1.f) : make_float2(1.f, 0.f);
  int br = ((l&1)<<5) | ((l&2)<<3) | ((l&4)<<1) | ((l&8)>>1) | ((l&16)>>3) | ((l&32)>>5);
  f.br5 = 5 * br;
  return f;
}

template<int H>
__device__ __forceinline__ void bfly(float2& v, float2 tw, int lane){
  float px = __shfl_xor(v.x, H, 64);
  float py = __shfl_xor(v.y, H, 64);
  bool up = (lane & H) != 0;
  float ax = up ? px : v.x, ay = up ? py : v.y;
  float bx = up ? v.x : px, by = up ? v.y : py;
  float dx = ax - bx,  dy = ay - by;
  float mx = fmaf(dx, tw.x, -dy * tw.y);
  float my = fmaf(dx, tw.y,  dy * tw.x);
  v.x = up ? mx : (ax + bx);
  v.y = up ? my : (ay + by);
}

__device__ __forceinline__ void fft320w(const float2 a[5], const FT& f, float2* __restrict__ seg){
  float2 z[5];
  #pragma unroll
  for (int r = 0; r < 5; r++){
    float2 acc = a[0];
    #pragma unroll
    for (int q = 1; q < 5; q++){
      const int j = (q * r) % 5;
      cmac(acc, a[q], make_float2(W5R[j], W5I[j]));
    }
    z[r] = acc;
  }
  z[1] = cmul(z[1], f.t1); z[2] = cmul(z[2], f.t2);
  z[3] = cmul(z[3], f.t3); z[4] = cmul(z[4], f.t4);
  #pragma unroll
  for (int r = 0; r < 5; r++){
    float2 v = z[r];
    bfly<32>(v, f.tw0, f.lane);
    bfly<16>(v, f.tw1, f.lane);
    bfly< 8>(v, f.tw2, f.lane);
    bfly< 4>(v, f.tw3, f.lane);
    bfly< 2>(v, f.tw4, f.lane);
    {
      float px = __shfl_xor(v.x, 1, 64);
      float py = __shfl_xor(v.y, 1, 64);
      bool up = (f.lane & 1) != 0;
      float ax = up ? px : v.x, ay = up ? py : v.y;
      float bx = up ? v.x : px, by = up ? v.y : py;
      v.x = up ? (ax - bx) : (ax + bx);
      v.y = up ? (ay - by) : (ay + by);
    }
    seg[f.br5 + r] = v;
  }
}

// ---------------- k-point sorting (once per call; traj constant across iterations) ----------
__global__ __launch_bounds__(256) void k_khist(const float* __restrict__ traj, unsigned* __restrict__ yhist,
                                               unsigned* __restrict__ xhist){
  int gid = blockIdx.x * 256 + threadIdx.x;
  if (gid >= PH * NKP) return;
  int p = gid >> 12, k = gid & (NKP - 1);
  float gy, gx;
  traj_to_grid(traj[(p * 2 + 0) * NKP + k], traj[(p * 2 + 1) * NKP + k], gy, gx);
  atomicAdd(&yhist[p * HG + (int)floorf(gy)], 1u);
  atomicAdd(&xhist[p * WG + (int)floorf(gx)], 1u);
}

__global__ void k_kscan(const unsigned* __restrict__ yhist, const unsigned* __restrict__ xhist,
                        unsigned* __restrict__ ycur, unsigned* __restrict__ xcur, unsigned* __restrict__ xbnd){
  int t = threadIdx.x;
  if (t < PH){
    unsigned acc = 0;
    for (int b = 0; b < HG; b++){ ycur[t * HG + b] = acc; acc += yhist[t * HG + b]; }
  } else if (t < 2 * PH){
    int p = t - PH; unsigned acc = 0;
    for (int b = 0; b < WG; b++){ xcur[p * WG + b] = acc; xbnd[p * (WG + 1) + b] = acc; acc += xhist[p * WG + b]; }
    xbnd[p * (WG + 1) + WG] = acc;
  }
}

__global__ __launch_bounds__(256) void k_kperm(const float* __restrict__ traj, unsigned* __restrict__ ycur,
                                               unsigned* __restrict__ xcur, float4* __restrict__ permy,
                                               float4* __restrict__ permx){
  int gid = blockIdx.x * 256 + threadIdx.x;
  if (gid >= PH * NKP) return;
  int p = gid >> 12, k = gid & (NKP - 1);
  float gy, gx;
  traj_to_grid(traj[(p * 2 + 0) * NKP + k], traj[(p * 2 + 1) * NKP + k], gy, gx);
  float4 e = make_float4(__uint_as_float((unsigned)k), gy, gx, 0.f);
  unsigned sy = atomicAdd(&ycur[p * HG + (int)floorf(gy)], 1u);
  permy[p * NKP + sy] = e;
  unsigned sx = atomicAdd(&xcur[p * WG + (int)floorf(gx)], 1u);
  permx[p * NKP + sx] = e;
}

// ---------------- kernels ----------------
__global__ __launch_bounds__(256) void k_init(const float2* __restrict__ img0, float2* __restrict__ x, int n){
  int i = blockIdx.x * 256 + threadIdx.x;
  if (i < n){
    float2 v = img0[i];
    v.x = isnan(v.x) ? 0.f : fminf(fmaxf(v.x, -3.4028235e38f), 3.4028235e38f);
    v.y = isnan(v.y) ? 0.f : fminf(fmaxf(v.y, -3.4028235e38f), 3.4028235e38f);
    x[i] = v;
  }
}

// fused: warped = bilinear-warp(x, mvf); gtv = conj(TV-grad(x))
__global__ __launch_bounds__(256) void k_warp_tv(const float2* __restrict__ x, const float* __restrict__ mvf,
                                                 float2* __restrict__ warped, float2* __restrict__ gtv){
  int gid = blockIdx.x * 256 + threadIdx.x;          // over PH*ZE*HW2
  int hw = gid % HW2;
  int pz = gid / HW2;
  int zz = pz % ZE, p = pz / ZE, z = zz + 1;
  int h = hw / WG, w = hw - h * WG;
  const float* mv = mvf + ((size_t)(p * 2 + 0) * ZT + z) * HW2;
  float fy = mv[hw];
  float fx = mv[(size_t)ZT * HW2 + hw];
  float gy = fminf(fmaxf((float)h + fy, 0.f), 319.f);
  float gx = fminf(fmaxf((float)w + fx, 0.f), 319.f);
  int y0, x0, y1, x1; float w00, w01, w10, w11;
  corners(gy, gx, y0, x0, y1, x1, w00, w01, w10, w11);
  const float2* xs = x + (size_t)(p * ZT + z) * HW2;
  float2 v00 = xs[y0 * WG + x0], v01 = xs[y0 * WG + x1];
  float2 v10 = xs[y1 * WG + x0], v11 = xs[y1 * WG + x1];
  float2 o;
  o.x = v00.x * w00 + v01.x * w01 + v10.x * w10 + v11.x * w11;
  o.y = v00.y * w00 + v01.y * w01 + v10.y * w10 + v11.y * w11;
  warped[gid] = o;
  // TV gradient
  float2 xc = xs[hw];
  float tre = 0.f, tim = 0.f;
  if (h > 0){
    float2 n = xs[hw - WG];
    float dr = xc.x - n.x, di = xc.y - n.y;
    float r = sqrtf(dr * dr + di * di + 1e-8f);
    tre += dr / r; tim += di / r;
  }
  if (h < HG - 1){
    float2 n = xs[hw + WG];
    float dr = n.x - xc.x, di = n.y - xc.y;
    float r = sqrtf(dr * dr + di * di + 1e-8f);
    tre -= dr / r; tim -= di / r;
  }
  if (w > 0){
    float2 n = xs[hw - 1];
    float dr = xc.x - n.x, di = xc.y - n.y;
    float r = sqrtf(dr * dr + di * di + 1e-8f);
    tre += dr / r; tim += di / r;
  }
  if (w < WG - 1){
    float2 n = xs[hw + 1];
    float dr = n.x - xc.x, di = n.y - xc.y;
    float r = sqrtf(dr * dr + di * di + 1e-8f);
    tre -= dr / r; tim -= di / r;
  }
  gtv[gid] = make_float2(tre, -tim);
}

// row FFT forward, phases batched: lineid over np*CHN*ZE*HG
__global__ __launch_bounds__(256) void k_fft_row_fwd(const float2* __restrict__ warped, const float2* __restrict__ csm,
                                                     float2* __restrict__ F, int p0){
  __shared__ float2 seg[4 * LSTR];
  FT f = ft_init();
  int wid = threadIdx.x >> 6, l = f.lane;
  int lineid = blockIdx.x * 4 + wid;
  int pp = lineid / (CHN * ZE * HG); int rem = lineid - pp * (CHN * ZE * HG);
  int c = rem / (ZE * HG); rem -= c * (ZE * HG);
  int zz = rem / HG; int h = rem - zz * HG; int z = zz + 1;
  int p = p0 + pp;
  const float2* wr = warped + ((size_t)(p * ZE + zz)) * HW2 + (size_t)h * WG;
  const float2* cs = csm + ((size_t)(c * ZT + z)) * HW2 + (size_t)h * WG;
  float sgn = ((h + l) & 1) ? -1.f : 1.f;
  float2 a[5];
  #pragma unroll
  for (int q = 0; q < 5; q++){
    float2 v = cmul(wr[64 * q + l], cs[64 * q + l]);
    a[q] = make_float2(v.x * sgn, v.y * sgn);
  }
  float2* sg = seg + wid * LSTR;
  fft320w(a, f, sg);
  __syncthreads();
  float2* out = F + ((size_t)((pp * CHN + c) * ZE + zz)) * HW2 + (size_t)h * WG;
  #pragma unroll
  for (int q = 0; q < 5; q++) out[64 * q + l] = sg[64 * q + l];
}

// column FFT, in place; slice index local to this dispatch's F window
__global__ __launch_bounds__(256) void k_fft_col(float2* __restrict__ F){
  __shared__ float2 ld[16 * LSTR];
  FT f = ft_init();
  int tid = threadIdx.x; int wid = tid >> 6, l = f.lane;
  int cg = blockIdx.x % 20; int s = blockIdx.x / 20;
  float2* Fs = F + (size_t)s * HW2 + cg * 16;
  for (int i = tid; i < 5120; i += 256){ int h = i >> 4, col = i & 15; ld[col * LSTR + h] = Fs[h * WG + col]; }
  __syncthreads();
  #pragma unroll
  for (int cc = 0; cc < 4; cc++){
    float2* base = ld + (wid * 4 + cc) * LSTR;
    float2 a[5];
    #pragma unroll
    for (int q = 0; q < 5; q++) a[q] = base[64 * q + l];
    fft320w(a, f, base);
  }
  __syncthreads();
  for (int i = tid; i < 5120; i += 256){ int h = i >> 4, col = i & 15; Fs[h * WG + col] = ld[col * LSTR + h]; }
}

// sample: y-sorted k order for cacheline locality; (k,gy,gx) precomputed
__global__ __launch_bounds__(256) void k_sample(const float2* __restrict__ F, const float4* __restrict__ permy,
                                                float2* __restrict__ est, unsigned int* __restrict__ dmax, int p0){
  int gid = blockIdx.x * 256 + threadIdx.x;     // over np*CHN*ZE*NKP
  int sk = gid & (NKP - 1);
  int t = gid >> 12;                            // local slice (pp,c,zz)
  int t2 = t / ZE; int pp = t2 / CHN;
  int p = p0 + pp;
  float4 e4 = permy[p * NKP + sk];
  int k = (int)__float_as_uint(e4.x);
  int y0, x0, y1, x1; float w00, w01, w10, w11;
  corners(e4.y, e4.z, y0, x0, y1, x1, w00, w01, w10, w11);
  const float2* Fs = F + (size_t)t * HW2;
  float2 v00 = Fs[y0 * WG + x0], v01 = Fs[y0 * WG + x1];
  float2 v10 = Fs[y1 * WG + x0], v11 = Fs[y1 * WG + x1];
  float2 e;
  e.x = v00.x * w00 + v01.x * w01 + v10.x * w10 + v11.x * w11;
  e.y = v00.y * w00 + v01.y * w01 + v10.y * w10 + v11.y * w11;
  est[((size_t)(p0 * CHN * ZE) + t) * NKP + k] = e;
  float d2 = e.x * e.x + e.y * e.y;
  for (int off = 32; off > 0; off >>= 1) d2 = fmaxf(d2, __shfl_down(d2, off, 64));
  if ((threadIdx.x & 63) == 0) atomicMax(dmax, __float_as_uint(d2));
}

// est -> cotangent: G = (w^2/N) * conj(est - y)
__global__ __launch_bounds__(256) void k_weights(float2* __restrict__ est, const float2* __restrict__ kdata,
                                                 const unsigned int* __restrict__ dmax){
  int gid = blockIdx.x * 256 + threadIdx.x;     // over PH*CHN*ZE*NKP
  int k = gid & (NKP - 1);
  int t = gid >> 12;
  int zz = t % ZE; int pc = t / ZE; int z = zz + 1;
  float md = sqrtf(__uint_as_float(*dmax));
  float2 e = est[gid];
  float det = sqrtf(e.x * e.x + e.y * e.y);
  float wv = 1.0f / (det / md + EPS_C);
  float sc = wv * wv * INV_N;
  float2 y = kdata[((size_t)pc * ZT + z) * NKP + k];
  est[gid] = make_float2(sc * (e.x - y.x), -sc * (e.y - y.y));
}

// backward: fused { zero tile + x-bucketed corner scatter (LDS atomics) + per-wave column DFT^T }
__global__ __launch_bounds__(256) void k_fft_col_scatter(const float2* __restrict__ G, const float4* __restrict__ permx,
                                                         const unsigned* __restrict__ xbnd,
                                                         float2* __restrict__ F, int p0){
  __shared__ float2 ld[16 * LSTR];
  FT f = ft_init();
  int tid = threadIdx.x; int wid = tid >> 6, l = f.lane;
  int cg = blockIdx.x % 20; int sl = blockIdx.x / 20;       // local slice
  int s2 = sl / ZE; int pp = s2 / CHN;
  int p = p0 + pp;
  for (int i = tid; i < 16 * LSTR; i += 256) ld[i] = make_float2(0.f, 0.f);
  __syncthreads();
  int cbase = cg * 16;
  // x0 in [cbase-1, cbase+16) covers every k whose corner columns intersect this window
  int lo = (cbase > 0) ? (int)xbnd[p * (WG + 1) + cbase - 1] : 0;
  int hi = (int)xbnd[p * (WG + 1) + min(cbase + 16, WG)];
  const float2* Gs = G + ((size_t)(p0 * CHN * ZE) + sl) * NKP;
  for (int j = lo + tid; j < hi; j += 256){
    float4 e4 = permx[p * NKP + j];
    int k = (int)__float_as_uint(e4.x);
    int y0, x0, y1, x1; float w00, w01, w10, w11;
    corners(e4.y, e4.z, y0, x0, y1, x1, w00, w01, w10, w11);
    float2 gv = Gs[k];
    int c0 = x0 - cbase, c1 = x1 - cbase;
    if ((unsigned)c0 < 16u){
      atomicAdd(&ld[c0 * LSTR + y0].x, gv.x * w00); atomicAdd(&ld[c0 * LSTR + y0].y, gv.y * w00);
      atomicAdd(&ld[c0 * LSTR + y1].x, gv.x * w10); atomicAdd(&ld[c0 * LSTR + y1].y, gv.y * w10);
    }
    if ((unsigned)c1 < 16u){
      atomicAdd(&ld[c1 * LSTR + y0].x, gv.x * w01); atomicAdd(&ld[c1 * LSTR + y0].y, gv.y * w01);
      atomicAdd(&ld[c1 * LSTR + y1].x, gv.x * w11); atomicAdd(&ld[c1 * LSTR + y1].y, gv.y * w11);
    }
  }
  __syncthreads();
  #pragma unroll
  for (int cc = 0; cc < 4; cc++){
    float2* base = ld + (wid * 4 + cc) * LSTR;
    float2 a[5];
    #pragma unroll
    for (int q = 0; q < 5; q++) a[q] = base[64 * q + l];
    fft320w(a, f, base);
  }
  __syncthreads();
  float2* Fs = F + (size_t)sl * HW2 + cbase;
  for (int i = tid; i < 5120; i += 256){ int h = i >> 4, col = i & 15; Fs[h * WG + col] = ld[col * LSTR + h]; }
}

// transpose row pass: 8 waves = 8 coils of one (pp,zz,h) row; epilogue *(-1)^(h+w), *csm, coil sum
__global__ __launch_bounds__(512) void k_fft_row_bwd(const float2* __restrict__ F, const float2* __restrict__ csm,
                                                     float2* __restrict__ gwarped, int p0){
  __shared__ float2 seg[8 * LSTR];
  FT f = ft_init();
  int tid = threadIdx.x; int c = tid >> 6, l = f.lane;
  int bid = blockIdx.x;                          // over np*ZE*HG
  int h = bid % HG; int b2 = bid / HG;
  int zz = b2 % ZE; int pp = b2 / ZE;
  int p = p0 + pp; int z = zz + 1;
  const float2* Fl = F + ((size_t)((pp * CHN + c) * ZE + zz)) * HW2 + (size_t)h * WG;
  float2 a[5];
  #pragma unroll
  for (int q = 0; q < 5; q++) a[q] = Fl[64 * q + l];
  fft320w(a, f, seg + c * LSTR);
  __syncthreads();
  if (tid < WG){
    int w = tid;
    float2 acc = make_float2(0.f, 0.f);
    #pragma unroll
    for (int cc = 0; cc < 8; cc++){
      cmac(acc, seg[cc * LSTR + w], csm[((size_t)(cc * ZT + z)) * HW2 + (size_t)h * WG + w]);
    }
    float sg = ((h + w) & 1) ? -1.f : 1.f;
    gwarped[((size_t)(p * ZE + zz)) * HW2 + (size_t)h * WG + w] = make_float2(acc.x * sg, acc.y * sg);
  }
}

// ---------------- gather-tiled warp adjoint + fused gradient update ----------------
#define TRG 8
#define HAG 8
__global__ __launch_bounds__(512) void k_warpadj_update(const float2* __restrict__ gw, const float* __restrict__ mvf,
                                                        const float2* __restrict__ gtv, const float* __restrict__ stdp,
                                                        float2* __restrict__ x,
                                                        uint4* __restrict__ fb, unsigned int* __restrict__ fbcnt){
  __shared__ float lt[TRG * WG * 2];   // 20480 B
  int tid = threadIdx.x;
  int bid = blockIdx.x;                    // pz*40 + tile
  int tile = bid % 40; int pz = bid / 40;
  int zz = pz % ZE, p = pz / ZE, z = zz + 1;
  int R = tile * TRG;
  for (int i = tid; i < TRG * WG * 2; i += 512) lt[i] = 0.f;
  __syncthreads();
  const float* mvy = mvf + ((size_t)(p * 2 + 0) * ZT + z) * HW2;
  const float* mvx = mvy + (size_t)ZT * HW2;
  const float2* g = gw + (size_t)pz * HW2;
  const size_t xbase = (size_t)(p * ZT + z) * HW2;
  int wlo = max(R - HAG, 0), whi = min(R + TRG + HAG, HG);
  int npx = (whi - wlo) * WG;
  int base0 = wlo * WG;
  int i = tid;
  float fy = 0.f, fx = 0.f; float2 gv = make_float2(0.f, 0.f);
  if (i < npx){ fy = mvy[base0 + i]; fx = mvx[base0 + i]; gv = g[base0 + i]; }
  while (i < npx){
    int inx = i + 512;
    float fy2 = 0.f, fx2 = 0.f; float2 gv2 = make_float2(0.f, 0.f);
    if (inx < npx){ fy2 = mvy[base0 + inx]; fx2 = mvx[base0 + inx]; gv2 = g[base0 + inx]; }
    int hh = i / WG; int w = i - hh * WG;
    int h = wlo + hh;
    float gy = fminf(fmaxf((float)h + fy, 0.f), 319.f);
    float gx = fminf(fmaxf((float)w + fx, 0.f), 319.f);
    int y0, x0, y1, x1; float w00, w01, w10, w11;
    corners(gy, gx, y0, x0, y1, x1, w00, w01, w10, w11);
    bool owner = (h >= R) && (h < R + TRG);
    #define PROC(Y, XC, WT) { \
      int ry = (Y) - R; \
      if ((unsigned)ry < (unsigned)TRG){ \
        atomicAdd(&lt[(ry * WG + (XC)) * 2 + 0], gv.x * (WT)); \
        atomicAdd(&lt[(ry * WG + (XC)) * 2 + 1], gv.y * (WT)); \
      } else if (owner){ \
        int Ry = (Y) & ~(TRG - 1); \
        if (h < Ry - HAG || h >= Ry + TRG + HAG){ \
          unsigned slot = atomicAdd(fbcnt, 1u); \
          if (slot < FBCAP) fb[slot] = make_uint4((unsigned)(xbase + (size_t)(Y) * WG + (XC)), \
                                                  __float_as_uint(gv.x * (WT)), __float_as_uint(gv.y * (WT)), 0u); \
        } \
      } \
    }
    PROC(y0, x0, w00); PROC(y0, x1, w01); PROC(y1, x0, w10); PROC(y1, x1, w11);
    #undef PROC
    i = inx; fy = fy2; fx = fx2; gv = gv2;
  }
  __syncthreads();
  float s = stdp[0];
  const float2* gt = gtv + (size_t)pz * HW2;
  for (int i2 = tid; i2 < TRG * WG; i2 += 512){
    int yy = i2 / WG; int w = i2 - yy * WG;
    int hw = (R + yy) * WG + w;
    float2 xv = x[xbase + hw];
    float2 tv = gt[hw];
    xv.x -= GAMMA_C * lt[i2 * 2 + 0] + TAU_C * s * tv.x;
    xv.y -= GAMMA_C * lt[i2 * 2 + 1] + TAU_C * s * tv.y;
    x[xbase + hw] = xv;
  }
}

// apply rare out-of-halo contributions: x[idx] -= GAMMA * val
__global__ __launch_bounds__(256) void k_fixup(const uint4* __restrict__ fb, const unsigned int* __restrict__ fbcnt,
                                               float2* __restrict__ x){
  unsigned n = *fbcnt; if (n > FBCAP) n = FBCAP;
  for (unsigned i = blockIdx.x * 256 + threadIdx.x; i < n; i += gridDim.x * 256){
    uint4 e = fb[i];
    atomicAdd(&x[e.x].x, -GAMMA_C * __uint_as_float(e.y));
    atomicAdd(&x[e.x].y, -GAMMA_C * __uint_as_float(e.z));
  }
}

// ---------------- host ----------------
extern "C" void kernel_launch(void* const* d_in, const int* in_sizes, int n_in,
                              void* d_out, int out_size, void* d_ws, size_t ws_size,
                              hipStream_t stream) {
  const float2* kdata = (const float2*)d_in[0];
  const float*  traj  = (const float*) d_in[1];
  const float2* img0  = (const float2*)d_in[2];
  const float*  mvf   = (const float*) d_in[3];
  const float2* csm   = (const float2*)d_in[4];
  const float*  stdp  = (const float*) d_in[5];
  float2* x = (float2*)d_out;

  const size_t F_B  = (size_t)CHN * ZE * HW2 * 8;        // 39,321,600
  const size_t W_B  = (size_t)PH * ZE * HW2 * 8;         // 19,660,800
  const size_t E_B  = (size_t)PH * CHN * ZE * NKP * 8;   //  6,291,456
  const size_t FB_B = (size_t)FBCAP * 16;                //  2,097,152
  const size_t P_B  = (size_t)PH * NKP * 16;             //    262,144 (per perm)
  const size_t SORT_B = 2 * P_B + 6 * 8192;              // perms + hist/cursor/bnd

  size_t need_big = 4 * F_B + 2 * W_B + E_B + 512 + FB_B + SORT_B;   // ~206 MB
  const int NP = (ws_size >= need_big) ? 4 : 1;

  char* cur = (char*)d_ws;
  float2* F      = (float2*)cur;  cur += (size_t)NP * F_B;
  float2* warped = (float2*)cur;  cur += W_B;              // also holds gwarped
  float2* est    = (float2*)cur;  cur += E_B;
  float2* gtvb   = (float2*)cur;  cur += W_B;
  unsigned int* dmax  = (unsigned int*)cur; cur += 128;
  unsigned int* fbcnt = (unsigned int*)cur; cur += 128;
  uint4* fb           = (uint4*)cur;        cur += FB_B;
  float4* permy       = (float4*)cur;       cur += P_B;
  float4* permx       = (float4*)cur;       cur += P_B;
  unsigned* yhist     = (unsigned*)cur;     cur += 8192;
  unsigned* xhist     = (unsigned*)cur;     cur += 8192;
  unsigned* ycur      = (unsigned*)cur;     cur += 8192;
  unsigned* xcur      = (unsigned*)cur;     cur += 8192;
  unsigned* xbnd      = (unsigned*)cur;     cur += 8192;

  k_init<<<12800, 256, 0, stream>>>(img0, x, PH * ZT * HW2);
  // build sorted k-point lists (traj is constant across iterations)
  hipMemsetAsync(yhist, 0, 16384, stream);   // yhist + xhist (contiguous)
  k_khist<<<64, 256, 0, stream>>>(traj, yhist, xhist);
  k_kscan<<<1, 64, 0, stream>>>(yhist, xhist, ycur, xcur, xbnd);
  k_kperm<<<64, 256, 0, stream>>>(traj, ycur, xcur, permy, permx);

  for (int it = 0; it < 3; it++){
    k_warp_tv<<<9600, 256, 0, stream>>>(x, mvf, warped, gtvb);
    hipMemsetAsync(dmax, 0, 4, stream);
    for (int p0 = 0; p0 < PH; p0 += NP){
      k_fft_row_fwd<<<NP * 3840, 256, 0, stream>>>(warped, csm, F, p0);
      k_fft_col    <<<NP *  960, 256, 0, stream>>>(F);
      k_sample     <<<NP *  768, 256, 0, stream>>>(F, permy, est, dmax, p0);
    }
    k_weights<<<3072, 256, 0, stream>>>(est, kdata, dmax);
    for (int p0 = 0; p0 < PH; p0 += NP){
      k_fft_col_scatter<<<NP *  960, 256, 0, stream>>>(est, permx, xbnd, F, p0);
      k_fft_row_bwd    <<<NP * 1920, 512, 0, stream>>>(F, csm, warped, p0);
    }
    hipMemsetAsync(fbcnt, 0, 4, stream);
    k_warpadj_update<<<960, 512, 0, stream>>>(warped, mvf, gtvb, stdp, x, fb, fbcnt);
    k_fixup<<<16, 256, 0, stream>>>(fb, fbcnt, x);
  }
}

// Round 9
// 1883.570 us; speedup vs baseline: 1.7671x; 1.0555x over previous
//
#include <hip/hip_runtime.h>
#include <math.h>

// ---------------- problem constants ----------------
#define PH   4
#define CHN  8
#define ZT   8
#define ZE   6          // effective z slices: z in [1,7)
#define HG   320
#define WG   320
#define HW2  102400     // 320*320
#define NKP  4096
#define LSTR 321        // LDS line stride (pad +1)
#define FBCAP 131072u   // fallback list capacity (entries)

constexpr float GAMMA_C = 0.1f;
constexpr float TAU_C   = 0.2f;
constexpr float EPS_C   = 0.01f;
constexpr float INV_N   = 1.0f / 786432.0f;   // PH*CHN*ZE*NKP
#define TWO_PI_F 6.28318530717958647692f

// W5^j = e^{-2*pi*i*j/5}
constexpr float W5R[5] = { 1.f,  0.30901699f, -0.80901699f, -0.80901699f,  0.30901699f};
constexpr float W5I[5] = { 0.f, -0.95105652f, -0.58778525f,  0.58778525f,  0.95105652f};

// ---------------- complex helpers ----------------
__device__ __forceinline__ float2 cmul(float2 a, float2 b){
  return make_float2(a.x*b.x - a.y*b.y, a.x*b.y + a.y*b.x);
}
__device__ __forceinline__ void cmac(float2& d, float2 a, float2 b){
  d.x = fmaf(a.x, b.x, fmaf(-a.y, b.y, d.x));
  d.y = fmaf(a.x, b.y, fmaf( a.y, b.x, d.y));
}

__device__ __forceinline__ void corners(float gy, float gx, int& y0, int& x0, int& y1, int& x1,
                                        float& w00, float& w01, float& w10, float& w11){
  float y0f = floorf(gy), x0f = floorf(gx);
  float wy = gy - y0f, wx = gx - x0f;
  y0 = (int)y0f; x0 = (int)x0f;
  y1 = min(y0 + 1, HG - 1); x1 = min(x0 + 1, WG - 1);
  w00 = (1.f - wy) * (1.f - wx);
  w01 = (1.f - wy) * wx;
  w10 = wy * (1.f - wx);
  w11 = wy * wx;
}

__device__ __forceinline__ void traj_to_grid(float ty, float tx, float& gy, float& gx){
  gy = fminf(fmaxf((ty / TWO_PI_F + 0.5f) * 320.f, 0.f), 319.f);
  gx = fminf(fmaxf((tx / TWO_PI_F + 0.5f) * 320.f, 0.f), 319.f);
}

// ---------------- in-register 320-pt FFT: one wave per line, N = 5 x 64 ----------------
// (verified rounds 5-8). Lane l stores X[5*br6(l)+r]; un-permuted via LDS seg.
struct FT {
  float2 t1, t2, t3, t4;
  float2 tw0, tw1, tw2, tw3, tw4;
  int br5, lane;
};

__device__ __forceinline__ FT ft_init(){
  FT f; int l = (int)(threadIdx.x & 63); f.lane = l;
  sincosf(-TWO_PI_F * (float)l * (1.0f/320.0f), &f.t1.y, &f.t1.x);
  f.t2 = cmul(f.t1, f.t1); f.t3 = cmul(f.t2, f.t1); f.t4 = cmul(f.t2, f.t2);
  sincosf(-TWO_PI_F * (float)(l & 31) * (1.0f/64.0f), &f.tw0.y, &f.tw0.x);
  sincosf(-TWO_PI_F * (float)(l & 15) * (1.0f/32.0f), &f.tw1.y, &f.tw1.x);
  sincosf(-TWO_PI_F * (float)(l &  7) * (1.0f/16.0f), &f.tw2.y, &f.tw2.x);
  sincosf(-TWO_PI_F * (float)(l &  3) * (1.0f/ 8.0f), &f.tw3.y, &f.tw3.x);
  f.tw4 = (l & 1) ? make_float2(0.f, -1.f) : make_float2(1.f, 0.f);
  int br = ((l&1)<<5) | ((l&2)<<3) | ((l&4)<<1) | ((l&8)>>1) | ((l&16)>>3) | ((l&32)>>5);
  f.br5 = 5 * br;
  return f;
}

template<int H>
__device__ __forceinline__ void bfly(float2& v, float2 tw, int lane){
  float px = __shfl_xor(v.x, H, 64);
  float py = __shfl_xor(v.y, H, 64);
  bool up = (lane & H) != 0;
  float ax = up ? px : v.x, ay = up ? py : v.y;
  float bx = up ? v.x : px, by = up ? v.y : py;
  float dx = ax - bx,  dy = ay - by;
  float mx = fmaf(dx, tw.x, -dy * tw.y);
  float my = fmaf(dx, tw.y,  dy * tw.x);
  v.x = up ? mx : (ax + bx);
  v.y = up ? my : (ay + by);
}

__device__ __forceinline__ void fft320w(const float2 a[5], const FT& f, float2* __restrict__ seg){
  float2 z[5];
  #pragma unroll
  for (int r = 0; r < 5; r++){
    float2 acc = a[0];
    #pragma unroll
    for (int q = 1; q < 5; q++){
      const int j = (q * r) % 5;
      cmac(acc, a[q], make_float2(W5R[j], W5I[j]));
    }
    z[r] = acc;
  }
  z[1] = cmul(z[1], f.t1); z[2] = cmul(z[2], f.t2);
  z[3] = cmul(z[3], f.t3); z[4] = cmul(z[4], f.t4);
  #pragma unroll
  for (int r = 0; r < 5; r++){
    float2 v = z[r];
    bfly<32>(v, f.tw0, f.lane);
    bfly<16>(v, f.tw1, f.lane);
    bfly< 8>(v, f.tw2, f.lane);
    bfly< 4>(v, f.tw3, f.lane);
    bfly< 2>(v, f.tw4, f.lane);
    {
      float px = __shfl_xor(v.x, 1, 64);
      float py = __shfl_xor(v.y, 1, 64);
      bool up = (f.lane & 1) != 0;
      float ax = up ? px : v.x, ay = up ? py : v.y;
      float bx = up ? v.x : px, by = up ? v.y : py;
      v.x = up ? (ax - bx) : (ax + bx);
      v.y = up ? (ay - by) : (ay + by);
    }
    seg[f.br5 + r] = v;
  }
}

// ---------------- k-point x-sorting (once per call; traj constant across iterations) --------
__global__ __launch_bounds__(256) void k_khist(const float* __restrict__ traj, unsigned* __restrict__ xhist){
  int gid = blockIdx.x * 256 + threadIdx.x;
  if (gid >= PH * NKP) return;
  int p = gid >> 12, k = gid & (NKP - 1);
  float gy, gx;
  traj_to_grid(traj[(p * 2 + 0) * NKP + k], traj[(p * 2 + 1) * NKP + k], gy, gx);
  atomicAdd(&xhist[p * WG + (int)floorf(gx)], 1u);
}

__global__ void k_kscan(const unsigned* __restrict__ xhist, unsigned* __restrict__ xcur,
                        unsigned* __restrict__ xbnd){
  int p = threadIdx.x;
  if (p < PH){
    unsigned acc = 0;
    for (int b = 0; b < WG; b++){ xcur[p * WG + b] = acc; xbnd[p * (WG + 1) + b] = acc; acc += xhist[p * WG + b]; }
    xbnd[p * (WG + 1) + WG] = acc;
  }
}

__global__ __launch_bounds__(256) void k_kperm(const float* __restrict__ traj, unsigned* __restrict__ xcur,
                                               float4* __restrict__ permx){
  int gid = blockIdx.x * 256 + threadIdx.x;
  if (gid >= PH * NKP) return;
  int p = gid >> 12, k = gid & (NKP - 1);
  float gy, gx;
  traj_to_grid(traj[(p * 2 + 0) * NKP + k], traj[(p * 2 + 1) * NKP + k], gy, gx);
  unsigned sx = atomicAdd(&xcur[p * WG + (int)floorf(gx)], 1u);
  permx[p * NKP + sx] = make_float4(__uint_as_float((unsigned)k), gy, gx, 0.f);
}

// ---------------- kernels ----------------
__global__ __launch_bounds__(256) void k_init(const float2* __restrict__ img0, float2* __restrict__ x, int n){
  int i = blockIdx.x * 256 + threadIdx.x;
  if (i < n){
    float2 v = img0[i];
    v.x = isnan(v.x) ? 0.f : fminf(fmaxf(v.x, -3.4028235e38f), 3.4028235e38f);
    v.y = isnan(v.y) ? 0.f : fminf(fmaxf(v.y, -3.4028235e38f), 3.4028235e38f);
    x[i] = v;
  }
}

// fused: warped = bilinear-warp(x, mvf); gtv = conj(TV-grad(x))
__global__ __launch_bounds__(256) void k_warp_tv(const float2* __restrict__ x, const float* __restrict__ mvf,
                                                 float2* __restrict__ warped, float2* __restrict__ gtv){
  int gid = blockIdx.x * 256 + threadIdx.x;          // over PH*ZE*HW2
  int hw = gid % HW2;
  int pz = gid / HW2;
  int zz = pz % ZE, p = pz / ZE, z = zz + 1;
  int h = hw / WG, w = hw - h * WG;
  const float* mv = mvf + ((size_t)(p * 2 + 0) * ZT + z) * HW2;
  float fy = mv[hw];
  float fx = mv[(size_t)ZT * HW2 + hw];
  float gy = fminf(fmaxf((float)h + fy, 0.f), 319.f);
  float gx = fminf(fmaxf((float)w + fx, 0.f), 319.f);
  int y0, x0, y1, x1; float w00, w01, w10, w11;
  corners(gy, gx, y0, x0, y1, x1, w00, w01, w10, w11);
  const float2* xs = x + (size_t)(p * ZT + z) * HW2;
  float2 v00 = xs[y0 * WG + x0], v01 = xs[y0 * WG + x1];
  float2 v10 = xs[y1 * WG + x0], v11 = xs[y1 * WG + x1];
  float2 o;
  o.x = v00.x * w00 + v01.x * w01 + v10.x * w10 + v11.x * w11;
  o.y = v00.y * w00 + v01.y * w01 + v10.y * w10 + v11.y * w11;
  warped[gid] = o;
  // TV gradient
  float2 xc = xs[hw];
  float tre = 0.f, tim = 0.f;
  if (h > 0){
    float2 n = xs[hw - WG];
    float dr = xc.x - n.x, di = xc.y - n.y;
    float r = sqrtf(dr * dr + di * di + 1e-8f);
    tre += dr / r; tim += di / r;
  }
  if (h < HG - 1){
    float2 n = xs[hw + WG];
    float dr = n.x - xc.x, di = n.y - xc.y;
    float r = sqrtf(dr * dr + di * di + 1e-8f);
    tre -= dr / r; tim -= di / r;
  }
  if (w > 0){
    float2 n = xs[hw - 1];
    float dr = xc.x - n.x, di = xc.y - n.y;
    float r = sqrtf(dr * dr + di * di + 1e-8f);
    tre += dr / r; tim += di / r;
  }
  if (w < WG - 1){
    float2 n = xs[hw + 1];
    float dr = n.x - xc.x, di = n.y - xc.y;
    float r = sqrtf(dr * dr + di * di + 1e-8f);
    tre -= dr / r; tim -= di / r;
  }
  gtv[gid] = make_float2(tre, -tim);
}

// row FFT forward, phases batched: lineid over np*CHN*ZE*HG
__global__ __launch_bounds__(256) void k_fft_row_fwd(const float2* __restrict__ warped, const float2* __restrict__ csm,
                                                     float2* __restrict__ F, int p0){
  __shared__ float2 seg[4 * LSTR];
  FT f = ft_init();
  int wid = threadIdx.x >> 6, l = f.lane;
  int lineid = blockIdx.x * 4 + wid;
  int pp = lineid / (CHN * ZE * HG); int rem = lineid - pp * (CHN * ZE * HG);
  int c = rem / (ZE * HG); rem -= c * (ZE * HG);
  int zz = rem / HG; int h = rem - zz * HG; int z = zz + 1;
  int p = p0 + pp;
  const float2* wr = warped + ((size_t)(p * ZE + zz)) * HW2 + (size_t)h * WG;
  const float2* cs = csm + ((size_t)(c * ZT + z)) * HW2 + (size_t)h * WG;
  float sgn = ((h + l) & 1) ? -1.f : 1.f;
  float2 a[5];
  #pragma unroll
  for (int q = 0; q < 5; q++){
    float2 v = cmul(wr[64 * q + l], cs[64 * q + l]);
    a[q] = make_float2(v.x * sgn, v.y * sgn);
  }
  float2* sg = seg + wid * LSTR;
  fft320w(a, f, sg);
  __syncthreads();
  float2* out = F + ((size_t)((pp * CHN + c) * ZE + zz)) * HW2 + (size_t)h * WG;
  #pragma unroll
  for (int q = 0; q < 5; q++) out[64 * q + l] = sg[64 * q + l];
}

// fused forward: column FFT of 17 columns (16 owned + 1 overlap) in LDS, then sample all
// k-points with x0 in [cbase, cbase+16) straight from LDS. est written in x-sorted (j) order.
// F (row-FFT'd) is READ-ONLY here — the col-FFT'd spectrum never touches HBM.
__global__ __launch_bounds__(256) void k_fft_col_sample(const float2* __restrict__ F, const float4* __restrict__ permx,
                                                        const unsigned* __restrict__ xbnd, float2* __restrict__ est,
                                                        unsigned int* __restrict__ dmax, int p0){
  __shared__ float2 ld[17 * LSTR];   // 43,656 B
  FT f = ft_init();
  int tid = threadIdx.x; int wid = tid >> 6, l = f.lane;
  int cg = blockIdx.x % 20; int sl = blockIdx.x / 20;       // local slice (pp*CHN+c)*ZE+zz
  int s2 = sl / ZE; int pp = s2 / CHN;
  int p = p0 + pp;
  int cbase = cg * 16;
  const int ncol = (cbase + 16 <= WG - 1) ? 17 : 16;
  const float2* Fs = F + (size_t)sl * HW2 + cbase;
  if (ncol == 17){
    for (int i = tid; i < 17 * HG; i += 256){ int h = i / 17, col = i - h * 17; ld[col * LSTR + h] = Fs[h * WG + col]; }
  } else {
    for (int i = tid; i < 16 * HG; i += 256){ int h = i >> 4, col = i & 15; ld[col * LSTR + h] = Fs[h * WG + col]; }
  }
  __syncthreads();
  #pragma unroll
  for (int cc = 0; cc < 5; cc++){
    int col = cc * 4 + wid;
    if (col < ncol){
      float2* base = ld + col * LSTR;
      float2 a[5];
      #pragma unroll
      for (int q = 0; q < 5; q++) a[q] = base[64 * q + l];
      fft320w(a, f, base);
    }
  }
  __syncthreads();
  // sample from LDS
  int lo = (int)xbnd[p * (WG + 1) + cbase];
  int hi = (int)xbnd[p * (WG + 1) + min(cbase + 16, WG)];
  float2* eb = est + ((size_t)(p0 * CHN * ZE) + sl) * NKP;
  const float4* px = permx + p * NKP;
  float md2 = 0.f;
  for (int j = lo + tid; j < hi; j += 256){
    float4 e4 = px[j];
    int y0, x0, y1, x1; float w00, w01, w10, w11;
    corners(e4.y, e4.z, y0, x0, y1, x1, w00, w01, w10, w11);
    int lc0 = x0 - cbase, lc1 = x1 - cbase;
    float2 v00 = ld[lc0 * LSTR + y0], v01 = ld[lc1 * LSTR + y0];
    float2 v10 = ld[lc0 * LSTR + y1], v11 = ld[lc1 * LSTR + y1];
    float2 e;
    e.x = v00.x * w00 + v01.x * w01 + v10.x * w10 + v11.x * w11;
    e.y = v00.y * w00 + v01.y * w01 + v10.y * w10 + v11.y * w11;
    eb[j] = e;
    md2 = fmaxf(md2, e.x * e.x + e.y * e.y);
  }
  for (int off = 32; off > 0; off >>= 1) md2 = fmaxf(md2, __shfl_down(md2, off, 64));
  if ((tid & 63) == 0 && md2 > 0.f) atomicMax(dmax, __float_as_uint(md2));
}

// est (x-sorted order) -> cotangent: G = (w^2/N) * conj(est - y); kdata gathered via permx
__global__ __launch_bounds__(256) void k_weights(float2* __restrict__ est, const float2* __restrict__ kdata,
                                                 const float4* __restrict__ permx,
                                                 const unsigned int* __restrict__ dmax){
  int gid = blockIdx.x * 256 + threadIdx.x;     // over PH*CHN*ZE*NKP (j-order)
  int j = gid & (NKP - 1);
  int t = gid >> 12;                            // (p*CHN+c)*ZE + zz
  int zz = t % ZE; int pc = t / ZE; int z = zz + 1;
  int p = pc / CHN;
  int k = (int)__float_as_uint(permx[p * NKP + j].x);
  float md = sqrtf(__uint_as_float(*dmax));
  float2 e = est[gid];
  float det = sqrtf(e.x * e.x + e.y * e.y);
  float wv = 1.0f / (det / md + EPS_C);
  float sc = wv * wv * INV_N;
  float2 y = kdata[((size_t)pc * ZT + z) * NKP + k];
  est[gid] = make_float2(sc * (e.x - y.x), -sc * (e.y - y.y));
}

// backward: fused { zero tile + x-bucketed corner scatter (LDS atomics, G read contiguous) + col DFT^T }
__global__ __launch_bounds__(256) void k_fft_col_scatter(const float2* __restrict__ G, const float4* __restrict__ permx,
                                                         const unsigned* __restrict__ xbnd,
                                                         float2* __restrict__ F, int p0){
  __shared__ float2 ld[16 * LSTR];
  FT f = ft_init();
  int tid = threadIdx.x; int wid = tid >> 6, l = f.lane;
  int cg = blockIdx.x % 20; int sl = blockIdx.x / 20;       // local slice
  int s2 = sl / ZE; int pp = s2 / CHN;
  int p = p0 + pp;
  for (int i = tid; i < 16 * LSTR; i += 256) ld[i] = make_float2(0.f, 0.f);
  __syncthreads();
  int cbase = cg * 16;
  // x0 in [cbase-1, cbase+16) covers every k whose corner columns intersect this window
  int lo = (cbase > 0) ? (int)xbnd[p * (WG + 1) + cbase - 1] : 0;
  int hi = (int)xbnd[p * (WG + 1) + min(cbase + 16, WG)];
  const float2* Gs = G + ((size_t)(p0 * CHN * ZE) + sl) * NKP;
  const float4* px = permx + p * NKP;
  for (int j = lo + tid; j < hi; j += 256){
    float4 e4 = px[j];
    int y0, x0, y1, x1; float w00, w01, w10, w11;
    corners(e4.y, e4.z, y0, x0, y1, x1, w00, w01, w10, w11);
    float2 gv = Gs[j];
    int c0 = x0 - cbase, c1 = x1 - cbase;
    if ((unsigned)c0 < 16u){
      atomicAdd(&ld[c0 * LSTR + y0].x, gv.x * w00); atomicAdd(&ld[c0 * LSTR + y0].y, gv.y * w00);
      atomicAdd(&ld[c0 * LSTR + y1].x, gv.x * w10); atomicAdd(&ld[c0 * LSTR + y1].y, gv.y * w10);
    }
    if ((unsigned)c1 < 16u){
      atomicAdd(&ld[c1 * LSTR + y0].x, gv.x * w01); atomicAdd(&ld[c1 * LSTR + y0].y, gv.y * w01);
      atomicAdd(&ld[c1 * LSTR + y1].x, gv.x * w11); atomicAdd(&ld[c1 * LSTR + y1].y, gv.y * w11);
    }
  }
  __syncthreads();
  #pragma unroll
  for (int cc = 0; cc < 4; cc++){
    float2* base = ld + (wid * 4 + cc) * LSTR;
    float2 a[5];
    #pragma unroll
    for (int q = 0; q < 5; q++) a[q] = base[64 * q + l];
    fft320w(a, f, base);
  }
  __syncthreads();
  float2* Fs = F + (size_t)sl * HW2 + cbase;
  for (int i = tid; i < 5120; i += 256){ int h = i >> 4, col = i & 15; Fs[h * WG + col] = ld[col * LSTR + h]; }
}

// transpose row pass: 8 waves = 8 coils of one (pp,zz,h) row; epilogue *(-1)^(h+w), *csm, coil sum
__global__ __launch_bounds__(512) void k_fft_row_bwd(const float2* __restrict__ F, const float2* __restrict__ csm,
                                                     float2* __restrict__ gwarped, int p0){
  __shared__ float2 seg[8 * LSTR];
  FT f = ft_init();
  int tid = threadIdx.x; int c = tid >> 6, l = f.lane;
  int bid = blockIdx.x;                          // over np*ZE*HG
  int h = bid % HG; int b2 = bid / HG;
  int zz = b2 % ZE; int pp = b2 / ZE;
  int p = p0 + pp; int z = zz + 1;
  const float2* Fl = F + ((size_t)((pp * CHN + c) * ZE + zz)) * HW2 + (size_t)h * WG;
  float2 a[5];
  #pragma unroll
  for (int q = 0; q < 5; q++) a[q] = Fl[64 * q + l];
  fft320w(a, f, seg + c * LSTR);
  __syncthreads();
  if (tid < WG){
    int w = tid;
    float2 acc = make_float2(0.f, 0.f);
    #pragma unroll
    for (int cc = 0; cc < 8; cc++){
      cmac(acc, seg[cc * LSTR + w], csm[((size_t)(cc * ZT + z)) * HW2 + (size_t)h * WG + w]);
    }
    float sg = ((h + w) & 1) ? -1.f : 1.f;
    gwarped[((size_t)(p * ZE + zz)) * HW2 + (size_t)h * WG + w] = make_float2(acc.x * sg, acc.y * sg);
  }
}

// ---------------- gather-tiled warp adjoint + fused gradient update ----------------
#define TRG 8
#define HAG 8
__global__ __launch_bounds__(512) void k_warpadj_update(const float2* __restrict__ gw, const float* __restrict__ mvf,
                                                        const float2* __restrict__ gtv, const float* __restrict__ stdp,
                                                        float2* __restrict__ x,
                                                        uint4* __restrict__ fb, unsigned int* __restrict__ fbcnt){
  __shared__ float lt[TRG * WG * 2];   // 20480 B
  int tid = threadIdx.x;
  int bid = blockIdx.x;                    // pz*40 + tile
  int tile = bid % 40; int pz = bid / 40;
  int zz = pz % ZE, p = pz / ZE, z = zz + 1;
  int R = tile * TRG;
  for (int i = tid; i < TRG * WG * 2; i += 512) lt[i] = 0.f;
  __syncthreads();
  const float* mvy = mvf + ((size_t)(p * 2 + 0) * ZT + z) * HW2;
  const float* mvx = mvy + (size_t)ZT * HW2;
  const float2* g = gw + (size_t)pz * HW2;
  const size_t xbase = (size_t)(p * ZT + z) * HW2;
  int wlo = max(R - HAG, 0), whi = min(R + TRG + HAG, HG);
  int npx = (whi - wlo) * WG;
  int base0 = wlo * WG;
  int i = tid;
  float fy = 0.f, fx = 0.f; float2 gv = make_float2(0.f, 0.f);
  if (i < npx){ fy = mvy[base0 + i]; fx = mvx[base0 + i]; gv = g[base0 + i]; }
  while (i < npx){
    int inx = i + 512;
    float fy2 = 0.f, fx2 = 0.f; float2 gv2 = make_float2(0.f, 0.f);
    if (inx < npx){ fy2 = mvy[base0 + inx]; fx2 = mvx[base0 + inx]; gv2 = g[base0 + inx]; }
    int hh = i / WG; int w = i - hh * WG;
    int h = wlo + hh;
    float gy = fminf(fmaxf((float)h + fy, 0.f), 319.f);
    float gx = fminf(fmaxf((float)w + fx, 0.f), 319.f);
    int y0, x0, y1, x1; float w00, w01, w10, w11;
    corners(gy, gx, y0, x0, y1, x1, w00, w01, w10, w11);
    bool owner = (h >= R) && (h < R + TRG);
    #define PROC(Y, XC, WT) { \
      int ry = (Y) - R; \
      if ((unsigned)ry < (unsigned)TRG){ \
        atomicAdd(&lt[(ry * WG + (XC)) * 2 + 0], gv.x * (WT)); \
        atomicAdd(&lt[(ry * WG + (XC)) * 2 + 1], gv.y * (WT)); \
      } else if (owner){ \
        int Ry = (Y) & ~(TRG - 1); \
        if (h < Ry - HAG || h >= Ry + TRG + HAG){ \
          unsigned slot = atomicAdd(fbcnt, 1u); \
          if (slot < FBCAP) fb[slot] = make_uint4((unsigned)(xbase + (size_t)(Y) * WG + (XC)), \
                                                  __float_as_uint(gv.x * (WT)), __float_as_uint(gv.y * (WT)), 0u); \
        } \
      } \
    }
    PROC(y0, x0, w00); PROC(y0, x1, w01); PROC(y1, x0, w10); PROC(y1, x1, w11);
    #undef PROC
    i = inx; fy = fy2; fx = fx2; gv = gv2;
  }
  __syncthreads();
  float s = stdp[0];
  const float2* gt = gtv + (size_t)pz * HW2;
  for (int i2 = tid; i2 < TRG * WG; i2 += 512){
    int yy = i2 / WG; int w = i2 - yy * WG;
    int hw = (R + yy) * WG + w;
    float2 xv = x[xbase + hw];
    float2 tv = gt[hw];
    xv.x -= GAMMA_C * lt[i2 * 2 + 0] + TAU_C * s * tv.x;
    xv.y -= GAMMA_C * lt[i2 * 2 + 1] + TAU_C * s * tv.y;
    x[xbase + hw] = xv;
  }
}

// apply rare out-of-halo contributions: x[idx] -= GAMMA * val
__global__ __launch_bounds__(256) void k_fixup(const uint4* __restrict__ fb, const unsigned int* __restrict__ fbcnt,
                                               float2* __restrict__ x){
  unsigned n = *fbcnt; if (n > FBCAP) n = FBCAP;
  for (unsigned i = blockIdx.x * 256 + threadIdx.x; i < n; i += gridDim.x * 256){
    uint4 e = fb[i];
    atomicAdd(&x[e.x].x, -GAMMA_C * __uint_as_float(e.y));
    atomicAdd(&x[e.x].y, -GAMMA_C * __uint_as_float(e.z));
  }
}

// ---------------- host ----------------
extern "C" void kernel_launch(void* const* d_in, const int* in_sizes, int n_in,
                              void* d_out, int out_size, void* d_ws, size_t ws_size,
                              hipStream_t stream) {
  const float2* kdata = (const float2*)d_in[0];
  const float*  traj  = (const float*) d_in[1];
  const float2* img0  = (const float2*)d_in[2];
  const float*  mvf   = (const float*) d_in[3];
  const float2* csm   = (const float2*)d_in[4];
  const float*  stdp  = (const float*) d_in[5];
  float2* x = (float2*)d_out;

  const size_t F_B  = (size_t)CHN * ZE * HW2 * 8;        // 39,321,600
  const size_t W_B  = (size_t)PH * ZE * HW2 * 8;         // 19,660,800
  const size_t E_B  = (size_t)PH * CHN * ZE * NKP * 8;   //  6,291,456
  const size_t FB_B = (size_t)FBCAP * 16;                //  2,097,152
  const size_t P_B  = (size_t)PH * NKP * 16;             //    262,144
  const size_t SORT_B = P_B + 4 * 8192;

  size_t need_big = 4 * F_B + 2 * W_B + E_B + 512 + FB_B + SORT_B;   // ~186 MB
  const int NP = (ws_size >= need_big) ? 4 : 1;

  char* cur = (char*)d_ws;
  float2* F      = (float2*)cur;  cur += (size_t)NP * F_B;
  float2* warped = (float2*)cur;  cur += W_B;              // also holds gwarped
  float2* est    = (float2*)cur;  cur += E_B;
  float2* gtvb   = (float2*)cur;  cur += W_B;
  unsigned int* dmax  = (unsigned int*)cur; cur += 128;
  unsigned int* fbcnt = (unsigned int*)cur; cur += 128;
  uint4* fb           = (uint4*)cur;        cur += FB_B;
  float4* permx       = (float4*)cur;       cur += P_B;
  unsigned* xhist     = (unsigned*)cur;     cur += 8192;
  unsigned* xcur      = (unsigned*)cur;     cur += 8192;
  unsigned* xbnd      = (unsigned*)cur;     cur += 8192;

  k_init<<<12800, 256, 0, stream>>>(img0, x, PH * ZT * HW2);
  // build x-sorted k-point list (traj constant across iterations)
  hipMemsetAsync(xhist, 0, 8192, stream);
  k_khist<<<64, 256, 0, stream>>>(traj, xhist);
  k_kscan<<<1, 64, 0, stream>>>(xhist, xcur, xbnd);
  k_kperm<<<64, 256, 0, stream>>>(traj, xcur, permx);

  for (int it = 0; it < 3; it++){
    k_warp_tv<<<9600, 256, 0, stream>>>(x, mvf, warped, gtvb);
    hipMemsetAsync(dmax, 0, 4, stream);
    for (int p0 = 0; p0 < PH; p0 += NP){
      k_fft_row_fwd   <<<NP * 3840, 256, 0, stream>>>(warped, csm, F, p0);
      k_fft_col_sample<<<NP *  960, 256, 0, stream>>>(F, permx, xbnd, est, dmax, p0);
    }
    k_weights<<<3072, 256, 0, stream>>>(est, kdata, permx, dmax);
    for (int p0 = 0; p0 < PH; p0 += NP){
      k_fft_col_scatter<<<NP *  960, 256, 0, stream>>>(est, permx, xbnd, F, p0);
      k_fft_row_bwd    <<<NP * 1920, 512, 0, stream>>>(F, csm, warped, p0);
    }
    hipMemsetAsync(fbcnt, 0, 4, stream);
    k_warpadj_update<<<960, 512, 0, stream>>>(warped, mvf, gtvb, stdp, x, fb, fbcnt);
    k_fixup<<<16, 256, 0, stream>>>(fb, fbcnt, x);
  }
}

// Round 10
// 1828.633 us; speedup vs baseline: 1.8202x; 1.0300x over previous
//
#include <hip/hip_runtime.h>
#include <math.h>

// ---------------- problem constants ----------------
#define PH   4
#define CHN  8
#define ZT   8
#define ZE   6          // effective z slices: z in [1,7)
#define HG   320
#define WG   320
#define HW2  102400     // 320*320
#define NKP  4096
#define LSTR 321        // LDS line stride (pad +1)
#define FBCAP 131072u   // fallback list capacity (entries)

constexpr float GAMMA_C = 0.1f;
constexpr float TAU_C   = 0.2f;
constexpr float EPS_C   = 0.01f;
constexpr float INV_N   = 1.0f / 786432.0f;   // PH*CHN*ZE*NKP
#define TWO_PI_F 6.28318530717958647692f

// W5^j = e^{-2*pi*i*j/5}
constexpr float W5R[5] = { 1.f,  0.30901699f, -0.80901699f, -0.80901699f,  0.30901699f};
constexpr float W5I[5] = { 0.f, -0.95105652f, -0.58778525f,  0.58778525f,  0.95105652f};

// ---------------- complex helpers ----------------
__device__ __forceinline__ float2 cmul(float2 a, float2 b){
  return make_float2(a.x*b.x - a.y*b.y, a.x*b.y + a.y*b.x);
}
__device__ __forceinline__ void cmac(float2& d, float2 a, float2 b){
  d.x = fmaf(a.x, b.x, fmaf(-a.y, b.y, d.x));
  d.y = fmaf(a.x, b.y, fmaf( a.y, b.x, d.y));
}

__device__ __forceinline__ void corners(float gy, float gx, int& y0, int& x0, int& y1, int& x1,
                                        float& w00, float& w01, float& w10, float& w11){
  float y0f = floorf(gy), x0f = floorf(gx);
  float wy = gy - y0f, wx = gx - x0f;
  y0 = (int)y0f; x0 = (int)x0f;
  y1 = min(y0 + 1, HG - 1); x1 = min(x0 + 1, WG - 1);
  w00 = (1.f - wy) * (1.f - wx);
  w01 = (1.f - wy) * wx;
  w10 = wy * (1.f - wx);
  w11 = wy * wx;
}

__device__ __forceinline__ void traj_to_grid(float ty, float tx, float& gy, float& gx){
  gy = fminf(fmaxf((ty / TWO_PI_F + 0.5f) * 320.f, 0.f), 319.f);
  gx = fminf(fmaxf((tx / TWO_PI_F + 0.5f) * 320.f, 0.f), 319.f);
}

// ---------------- in-register 320-pt FFT: one wave per line, N = 5 x 64 ----------------
// (verified rounds 5-9). Lane l stores X[5*br6(l)+r]; un-permuted via LDS seg.
struct FT {
  float2 t1, t2, t3, t4;
  float2 tw0, tw1, tw2, tw3, tw4;
  int br5, lane;
};

__device__ __forceinline__ FT ft_init(){
  FT f; int l = (int)(threadIdx.x & 63); f.lane = l;
  sincosf(-TWO_PI_F * (float)l * (1.0f/320.0f), &f.t1.y, &f.t1.x);
  f.t2 = cmul(f.t1, f.t1); f.t3 = cmul(f.t2, f.t1); f.t4 = cmul(f.t2, f.t2);
  sincosf(-TWO_PI_F * (float)(l & 31) * (1.0f/64.0f), &f.tw0.y, &f.tw0.x);
  sincosf(-TWO_PI_F * (float)(l & 15) * (1.0f/32.0f), &f.tw1.y, &f.tw1.x);
  sincosf(-TWO_PI_F * (float)(l &  7) * (1.0f/16.0f), &f.tw2.y, &f.tw2.x);
  sincosf(-TWO_PI_F * (float)(l &  3) * (1.0f/ 8.0f), &f.tw3.y, &f.tw3.x);
  f.tw4 = (l & 1) ? make_float2(0.f, -1.f) : make_float2(1.f, 0.f);
  int br = ((l&1)<<5) | ((l&2)<<3) | ((l&4)<<1) | ((l&8)>>1) | ((l&16)>>3) | ((l&32)>>5);
  f.br5 = 5 * br;
  return f;
}

template<int H>
__device__ __forceinline__ void bfly(float2& v, float2 tw, int lane){
  float px = __shfl_xor(v.x, H, 64);
  float py = __shfl_xor(v.y, H, 64);
  bool up = (lane & H) != 0;
  float ax = up ? px : v.x, ay = up ? py : v.y;
  float bx = up ? v.x : px, by = up ? v.y : py;
  float dx = ax - bx,  dy = ay - by;
  float mx = fmaf(dx, tw.x, -dy * tw.y);
  float my = fmaf(dx, tw.y,  dy * tw.x);
  v.x = up ? mx : (ax + bx);
  v.y = up ? my : (ay + by);
}

__device__ __forceinline__ void fft320w(const float2 a[5], const FT& f, float2* __restrict__ seg){
  float2 z[5];
  #pragma unroll
  for (int r = 0; r < 5; r++){
    float2 acc = a[0];
    #pragma unroll
    for (int q = 1; q < 5; q++){
      const int j = (q * r) % 5;
      cmac(acc, a[q], make_float2(W5R[j], W5I[j]));
    }
    z[r] = acc;
  }
  z[1] = cmul(z[1], f.t1); z[2] = cmul(z[2], f.t2);
  z[3] = cmul(z[3], f.t3); z[4] = cmul(z[4], f.t4);
  #pragma unroll
  for (int r = 0; r < 5; r++){
    float2 v = z[r];
    bfly<32>(v, f.tw0, f.lane);
    bfly<16>(v, f.tw1, f.lane);
    bfly< 8>(v, f.tw2, f.lane);
    bfly< 4>(v, f.tw3, f.lane);
    bfly< 2>(v, f.tw4, f.lane);
    {
      float px = __shfl_xor(v.x, 1, 64);
      float py = __shfl_xor(v.y, 1, 64);
      bool up = (f.lane & 1) != 0;
      float ax = up ? px : v.x, ay = up ? py : v.y;
      float bx = up ? v.x : px, by = up ? v.y : py;
      v.x = up ? (ax - bx) : (ax + bx);
      v.y = up ? (ay - by) : (ay + by);
    }
    seg[f.br5 + r] = v;
  }
}

// ---------------- k-point x-sorting (once per call; traj constant across iterations) --------
__global__ __launch_bounds__(256) void k_khist(const float* __restrict__ traj, unsigned* __restrict__ xhist){
  int gid = blockIdx.x * 256 + threadIdx.x;
  if (gid >= PH * NKP) return;
  int p = gid >> 12, k = gid & (NKP - 1);
  float gy, gx;
  traj_to_grid(traj[(p * 2 + 0) * NKP + k], traj[(p * 2 + 1) * NKP + k], gy, gx);
  atomicAdd(&xhist[p * WG + (int)floorf(gx)], 1u);
}

__global__ void k_kscan(const unsigned* __restrict__ xhist, unsigned* __restrict__ xcur,
                        unsigned* __restrict__ xbnd){
  int p = threadIdx.x;
  if (p < PH){
    unsigned acc = 0;
    for (int b = 0; b < WG; b++){ xcur[p * WG + b] = acc; xbnd[p * (WG + 1) + b] = acc; acc += xhist[p * WG + b]; }
    xbnd[p * (WG + 1) + WG] = acc;
  }
}

__global__ __launch_bounds__(256) void k_kperm(const float* __restrict__ traj, unsigned* __restrict__ xcur,
                                               float4* __restrict__ permx){
  int gid = blockIdx.x * 256 + threadIdx.x;
  if (gid >= PH * NKP) return;
  int p = gid >> 12, k = gid & (NKP - 1);
  float gy, gx;
  traj_to_grid(traj[(p * 2 + 0) * NKP + k], traj[(p * 2 + 1) * NKP + k], gy, gx);
  unsigned sx = atomicAdd(&xcur[p * WG + (int)floorf(gx)], 1u);
  permx[p * NKP + sx] = make_float4(__uint_as_float((unsigned)k), gy, gx, 0.f);
}

// ---------------- kernels ----------------
__global__ __launch_bounds__(256) void k_init(const float2* __restrict__ img0, float2* __restrict__ x, int n){
  int i = blockIdx.x * 256 + threadIdx.x;
  if (i < n){
    float2 v = img0[i];
    v.x = isnan(v.x) ? 0.f : fminf(fmaxf(v.x, -3.4028235e38f), 3.4028235e38f);
    v.y = isnan(v.y) ? 0.f : fminf(fmaxf(v.y, -3.4028235e38f), 3.4028235e38f);
    x[i] = v;
  }
}

// fused: warped = bilinear-warp(x, mvf); gtv = conj(TV-grad(x))
__global__ __launch_bounds__(256) void k_warp_tv(const float2* __restrict__ x, const float* __restrict__ mvf,
                                                 float2* __restrict__ warped, float2* __restrict__ gtv){
  int gid = blockIdx.x * 256 + threadIdx.x;          // over PH*ZE*HW2
  int hw = gid % HW2;
  int pz = gid / HW2;
  int zz = pz % ZE, p = pz / ZE, z = zz + 1;
  int h = hw / WG, w = hw - h * WG;
  const float* mv = mvf + ((size_t)(p * 2 + 0) * ZT + z) * HW2;
  float fy = mv[hw];
  float fx = mv[(size_t)ZT * HW2 + hw];
  float gy = fminf(fmaxf((float)h + fy, 0.f), 319.f);
  float gx = fminf(fmaxf((float)w + fx, 0.f), 319.f);
  int y0, x0, y1, x1; float w00, w01, w10, w11;
  corners(gy, gx, y0, x0, y1, x1, w00, w01, w10, w11);
  const float2* xs = x + (size_t)(p * ZT + z) * HW2;
  float2 v00 = xs[y0 * WG + x0], v01 = xs[y0 * WG + x1];
  float2 v10 = xs[y1 * WG + x0], v11 = xs[y1 * WG + x1];
  float2 o;
  o.x = v00.x * w00 + v01.x * w01 + v10.x * w10 + v11.x * w11;
  o.y = v00.y * w00 + v01.y * w01 + v10.y * w10 + v11.y * w11;
  warped[gid] = o;
  // TV gradient
  float2 xc = xs[hw];
  float tre = 0.f, tim = 0.f;
  if (h > 0){
    float2 n = xs[hw - WG];
    float dr = xc.x - n.x, di = xc.y - n.y;
    float r = sqrtf(dr * dr + di * di + 1e-8f);
    tre += dr / r; tim += di / r;
  }
  if (h < HG - 1){
    float2 n = xs[hw + WG];
    float dr = n.x - xc.x, di = n.y - xc.y;
    float r = sqrtf(dr * dr + di * di + 1e-8f);
    tre -= dr / r; tim -= di / r;
  }
  if (w > 0){
    float2 n = xs[hw - 1];
    float dr = xc.x - n.x, di = xc.y - n.y;
    float r = sqrtf(dr * dr + di * di + 1e-8f);
    tre += dr / r; tim += di / r;
  }
  if (w < WG - 1){
    float2 n = xs[hw + 1];
    float dr = n.x - xc.x, di = n.y - xc.y;
    float r = sqrtf(dr * dr + di * di + 1e-8f);
    tre -= dr / r; tim -= di / r;
  }
  gtv[gid] = make_float2(tre, -tim);
}

// row FFT forward: 8 rows of one slice per block (8 waves); output written TRANSPOSED:
// FT_[sl][w][h] (addr = sl*HW2 + w*HG + h) so the column pass reads contiguously.
// Write pattern: per w, 8 consecutive h = one 64 B cacheline.
__global__ __launch_bounds__(512) void k_fft_row_fwd(const float2* __restrict__ warped, const float2* __restrict__ csm,
                                                     float2* __restrict__ FT_, int p0){
  __shared__ float2 seg[8 * LSTR];
  FT f = ft_init();
  int wid = threadIdx.x >> 6, l = f.lane;
  int hg = blockIdx.x % 40; int sl = blockIdx.x / 40;      // sl = (pp*CHN + c)*ZE + zz
  int zz = sl % ZE; int s2 = sl / ZE; int c = s2 % CHN; int pp = s2 / CHN;
  int p = p0 + pp; int z = zz + 1;
  int h = hg * 8 + wid;
  const float2* wr = warped + ((size_t)(p * ZE + zz)) * HW2 + (size_t)h * WG;
  const float2* cs = csm + ((size_t)(c * ZT + z)) * HW2 + (size_t)h * WG;
  float sgn = ((h + l) & 1) ? -1.f : 1.f;
  float2 a[5];
  #pragma unroll
  for (int q = 0; q < 5; q++){
    float2 v = cmul(wr[64 * q + l], cs[64 * q + l]);
    a[q] = make_float2(v.x * sgn, v.y * sgn);
  }
  fft320w(a, f, seg + wid * LSTR);
  __syncthreads();
  float2* out = FT_ + (size_t)sl * HW2 + hg * 8;           // + w*HG later
  for (int i = threadIdx.x; i < 8 * WG; i += 512){
    int w = i >> 3; int hh = i & 7;
    out[(size_t)w * HG + hh] = seg[hh * LSTR + w];
  }
}

// fused forward: column FFT of 17 F-columns (= contiguous F^T rows) in LDS, then sample all
// k-points with x0 in [cbase, cbase+16) straight from LDS. est written in x-sorted (j) order.
// The col-FFT'd spectrum never touches HBM.
__global__ __launch_bounds__(512) void k_fft_col_sample(const float2* __restrict__ FT_, const float4* __restrict__ permx,
                                                        const unsigned* __restrict__ xbnd, float2* __restrict__ est,
                                                        unsigned int* __restrict__ dmax, int p0){
  __shared__ float2 ld[17 * LSTR];   // 43,656 B
  FT f = ft_init();
  int tid = threadIdx.x; int wid = tid >> 6, l = f.lane;
  int cg = blockIdx.x % 20; int sl = blockIdx.x / 20;       // local slice (pp*CHN+c)*ZE+zz
  int s2 = sl / ZE; int pp = s2 / CHN;
  int p = p0 + pp;
  int cbase = cg * 16;
  const int ncol = (cbase + 16 <= WG - 1) ? 17 : 16;
  const float2* Fs = FT_ + (size_t)sl * HW2 + (size_t)cbase * HG;   // contiguous stream
  for (int i = tid; i < ncol * HG; i += 512){
    ld[i + i / HG] = Fs[i];     // ld[col*LSTR + h] with i = col*HG + h
  }
  __syncthreads();
  #pragma unroll
  for (int cc = 0; cc < 3; cc++){
    int col = cc * 8 + wid;
    if (col < ncol){
      float2* base = ld + col * LSTR;
      float2 a[5];
      #pragma unroll
      for (int q = 0; q < 5; q++) a[q] = base[64 * q + l];
      fft320w(a, f, base);
    }
  }
  __syncthreads();
  // sample from LDS
  int lo = (int)xbnd[p * (WG + 1) + cbase];
  int hi = (int)xbnd[p * (WG + 1) + min(cbase + 16, WG)];
  float2* eb = est + ((size_t)(p0 * CHN * ZE) + sl) * NKP;
  const float4* px = permx + p * NKP;
  float md2 = 0.f;
  for (int j = lo + tid; j < hi; j += 512){
    float4 e4 = px[j];
    int y0, x0, y1, x1; float w00, w01, w10, w11;
    corners(e4.y, e4.z, y0, x0, y1, x1, w00, w01, w10, w11);
    int lc0 = x0 - cbase, lc1 = x1 - cbase;
    float2 v00 = ld[lc0 * LSTR + y0], v01 = ld[lc1 * LSTR + y0];
    float2 v10 = ld[lc0 * LSTR + y1], v11 = ld[lc1 * LSTR + y1];
    float2 e;
    e.x = v00.x * w00 + v01.x * w01 + v10.x * w10 + v11.x * w11;
    e.y = v00.y * w00 + v01.y * w01 + v10.y * w10 + v11.y * w11;
    eb[j] = e;
    md2 = fmaxf(md2, e.x * e.x + e.y * e.y);
  }
  for (int off = 32; off > 0; off >>= 1) md2 = fmaxf(md2, __shfl_down(md2, off, 64));
  if ((tid & 63) == 0 && md2 > 0.f) atomicMax(dmax, __float_as_uint(md2));
}

// est (x-sorted order) -> cotangent: G = (w^2/N) * conj(est - y); kdata gathered via permx
__global__ __launch_bounds__(256) void k_weights(float2* __restrict__ est, const float2* __restrict__ kdata,
                                                 const float4* __restrict__ permx,
                                                 const unsigned int* __restrict__ dmax){
  int gid = blockIdx.x * 256 + threadIdx.x;     // over PH*CHN*ZE*NKP (j-order)
  int j = gid & (NKP - 1);
  int t = gid >> 12;                            // (p*CHN+c)*ZE + zz
  int zz = t % ZE; int pc = t / ZE; int z = zz + 1;
  int p = pc / CHN;
  int k = (int)__float_as_uint(permx[p * NKP + j].x);
  float md = sqrtf(__uint_as_float(*dmax));
  float2 e = est[gid];
  float det = sqrtf(e.x * e.x + e.y * e.y);
  float wv = 1.0f / (det / md + EPS_C);
  float sc = wv * wv * INV_N;
  float2 y = kdata[((size_t)pc * ZT + z) * NKP + k];
  est[gid] = make_float2(sc * (e.x - y.x), -sc * (e.y - y.y));
}

// backward: fused { zero tile + x-bucketed corner scatter (LDS atomics, G read contiguous) + col DFT^T }
// F written in NORMAL layout here (row_bwd reads rows).
__global__ __launch_bounds__(256) void k_fft_col_scatter(const float2* __restrict__ G, const float4* __restrict__ permx,
                                                         const unsigned* __restrict__ xbnd,
                                                         float2* __restrict__ F, int p0){
  __shared__ float2 ld[16 * LSTR];
  FT f = ft_init();
  int tid = threadIdx.x; int wid = tid >> 6, l = f.lane;
  int cg = blockIdx.x % 20; int sl = blockIdx.x / 20;       // local slice
  int s2 = sl / ZE; int pp = s2 / CHN;
  int p = p0 + pp;
  for (int i = tid; i < 16 * LSTR; i += 256) ld[i] = make_float2(0.f, 0.f);
  __syncthreads();
  int cbase = cg * 16;
  int lo = (cbase > 0) ? (int)xbnd[p * (WG + 1) + cbase - 1] : 0;
  int hi = (int)xbnd[p * (WG + 1) + min(cbase + 16, WG)];
  const float2* Gs = G + ((size_t)(p0 * CHN * ZE) + sl) * NKP;
  const float4* px = permx + p * NKP;
  for (int j = lo + tid; j < hi; j += 256){
    float4 e4 = px[j];
    int y0, x0, y1, x1; float w00, w01, w10, w11;
    corners(e4.y, e4.z, y0, x0, y1, x1, w00, w01, w10, w11);
    float2 gv = Gs[j];
    int c0 = x0 - cbase, c1 = x1 - cbase;
    if ((unsigned)c0 < 16u){
      atomicAdd(&ld[c0 * LSTR + y0].x, gv.x * w00); atomicAdd(&ld[c0 * LSTR + y0].y, gv.y * w00);
      atomicAdd(&ld[c0 * LSTR + y1].x, gv.x * w10); atomicAdd(&ld[c0 * LSTR + y1].y, gv.y * w10);
    }
    if ((unsigned)c1 < 16u){
      atomicAdd(&ld[c1 * LSTR + y0].x, gv.x * w01); atomicAdd(&ld[c1 * LSTR + y0].y, gv.y * w01);
      atomicAdd(&ld[c1 * LSTR + y1].x, gv.x * w11); atomicAdd(&ld[c1 * LSTR + y1].y, gv.y * w11);
    }
  }
  __syncthreads();
  #pragma unroll
  for (int cc = 0; cc < 4; cc++){
    float2* base = ld + (wid * 4 + cc) * LSTR;
    float2 a[5];
    #pragma unroll
    for (int q = 0; q < 5; q++) a[q] = base[64 * q + l];
    fft320w(a, f, base);
  }
  __syncthreads();
  float2* Fs = F + (size_t)sl * HW2 + cbase;
  for (int i = tid; i < 5120; i += 256){ int h = i >> 4, col = i & 15; Fs[h * WG + col] = ld[col * LSTR + h]; }
}

// transpose row pass: 8 waves = 8 coils of one (pp,zz,h) row; epilogue *(-1)^(h+w), *csm, coil sum
__global__ __launch_bounds__(512) void k_fft_row_bwd(const float2* __restrict__ F, const float2* __restrict__ csm,
                                                     float2* __restrict__ gwarped, int p0){
  __shared__ float2 seg[8 * LSTR];
  FT f = ft_init();
  int tid = threadIdx.x; int c = tid >> 6, l = f.lane;
  int bid = blockIdx.x;                          // over np*ZE*HG
  int h = bid % HG; int b2 = bid / HG;
  int zz = b2 % ZE; int pp = b2 / ZE;
  int p = p0 + pp; int z = zz + 1;
  const float2* Fl = F + ((size_t)((pp * CHN + c) * ZE + zz)) * HW2 + (size_t)h * WG;
  float2 a[5];
  #pragma unroll
  for (int q = 0; q < 5; q++) a[q] = Fl[64 * q + l];
  fft320w(a, f, seg + c * LSTR);
  __syncthreads();
  if (tid < WG){
    int w = tid;
    float2 acc = make_float2(0.f, 0.f);
    #pragma unroll
    for (int cc = 0; cc < 8; cc++){
      cmac(acc, seg[cc * LSTR + w], csm[((size_t)(cc * ZT + z)) * HW2 + (size_t)h * WG + w]);
    }
    float sg = ((h + w) & 1) ? -1.f : 1.f;
    gwarped[((size_t)(p * ZE + zz)) * HW2 + (size_t)h * WG + w] = make_float2(acc.x * sg, acc.y * sg);
  }
}

// ---------------- gather-tiled warp adjoint + fused gradient update ----------------
#define TRG 8
#define HAG 8
__global__ __launch_bounds__(512) void k_warpadj_update(const float2* __restrict__ gw, const float* __restrict__ mvf,
                                                        const float2* __restrict__ gtv, const float* __restrict__ stdp,
                                                        float2* __restrict__ x,
                                                        uint4* __restrict__ fb, unsigned int* __restrict__ fbcnt){
  __shared__ float lt[TRG * WG * 2];   // 20480 B
  int tid = threadIdx.x;
  int bid = blockIdx.x;                    // pz*40 + tile
  int tile = bid % 40; int pz = bid / 40;
  int zz = pz % ZE, p = pz / ZE, z = zz + 1;
  int R = tile * TRG;
  for (int i = tid; i < TRG * WG * 2; i += 512) lt[i] = 0.f;
  __syncthreads();
  const float* mvy = mvf + ((size_t)(p * 2 + 0) * ZT + z) * HW2;
  const float* mvx = mvy + (size_t)ZT * HW2;
  const float2* g = gw + (size_t)pz * HW2;
  const size_t xbase = (size_t)(p * ZT + z) * HW2;
  int wlo = max(R - HAG, 0), whi = min(R + TRG + HAG, HG);
  int npx = (whi - wlo) * WG;
  int base0 = wlo * WG;
  int i = tid;
  float fy = 0.f, fx = 0.f; float2 gv = make_float2(0.f, 0.f);
  if (i < npx){ fy = mvy[base0 + i]; fx = mvx[base0 + i]; gv = g[base0 + i]; }
  while (i < npx){
    int inx = i + 512;
    float fy2 = 0.f, fx2 = 0.f; float2 gv2 = make_float2(0.f, 0.f);
    if (inx < npx){ fy2 = mvy[base0 + inx]; fx2 = mvx[base0 + inx]; gv2 = g[base0 + inx]; }
    int hh = i / WG; int w = i - hh * WG;
    int h = wlo + hh;
    float gy = fminf(fmaxf((float)h + fy, 0.f), 319.f);
    float gx = fminf(fmaxf((float)w + fx, 0.f), 319.f);
    int y0, x0, y1, x1; float w00, w01, w10, w11;
    corners(gy, gx, y0, x0, y1, x1, w00, w01, w10, w11);
    bool owner = (h >= R) && (h < R + TRG);
    #define PROC(Y, XC, WT) { \
      int ry = (Y) - R; \
      if ((unsigned)ry < (unsigned)TRG){ \
        atomicAdd(&lt[(ry * WG + (XC)) * 2 + 0], gv.x * (WT)); \
        atomicAdd(&lt[(ry * WG + (XC)) * 2 + 1], gv.y * (WT)); \
      } else if (owner){ \
        int Ry = (Y) & ~(TRG - 1); \
        if (h < Ry - HAG || h >= Ry + TRG + HAG){ \
          unsigned slot = atomicAdd(fbcnt, 1u); \
          if (slot < FBCAP) fb[slot] = make_uint4((unsigned)(xbase + (size_t)(Y) * WG + (XC)), \
                                                  __float_as_uint(gv.x * (WT)), __float_as_uint(gv.y * (WT)), 0u); \
        } \
      } \
    }
    PROC(y0, x0, w00); PROC(y0, x1, w01); PROC(y1, x0, w10); PROC(y1, x1, w11);
    #undef PROC
    i = inx; fy = fy2; fx = fx2; gv = gv2;
  }
  __syncthreads();
  float s = stdp[0];
  const float2* gt = gtv + (size_t)pz * HW2;
  for (int i2 = tid; i2 < TRG * WG; i2 += 512){
    int yy = i2 / WG; int w = i2 - yy * WG;
    int hw = (R + yy) * WG + w;
    float2 xv = x[xbase + hw];
    float2 tv = gt[hw];
    xv.x -= GAMMA_C * lt[i2 * 2 + 0] + TAU_C * s * tv.x;
    xv.y -= GAMMA_C * lt[i2 * 2 + 1] + TAU_C * s * tv.y;
    x[xbase + hw] = xv;
  }
}

// apply rare out-of-halo contributions: x[idx] -= GAMMA * val
__global__ __launch_bounds__(256) void k_fixup(const uint4* __restrict__ fb, const unsigned int* __restrict__ fbcnt,
                                               float2* __restrict__ x){
  unsigned n = *fbcnt; if (n > FBCAP) n = FBCAP;
  for (unsigned i = blockIdx.x * 256 + threadIdx.x; i < n; i += gridDim.x * 256){
    uint4 e = fb[i];
    atomicAdd(&x[e.x].x, -GAMMA_C * __uint_as_float(e.y));
    atomicAdd(&x[e.x].y, -GAMMA_C * __uint_as_float(e.z));
  }
}

// ---------------- host ----------------
extern "C" void kernel_launch(void* const* d_in, const int* in_sizes, int n_in,
                              void* d_out, int out_size, void* d_ws, size_t ws_size,
                              hipStream_t stream) {
  const float2* kdata = (const float2*)d_in[0];
  const float*  traj  = (const float*) d_in[1];
  const float2* img0  = (const float2*)d_in[2];
  const float*  mvf   = (const float*) d_in[3];
  const float2* csm   = (const float2*)d_in[4];
  const float*  stdp  = (const float*) d_in[5];
  float2* x = (float2*)d_out;

  const size_t F_B  = (size_t)CHN * ZE * HW2 * 8;        // 39,321,600
  const size_t W_B  = (size_t)PH * ZE * HW2 * 8;         // 19,660,800
  const size_t E_B  = (size_t)PH * CHN * ZE * NKP * 8;   //  6,291,456
  const size_t FB_B = (size_t)FBCAP * 16;                //  2,097,152
  const size_t P_B  = (size_t)PH * NKP * 16;             //    262,144
  const size_t SORT_B = P_B + 4 * 8192;

  size_t need_big = 4 * F_B + 2 * W_B + E_B + 512 + FB_B + SORT_B;   // ~186 MB
  const int NP = (ws_size >= need_big) ? 4 : 1;

  char* cur = (char*)d_ws;
  float2* F      = (float2*)cur;  cur += (size_t)NP * F_B;   // fwd: transposed; bwd: normal
  float2* warped = (float2*)cur;  cur += W_B;                // also holds gwarped
  float2* est    = (float2*)cur;  cur += E_B;
  float2* gtvb   = (float2*)cur;  cur += W_B;
  unsigned int* dmax  = (unsigned int*)cur; cur += 128;
  unsigned int* fbcnt = (unsigned int*)cur; cur += 128;
  uint4* fb           = (uint4*)cur;        cur += FB_B;
  float4* permx       = (float4*)cur;       cur += P_B;
  unsigned* xhist     = (unsigned*)cur;     cur += 8192;
  unsigned* xcur      = (unsigned*)cur;     cur += 8192;
  unsigned* xbnd      = (unsigned*)cur;     cur += 8192;

  k_init<<<12800, 256, 0, stream>>>(img0, x, PH * ZT * HW2);
  // build x-sorted k-point list (traj constant across iterations)
  hipMemsetAsync(xhist, 0, 8192, stream);
  k_khist<<<64, 256, 0, stream>>>(traj, xhist);
  k_kscan<<<1, 64, 0, stream>>>(xhist, xcur, xbnd);
  k_kperm<<<64, 256, 0, stream>>>(traj, xcur, permx);

  for (int it = 0; it < 3; it++){
    k_warp_tv<<<9600, 256, 0, stream>>>(x, mvf, warped, gtvb);
    hipMemsetAsync(dmax, 0, 4, stream);
    for (int p0 = 0; p0 < PH; p0 += NP){
      k_fft_row_fwd   <<<NP * 1920, 512, 0, stream>>>(warped, csm, F, p0);
      k_fft_col_sample<<<NP *  960, 512, 0, stream>>>(F, permx, xbnd, est, dmax, p0);
    }
    k_weights<<<3072, 256, 0, stream>>>(est, kdata, permx, dmax);
    for (int p0 = 0; p0 < PH; p0 += NP){
      k_fft_col_scatter<<<NP *  960, 256, 0, stream>>>(est, permx, xbnd, F, p0);
      k_fft_row_bwd    <<<NP * 1920, 512, 0, stream>>>(F, csm, warped, p0);
    }
    hipMemsetAsync(fbcnt, 0, 4, stream);
    k_warpadj_update<<<960, 512, 0, stream>>>(warped, mvf, gtvb, stdp, x, fb, fbcnt);
    k_fixup<<<16, 256, 0, stream>>>(fb, fbcnt, x);
  }
}

// Round 11
// 1794.954 us; speedup vs baseline: 1.8543x; 1.0188x over previous
//
#include <hip/hip_runtime.h>
#include <math.h>

// ---------------- problem constants ----------------
#define PH   4
#define CHN  8
#define ZT   8
#define ZE   6          // effective z slices: z in [1,7)
#define HG   320
#define WG   320
#define HW2  102400     // 320*320
#define NKP  4096
#define LSTR 321        // LDS line stride (pad +1)
#define FBCAP 131072u   // fallback list capacity (entries)

constexpr float GAMMA_C = 0.1f;
constexpr float TAU_C   = 0.2f;
constexpr float EPS_C   = 0.01f;
constexpr float INV_N   = 1.0f / 786432.0f;   // PH*CHN*ZE*NKP
#define TWO_PI_F 6.28318530717958647692f

// W5^j = e^{-2*pi*i*j/5}
constexpr float W5R[5] = { 1.f,  0.30901699f, -0.80901699f, -0.80901699f,  0.30901699f};
constexpr float W5I[5] = { 0.f, -0.95105652f, -0.58778525f,  0.58778525f,  0.95105652f};

// ---------------- complex helpers ----------------
__device__ __forceinline__ float2 cmul(float2 a, float2 b){
  return make_float2(a.x*b.x - a.y*b.y, a.x*b.y + a.y*b.x);
}
__device__ __forceinline__ void cmac(float2& d, float2 a, float2 b){
  d.x = fmaf(a.x, b.x, fmaf(-a.y, b.y, d.x));
  d.y = fmaf(a.x, b.y, fmaf( a.y, b.x, d.y));
}

__device__ __forceinline__ void corners(float gy, float gx, int& y0, int& x0, int& y1, int& x1,
                                        float& w00, float& w01, float& w10, float& w11){
  float y0f = floorf(gy), x0f = floorf(gx);
  float wy = gy - y0f, wx = gx - x0f;
  y0 = (int)y0f; x0 = (int)x0f;
  y1 = min(y0 + 1, HG - 1); x1 = min(x0 + 1, WG - 1);
  w00 = (1.f - wy) * (1.f - wx);
  w01 = (1.f - wy) * wx;
  w10 = wy * (1.f - wx);
  w11 = wy * wx;
}

__device__ __forceinline__ void traj_to_grid(float ty, float tx, float& gy, float& gx){
  gy = fminf(fmaxf((ty / TWO_PI_F + 0.5f) * 320.f, 0.f), 319.f);
  gx = fminf(fmaxf((tx / TWO_PI_F + 0.5f) * 320.f, 0.f), 319.f);
}

// ---------------- in-register 320-pt FFT: one wave per line, N = 5 x 64 ----------------
// (verified rounds 5-10). Lane l stores X[5*br6(l)+r]; un-permuted via LDS seg.
struct FT {
  float2 t1, t2, t3, t4;
  float2 tw0, tw1, tw2, tw3, tw4;
  int br5, lane;
};

__device__ __forceinline__ FT ft_init(){
  FT f; int l = (int)(threadIdx.x & 63); f.lane = l;
  sincosf(-TWO_PI_F * (float)l * (1.0f/320.0f), &f.t1.y, &f.t1.x);
  f.t2 = cmul(f.t1, f.t1); f.t3 = cmul(f.t2, f.t1); f.t4 = cmul(f.t2, f.t2);
  sincosf(-TWO_PI_F * (float)(l & 31) * (1.0f/64.0f), &f.tw0.y, &f.tw0.x);
  sincosf(-TWO_PI_F * (float)(l & 15) * (1.0f/32.0f), &f.tw1.y, &f.tw1.x);
  sincosf(-TWO_PI_F * (float)(l &  7) * (1.0f/16.0f), &f.tw2.y, &f.tw2.x);
  sincosf(-TWO_PI_F * (float)(l &  3) * (1.0f/ 8.0f), &f.tw3.y, &f.tw3.x);
  f.tw4 = (l & 1) ? make_float2(0.f, -1.f) : make_float2(1.f, 0.f);
  int br = ((l&1)<<5) | ((l&2)<<3) | ((l&4)<<1) | ((l&8)>>1) | ((l&16)>>3) | ((l&32)>>5);
  f.br5 = 5 * br;
  return f;
}

template<int H>
__device__ __forceinline__ void bfly(float2& v, float2 tw, int lane){
  float px = __shfl_xor(v.x, H, 64);
  float py = __shfl_xor(v.y, H, 64);
  bool up = (lane & H) != 0;
  float ax = up ? px : v.x, ay = up ? py : v.y;
  float bx = up ? v.x : px, by = up ? v.y : py;
  float dx = ax - bx,  dy = ay - by;
  float mx = fmaf(dx, tw.x, -dy * tw.y);
  float my = fmaf(dx, tw.y,  dy * tw.x);
  v.x = up ? mx : (ax + bx);
  v.y = up ? my : (ay + by);
}

__device__ __forceinline__ void fft320w(const float2 a[5], const FT& f, float2* __restrict__ seg){
  float2 z[5];
  #pragma unroll
  for (int r = 0; r < 5; r++){
    float2 acc = a[0];
    #pragma unroll
    for (int q = 1; q < 5; q++){
      const int j = (q * r) % 5;
      cmac(acc, a[q], make_float2(W5R[j], W5I[j]));
    }
    z[r] = acc;
  }
  z[1] = cmul(z[1], f.t1); z[2] = cmul(z[2], f.t2);
  z[3] = cmul(z[3], f.t3); z[4] = cmul(z[4], f.t4);
  #pragma unroll
  for (int r = 0; r < 5; r++){
    float2 v = z[r];
    bfly<32>(v, f.tw0, f.lane);
    bfly<16>(v, f.tw1, f.lane);
    bfly< 8>(v, f.tw2, f.lane);
    bfly< 4>(v, f.tw3, f.lane);
    bfly< 2>(v, f.tw4, f.lane);
    {
      float px = __shfl_xor(v.x, 1, 64);
      float py = __shfl_xor(v.y, 1, 64);
      bool up = (f.lane & 1) != 0;
      float ax = up ? px : v.x, ay = up ? py : v.y;
      float bx = up ? v.x : px, by = up ? v.y : py;
      v.x = up ? (ax - bx) : (ax + bx);
      v.y = up ? (ay - by) : (ay + by);
    }
    seg[f.br5 + r] = v;
  }
}

// ---------------- k-point x-sorting (once per call; traj constant across iterations) --------
__global__ __launch_bounds__(256) void k_khist(const float* __restrict__ traj, unsigned* __restrict__ xhist){
  int gid = blockIdx.x * 256 + threadIdx.x;
  if (gid >= PH * NKP) return;
  int p = gid >> 12, k = gid & (NKP - 1);
  float gy, gx;
  traj_to_grid(traj[(p * 2 + 0) * NKP + k], traj[(p * 2 + 1) * NKP + k], gy, gx);
  atomicAdd(&xhist[p * WG + (int)floorf(gx)], 1u);
}

__global__ void k_kscan(const unsigned* __restrict__ xhist, unsigned* __restrict__ xcur,
                        unsigned* __restrict__ xbnd){
  int p = threadIdx.x;
  if (p < PH){
    unsigned acc = 0;
    for (int b = 0; b < WG; b++){ xcur[p * WG + b] = acc; xbnd[p * (WG + 1) + b] = acc; acc += xhist[p * WG + b]; }
    xbnd[p * (WG + 1) + WG] = acc;
  }
}

__global__ __launch_bounds__(256) void k_kperm(const float* __restrict__ traj, unsigned* __restrict__ xcur,
                                               float4* __restrict__ permx){
  int gid = blockIdx.x * 256 + threadIdx.x;
  if (gid >= PH * NKP) return;
  int p = gid >> 12, k = gid & (NKP - 1);
  float gy, gx;
  traj_to_grid(traj[(p * 2 + 0) * NKP + k], traj[(p * 2 + 1) * NKP + k], gy, gx);
  unsigned sx = atomicAdd(&xcur[p * WG + (int)floorf(gx)], 1u);
  permx[p * NKP + sx] = make_float4(__uint_as_float((unsigned)k), gy, gx, 0.f);
}

// ---------------- kernels ----------------
__global__ __launch_bounds__(256) void k_init(const float2* __restrict__ img0, float2* __restrict__ x, int n){
  int i = blockIdx.x * 256 + threadIdx.x;
  if (i < n){
    float2 v = img0[i];
    v.x = isnan(v.x) ? 0.f : fminf(fmaxf(v.x, -3.4028235e38f), 3.4028235e38f);
    v.y = isnan(v.y) ? 0.f : fminf(fmaxf(v.y, -3.4028235e38f), 3.4028235e38f);
    x[i] = v;
  }
}

// fused: warped = bilinear-warp(x, mvf); gtv = conj(TV-grad(x))
__global__ __launch_bounds__(256) void k_warp_tv(const float2* __restrict__ x, const float* __restrict__ mvf,
                                                 float2* __restrict__ warped, float2* __restrict__ gtv){
  int gid = blockIdx.x * 256 + threadIdx.x;          // over PH*ZE*HW2
  int hw = gid % HW2;
  int pz = gid / HW2;
  int zz = pz % ZE, p = pz / ZE, z = zz + 1;
  int h = hw / WG, w = hw - h * WG;
  const float* mv = mvf + ((size_t)(p * 2 + 0) * ZT + z) * HW2;
  float fy = mv[hw];
  float fx = mv[(size_t)ZT * HW2 + hw];
  float gy = fminf(fmaxf((float)h + fy, 0.f), 319.f);
  float gx = fminf(fmaxf((float)w + fx, 0.f), 319.f);
  int y0, x0, y1, x1; float w00, w01, w10, w11;
  corners(gy, gx, y0, x0, y1, x1, w00, w01, w10, w11);
  const float2* xs = x + (size_t)(p * ZT + z) * HW2;
  float2 v00 = xs[y0 * WG + x0], v01 = xs[y0 * WG + x1];
  float2 v10 = xs[y1 * WG + x0], v11 = xs[y1 * WG + x1];
  float2 o;
  o.x = v00.x * w00 + v01.x * w01 + v10.x * w10 + v11.x * w11;
  o.y = v00.y * w00 + v01.y * w01 + v10.y * w10 + v11.y * w11;
  warped[gid] = o;
  // TV gradient
  float2 xc = xs[hw];
  float tre = 0.f, tim = 0.f;
  if (h > 0){
    float2 n = xs[hw - WG];
    float dr = xc.x - n.x, di = xc.y - n.y;
    float r = sqrtf(dr * dr + di * di + 1e-8f);
    tre += dr / r; tim += di / r;
  }
  if (h < HG - 1){
    float2 n = xs[hw + WG];
    float dr = n.x - xc.x, di = n.y - xc.y;
    float r = sqrtf(dr * dr + di * di + 1e-8f);
    tre -= dr / r; tim -= di / r;
  }
  if (w > 0){
    float2 n = xs[hw - 1];
    float dr = xc.x - n.x, di = xc.y - n.y;
    float r = sqrtf(dr * dr + di * di + 1e-8f);
    tre += dr / r; tim += di / r;
  }
  if (w < WG - 1){
    float2 n = xs[hw + 1];
    float dr = n.x - xc.x, di = n.y - xc.y;
    float r = sqrtf(dr * dr + di * di + 1e-8f);
    tre -= dr / r; tim -= di / r;
  }
  gtv[gid] = make_float2(tre, -tim);
}

// row FFT forward: 8 rows of one slice per block (8 waves); output written TRANSPOSED:
// FT_[sl][w][h] (addr = sl*HW2 + w*HG + h) so the column pass reads contiguously.
__global__ __launch_bounds__(512) void k_fft_row_fwd(const float2* __restrict__ warped, const float2* __restrict__ csm,
                                                     float2* __restrict__ FT_, int p0){
  __shared__ float2 seg[8 * LSTR];
  FT f = ft_init();
  int wid = threadIdx.x >> 6, l = f.lane;
  int hg = blockIdx.x % 40; int sl = blockIdx.x / 40;      // sl = (pp*CHN + c)*ZE + zz
  int zz = sl % ZE; int s2 = sl / ZE; int c = s2 % CHN; int pp = s2 / CHN;
  int p = p0 + pp; int z = zz + 1;
  int h = hg * 8 + wid;
  const float2* wr = warped + ((size_t)(p * ZE + zz)) * HW2 + (size_t)h * WG;
  const float2* cs = csm + ((size_t)(c * ZT + z)) * HW2 + (size_t)h * WG;
  float sgn = ((h + l) & 1) ? -1.f : 1.f;
  float2 a[5];
  #pragma unroll
  for (int q = 0; q < 5; q++){
    float2 v = cmul(wr[64 * q + l], cs[64 * q + l]);
    a[q] = make_float2(v.x * sgn, v.y * sgn);
  }
  fft320w(a, f, seg + wid * LSTR);
  __syncthreads();
  float2* out = FT_ + (size_t)sl * HW2 + hg * 8;           // + w*HG later
  for (int i = threadIdx.x; i < 8 * WG; i += 512){
    int w = i >> 3; int hh = i & 7;
    out[(size_t)w * HG + hh] = seg[hh * LSTR + w];
  }
}

// fused forward: per block, 8 owned F-columns + 1 overlap, loaded DIRECTLY global->regs
// (contiguous F^T rows), FFT'd in registers, spectrum to LDS, then sample all k-points with
// x0 in [cbase, cbase+8) from LDS. est written in x-sorted (j) order. No staging barrier;
// the col-FFT'd spectrum never touches HBM.
__global__ __launch_bounds__(256) void k_fft_col_sample(const float2* __restrict__ FT_, const float4* __restrict__ permx,
                                                        const unsigned* __restrict__ xbnd, float2* __restrict__ est,
                                                        unsigned int* __restrict__ dmax, int p0){
  __shared__ float2 seg[9 * LSTR];   // 23,112 B -> up to 6 blocks/CU
  FT f = ft_init();
  int tid = threadIdx.x; int wid = tid >> 6, l = f.lane;
  int cg = blockIdx.x % 40; int sl = blockIdx.x / 40;       // local slice (pp*CHN+c)*ZE+zz
  int s2 = sl / ZE; int pp = s2 / CHN;
  int p = p0 + pp;
  int cbase = cg * 8;
  const int ncol = (cbase + 8 <= WG - 1) ? 9 : 8;
  const float2* Fs = FT_ + (size_t)sl * HW2 + (size_t)cbase * HG;
  #pragma unroll
  for (int cc = 0; cc < 3; cc++){
    int col = cc * 4 + wid;
    if (col < ncol){
      const float2* src = Fs + (size_t)col * HG;
      float2 a[5];
      #pragma unroll
      for (int q = 0; q < 5; q++) a[q] = src[64 * q + l];   // coalesced 512 B per q
      fft320w(a, f, seg + col * LSTR);
    }
  }
  __syncthreads();
  // sample from LDS
  int lo = (int)xbnd[p * (WG + 1) + cbase];
  int hi = (int)xbnd[p * (WG + 1) + min(cbase + 8, WG)];
  float2* eb = est + ((size_t)(p0 * CHN * ZE) + sl) * NKP;
  const float4* px = permx + p * NKP;
  float md2 = 0.f;
  for (int j = lo + tid; j < hi; j += 256){
    float4 e4 = px[j];
    int y0, x0, y1, x1; float w00, w01, w10, w11;
    corners(e4.y, e4.z, y0, x0, y1, x1, w00, w01, w10, w11);
    int lc0 = x0 - cbase, lc1 = x1 - cbase;
    float2 v00 = seg[lc0 * LSTR + y0], v01 = seg[lc1 * LSTR + y0];
    float2 v10 = seg[lc0 * LSTR + y1], v11 = seg[lc1 * LSTR + y1];
    float2 e;
    e.x = v00.x * w00 + v01.x * w01 + v10.x * w10 + v11.x * w11;
    e.y = v00.y * w00 + v01.y * w01 + v10.y * w10 + v11.y * w11;
    eb[j] = e;
    md2 = fmaxf(md2, e.x * e.x + e.y * e.y);
  }
  for (int off = 32; off > 0; off >>= 1) md2 = fmaxf(md2, __shfl_down(md2, off, 64));
  if ((tid & 63) == 0 && md2 > 0.f) atomicMax(dmax, __float_as_uint(md2));
}

// est (x-sorted order) -> cotangent: G = (w^2/N) * conj(est - y); kdata gathered via permx
__global__ __launch_bounds__(256) void k_weights(float2* __restrict__ est, const float2* __restrict__ kdata,
                                                 const float4* __restrict__ permx,
                                                 const unsigned int* __restrict__ dmax){
  int gid = blockIdx.x * 256 + threadIdx.x;     // over PH*CHN*ZE*NKP (j-order)
  int j = gid & (NKP - 1);
  int t = gid >> 12;                            // (p*CHN+c)*ZE + zz
  int zz = t % ZE; int pc = t / ZE; int z = zz + 1;
  int p = pc / CHN;
  int k = (int)__float_as_uint(permx[p * NKP + j].x);
  float md = sqrtf(__uint_as_float(*dmax));
  float2 e = est[gid];
  float det = sqrtf(e.x * e.x + e.y * e.y);
  float wv = 1.0f / (det / md + EPS_C);
  float sc = wv * wv * INV_N;
  float2 y = kdata[((size_t)pc * ZT + z) * NKP + k];
  est[gid] = make_float2(sc * (e.x - y.x), -sc * (e.y - y.y));
}

// backward: fused { zero tile + x-bucketed corner scatter (LDS atomics, G read contiguous) + col DFT^T }
// F written in NORMAL layout here (row_bwd reads rows).
__global__ __launch_bounds__(256) void k_fft_col_scatter(const float2* __restrict__ G, const float4* __restrict__ permx,
                                                         const unsigned* __restrict__ xbnd,
                                                         float2* __restrict__ F, int p0){
  __shared__ float2 ld[16 * LSTR];
  FT f = ft_init();
  int tid = threadIdx.x; int wid = tid >> 6, l = f.lane;
  int cg = blockIdx.x % 20; int sl = blockIdx.x / 20;       // local slice
  int s2 = sl / ZE; int pp = s2 / CHN;
  int p = p0 + pp;
  for (int i = tid; i < 16 * LSTR; i += 256) ld[i] = make_float2(0.f, 0.f);
  __syncthreads();
  int cbase = cg * 16;
  int lo = (cbase > 0) ? (int)xbnd[p * (WG + 1) + cbase - 1] : 0;
  int hi = (int)xbnd[p * (WG + 1) + min(cbase + 16, WG)];
  const float2* Gs = G + ((size_t)(p0 * CHN * ZE) + sl) * NKP;
  const float4* px = permx + p * NKP;
  for (int j = lo + tid; j < hi; j += 256){
    float4 e4 = px[j];
    int y0, x0, y1, x1; float w00, w01, w10, w11;
    corners(e4.y, e4.z, y0, x0, y1, x1, w00, w01, w10, w11);
    float2 gv = Gs[j];
    int c0 = x0 - cbase, c1 = x1 - cbase;
    if ((unsigned)c0 < 16u){
      atomicAdd(&ld[c0 * LSTR + y0].x, gv.x * w00); atomicAdd(&ld[c0 * LSTR + y0].y, gv.y * w00);
      atomicAdd(&ld[c0 * LSTR + y1].x, gv.x * w10); atomicAdd(&ld[c0 * LSTR + y1].y, gv.y * w10);
    }
    if ((unsigned)c1 < 16u){
      atomicAdd(&ld[c1 * LSTR + y0].x, gv.x * w01); atomicAdd(&ld[c1 * LSTR + y0].y, gv.y * w01);
      atomicAdd(&ld[c1 * LSTR + y1].x, gv.x * w11); atomicAdd(&ld[c1 * LSTR + y1].y, gv.y * w11);
    }
  }
  __syncthreads();
  #pragma unroll
  for (int cc = 0; cc < 4; cc++){
    float2* base = ld + (wid * 4 + cc) * LSTR;
    float2 a[5];
    #pragma unroll
    for (int q = 0; q < 5; q++) a[q] = base[64 * q + l];
    fft320w(a, f, base);
  }
  __syncthreads();
  float2* Fs = F + (size_t)sl * HW2 + cbase;
  for (int i = tid; i < 5120; i += 256){ int h = i >> 4, col = i & 15; Fs[h * WG + col] = ld[col * LSTR + h]; }
}

// transpose row pass: 8 waves = 8 coils of one (pp,zz,h) row; epilogue *(-1)^(h+w), *csm, coil sum
__global__ __launch_bounds__(512) void k_fft_row_bwd(const float2* __restrict__ F, const float2* __restrict__ csm,
                                                     float2* __restrict__ gwarped, int p0){
  __shared__ float2 seg[8 * LSTR];
  FT f = ft_init();
  int tid = threadIdx.x; int c = tid >> 6, l = f.lane;
  int bid = blockIdx.x;                          // over np*ZE*HG
  int h = bid % HG; int b2 = bid / HG;
  int zz = b2 % ZE; int pp = b2 / ZE;
  int p = p0 + pp; int z = zz + 1;
  const float2* Fl = F + ((size_t)((pp * CHN + c) * ZE + zz)) * HW2 + (size_t)h * WG;
  float2 a[5];
  #pragma unroll
  for (int q = 0; q < 5; q++) a[q] = Fl[64 * q + l];
  fft320w(a, f, seg + c * LSTR);
  __syncthreads();
  if (tid < WG){
    int w = tid;
    float2 acc = make_float2(0.f, 0.f);
    #pragma unroll
    for (int cc = 0; cc < 8; cc++){
      cmac(acc, seg[cc * LSTR + w], csm[((size_t)(cc * ZT + z)) * HW2 + (size_t)h * WG + w]);
    }
    float sg = ((h + w) & 1) ? -1.f : 1.f;
    gwarped[((size_t)(p * ZE + zz)) * HW2 + (size_t)h * WG + w] = make_float2(acc.x * sg, acc.y * sg);
  }
}

// ---------------- gather-tiled warp adjoint + fused gradient update ----------------
#define TRG 8
#define HAG 8
__global__ __launch_bounds__(512) void k_warpadj_update(const float2* __restrict__ gw, const float* __restrict__ mvf,
                                                        const float2* __restrict__ gtv, const float* __restrict__ stdp,
                                                        float2* __restrict__ x,
                                                        uint4* __restrict__ fb, unsigned int* __restrict__ fbcnt){
  __shared__ float lt[TRG * WG * 2];   // 20480 B
  int tid = threadIdx.x;
  int bid = blockIdx.x;                    // pz*40 + tile
  int tile = bid % 40; int pz = bid / 40;
  int zz = pz % ZE, p = pz / ZE, z = zz + 1;
  int R = tile * TRG;
  for (int i = tid; i < TRG * WG * 2; i += 512) lt[i] = 0.f;
  __syncthreads();
  const float* mvy = mvf + ((size_t)(p * 2 + 0) * ZT + z) * HW2;
  const float* mvx = mvy + (size_t)ZT * HW2;
  const float2* g = gw + (size_t)pz * HW2;
  const size_t xbase = (size_t)(p * ZT + z) * HW2;
  int wlo = max(R - HAG, 0), whi = min(R + TRG + HAG, HG);
  int npx = (whi - wlo) * WG;
  int base0 = wlo * WG;
  int i = tid;
  float fy = 0.f, fx = 0.f; float2 gv = make_float2(0.f, 0.f);
  if (i < npx){ fy = mvy[base0 + i]; fx = mvx[base0 + i]; gv = g[base0 + i]; }
  while (i < npx){
    int inx = i + 512;
    float fy2 = 0.f, fx2 = 0.f; float2 gv2 = make_float2(0.f, 0.f);
    if (inx < npx){ fy2 = mvy[base0 + inx]; fx2 = mvx[base0 + inx]; gv2 = g[base0 + inx]; }
    int hh = i / WG; int w = i - hh * WG;
    int h = wlo + hh;
    float gy = fminf(fmaxf((float)h + fy, 0.f), 319.f);
    float gx = fminf(fmaxf((float)w + fx, 0.f), 319.f);
    int y0, x0, y1, x1; float w00, w01, w10, w11;
    corners(gy, gx, y0, x0, y1, x1, w00, w01, w10, w11);
    bool owner = (h >= R) && (h < R + TRG);
    #define PROC(Y, XC, WT) { \
      int ry = (Y) - R; \
      if ((unsigned)ry < (unsigned)TRG){ \
        atomicAdd(&lt[(ry * WG + (XC)) * 2 + 0], gv.x * (WT)); \
        atomicAdd(&lt[(ry * WG + (XC)) * 2 + 1], gv.y * (WT)); \
      } else if (owner){ \
        int Ry = (Y) & ~(TRG - 1); \
        if (h < Ry - HAG || h >= Ry + TRG + HAG){ \
          unsigned slot = atomicAdd(fbcnt, 1u); \
          if (slot < FBCAP) fb[slot] = make_uint4((unsigned)(xbase + (size_t)(Y) * WG + (XC)), \
                                                  __float_as_uint(gv.x * (WT)), __float_as_uint(gv.y * (WT)), 0u); \
        } \
      } \
    }
    PROC(y0, x0, w00); PROC(y0, x1, w01); PROC(y1, x0, w10); PROC(y1, x1, w11);
    #undef PROC
    i = inx; fy = fy2; fx = fx2; gv = gv2;
  }
  __syncthreads();
  float s = stdp[0];
  const float2* gt = gtv + (size_t)pz * HW2;
  for (int i2 = tid; i2 < TRG * WG; i2 += 512){
    int yy = i2 / WG; int w = i2 - yy * WG;
    int hw = (R + yy) * WG + w;
    float2 xv = x[xbase + hw];
    float2 tv = gt[hw];
    xv.x -= GAMMA_C * lt[i2 * 2 + 0] + TAU_C * s * tv.x;
    xv.y -= GAMMA_C * lt[i2 * 2 + 1] + TAU_C * s * tv.y;
    x[xbase + hw] = xv;
  }
}

// apply rare out-of-halo contributions: x[idx] -= GAMMA * val
__global__ __launch_bounds__(256) void k_fixup(const uint4* __restrict__ fb, const unsigned int* __restrict__ fbcnt,
                                               float2* __restrict__ x){
  unsigned n = *fbcnt; if (n > FBCAP) n = FBCAP;
  for (unsigned i = blockIdx.x * 256 + threadIdx.x; i < n; i += gridDim.x * 256){
    uint4 e = fb[i];
    atomicAdd(&x[e.x].x, -GAMMA_C * __uint_as_float(e.y));
    atomicAdd(&x[e.x].y, -GAMMA_C * __uint_as_float(e.z));
  }
}

// ---------------- host ----------------
extern "C" void kernel_launch(void* const* d_in, const int* in_sizes, int n_in,
                              void* d_out, int out_size, void* d_ws, size_t ws_size,
                              hipStream_t stream) {
  const float2* kdata = (const float2*)d_in[0];
  const float*  traj  = (const float*) d_in[1];
  const float2* img0  = (const float2*)d_in[2];
  const float*  mvf   = (const float*) d_in[3];
  const float2* csm   = (const float2*)d_in[4];
  const float*  stdp  = (const float*) d_in[5];
  float2* x = (float2*)d_out;

  const size_t F_B  = (size_t)CHN * ZE * HW2 * 8;        // 39,321,600
  const size_t W_B  = (size_t)PH * ZE * HW2 * 8;         // 19,660,800
  const size_t E_B  = (size_t)PH * CHN * ZE * NKP * 8;   //  6,291,456
  const size_t FB_B = (size_t)FBCAP * 16;                //  2,097,152
  const size_t P_B  = (size_t)PH * NKP * 16;             //    262,144
  const size_t SORT_B = P_B + 4 * 8192;

  size_t need_big = 4 * F_B + 2 * W_B + E_B + 512 + FB_B + SORT_B;   // ~186 MB
  const int NP = (ws_size >= need_big) ? 4 : 1;

  char* cur = (char*)d_ws;
  float2* F      = (float2*)cur;  cur += (size_t)NP * F_B;   // fwd: transposed; bwd: normal
  float2* warped = (float2*)cur;  cur += W_B;                // also holds gwarped
  float2* est    = (float2*)cur;  cur += E_B;
  float2* gtvb   = (float2*)cur;  cur += W_B;
  unsigned int* dmax  = (unsigned int*)cur; cur += 128;
  unsigned int* fbcnt = (unsigned int*)cur; cur += 128;
  uint4* fb           = (uint4*)cur;        cur += FB_B;
  float4* permx       = (float4*)cur;       cur += P_B;
  unsigned* xhist     = (unsigned*)cur;     cur += 8192;
  unsigned* xcur      = (unsigned*)cur;     cur += 8192;
  unsigned* xbnd      = (unsigned*)cur;     cur += 8192;

  k_init<<<12800, 256, 0, stream>>>(img0, x, PH * ZT * HW2);
  // build x-sorted k-point list (traj constant across iterations)
  hipMemsetAsync(xhist, 0, 8192, stream);
  k_khist<<<64, 256, 0, stream>>>(traj, xhist);
  k_kscan<<<1, 64, 0, stream>>>(xhist, xcur, xbnd);
  k_kperm<<<64, 256, 0, stream>>>(traj, xcur, permx);

  for (int it = 0; it < 3; it++){
    k_warp_tv<<<9600, 256, 0, stream>>>(x, mvf, warped, gtvb);
    hipMemsetAsync(dmax, 0, 4, stream);
    for (int p0 = 0; p0 < PH; p0 += NP){
      k_fft_row_fwd   <<<NP * 1920, 512, 0, stream>>>(warped, csm, F, p0);
      k_fft_col_sample<<<NP * 1920, 256, 0, stream>>>(F, permx, xbnd, est, dmax, p0);
    }
    k_weights<<<3072, 256, 0, stream>>>(est, kdata, permx, dmax);
    for (int p0 = 0; p0 < PH; p0 += NP){
      k_fft_col_scatter<<<NP *  960, 256, 0, stream>>>(est, permx, xbnd, F, p0);
      k_fft_row_bwd    <<<NP * 1920, 512, 0, stream>>>(F, csm, warped, p0);
    }
    hipMemsetAsync(fbcnt, 0, 4, stream);
    k_warpadj_update<<<960, 512, 0, stream>>>(warped, mvf, gtvb, stdp, x, fb, fbcnt);
    k_fixup<<<16, 256, 0, stream>>>(fb, fbcnt, x);
  }
}

// Round 12
// 1775.125 us; speedup vs baseline: 1.8751x; 1.0112x over previous
//
#include <hip/hip_runtime.h>
#include <math.h>

// ---------------- problem constants ----------------
#define PH   4
#define CHN  8
#define ZT   8
#define ZE   6          // effective z slices: z in [1,7)
#define HG   320
#define WG   320
#define HW2  102400     // 320*320
#define NKP  4096
#define LSTR 321        // LDS line stride (pad +1)
#define FBCAP 131072u   // fallback list capacity (entries)

constexpr float GAMMA_C = 0.1f;
constexpr float TAU_C   = 0.2f;
constexpr float EPS_C   = 0.01f;
constexpr float INV_N   = 1.0f / 786432.0f;   // PH*CHN*ZE*NKP
#define TWO_PI_F 6.28318530717958647692f

// W5^j = e^{-2*pi*i*j/5}
constexpr float W5R[5] = { 1.f,  0.30901699f, -0.80901699f, -0.80901699f,  0.30901699f};
constexpr float W5I[5] = { 0.f, -0.95105652f, -0.58778525f,  0.58778525f,  0.95105652f};

// ---------------- complex helpers ----------------
__device__ __forceinline__ float2 cmul(float2 a, float2 b){
  return make_float2(a.x*b.x - a.y*b.y, a.x*b.y + a.y*b.x);
}
__device__ __forceinline__ void cmac(float2& d, float2 a, float2 b){
  d.x = fmaf(a.x, b.x, fmaf(-a.y, b.y, d.x));
  d.y = fmaf(a.x, b.y, fmaf( a.y, b.x, d.y));
}

__device__ __forceinline__ void corners(float gy, float gx, int& y0, int& x0, int& y1, int& x1,
                                        float& w00, float& w01, float& w10, float& w11){
  float y0f = floorf(gy), x0f = floorf(gx);
  float wy = gy - y0f, wx = gx - x0f;
  y0 = (int)y0f; x0 = (int)x0f;
  y1 = min(y0 + 1, HG - 1); x1 = min(x0 + 1, WG - 1);
  w00 = (1.f - wy) * (1.f - wx);
  w01 = (1.f - wy) * wx;
  w10 = wy * (1.f - wx);
  w11 = wy * wx;
}

__device__ __forceinline__ void traj_to_grid(float ty, float tx, float& gy, float& gx){
  gy = fminf(fmaxf((ty / TWO_PI_F + 0.5f) * 320.f, 0.f), 319.f);
  gx = fminf(fmaxf((tx / TWO_PI_F + 0.5f) * 320.f, 0.f), 319.f);
}

// ---------------- in-register 320-pt FFT: one wave per line, N = 5 x 64 ----------------
// (verified rounds 5-11). Lane l stores X[5*br6(l)+r]; un-permuted via LDS seg.
struct FT {
  float2 t1, t2, t3, t4;
  float2 tw0, tw1, tw2, tw3, tw4;
  int br5, lane;
};

__device__ __forceinline__ FT ft_init(){
  FT f; int l = (int)(threadIdx.x & 63); f.lane = l;
  sincosf(-TWO_PI_F * (float)l * (1.0f/320.0f), &f.t1.y, &f.t1.x);
  f.t2 = cmul(f.t1, f.t1); f.t3 = cmul(f.t2, f.t1); f.t4 = cmul(f.t2, f.t2);
  sincosf(-TWO_PI_F * (float)(l & 31) * (1.0f/64.0f), &f.tw0.y, &f.tw0.x);
  sincosf(-TWO_PI_F * (float)(l & 15) * (1.0f/32.0f), &f.tw1.y, &f.tw1.x);
  sincosf(-TWO_PI_F * (float)(l &  7) * (1.0f/16.0f), &f.tw2.y, &f.tw2.x);
  sincosf(-TWO_PI_F * (float)(l &  3) * (1.0f/ 8.0f), &f.tw3.y, &f.tw3.x);
  f.tw4 = (l & 1) ? make_float2(0.f, -1.f) : make_float2(1.f, 0.f);
  int br = ((l&1)<<5) | ((l&2)<<3) | ((l&4)<<1) | ((l&8)>>1) | ((l&16)>>3) | ((l&32)>>5);
  f.br5 = 5 * br;
  return f;
}

template<int H>
__device__ __forceinline__ void bfly(float2& v, float2 tw, int lane){
  float px = __shfl_xor(v.x, H, 64);
  float py = __shfl_xor(v.y, H, 64);
  bool up = (lane & H) != 0;
  float ax = up ? px : v.x, ay = up ? py : v.y;
  float bx = up ? v.x : px, by = up ? v.y : py;
  float dx = ax - bx,  dy = ay - by;
  float mx = fmaf(dx, tw.x, -dy * tw.y);
  float my = fmaf(dx, tw.y,  dy * tw.x);
  v.x = up ? mx : (ax + bx);
  v.y = up ? my : (ay + by);
}

__device__ __forceinline__ void fft320w(const float2 a[5], const FT& f, float2* __restrict__ seg){
  float2 z[5];
  #pragma unroll
  for (int r = 0; r < 5; r++){
    float2 acc = a[0];
    #pragma unroll
    for (int q = 1; q < 5; q++){
      const int j = (q * r) % 5;
      cmac(acc, a[q], make_float2(W5R[j], W5I[j]));
    }
    z[r] = acc;
  }
  z[1] = cmul(z[1], f.t1); z[2] = cmul(z[2], f.t2);
  z[3] = cmul(z[3], f.t3); z[4] = cmul(z[4], f.t4);
  #pragma unroll
  for (int r = 0; r < 5; r++){
    float2 v = z[r];
    bfly<32>(v, f.tw0, f.lane);
    bfly<16>(v, f.tw1, f.lane);
    bfly< 8>(v, f.tw2, f.lane);
    bfly< 4>(v, f.tw3, f.lane);
    bfly< 2>(v, f.tw4, f.lane);
    {
      float px = __shfl_xor(v.x, 1, 64);
      float py = __shfl_xor(v.y, 1, 64);
      bool up = (f.lane & 1) != 0;
      float ax = up ? px : v.x, ay = up ? py : v.y;
      float bx = up ? v.x : px, by = up ? v.y : py;
      v.x = up ? (ax - bx) : (ax + bx);
      v.y = up ? (ay - by) : (ay + by);
    }
    seg[f.br5 + r] = v;
  }
}

// ---------------- k-point x-sorting (once per call; traj constant across iterations) --------
__global__ __launch_bounds__(256) void k_khist(const float* __restrict__ traj, unsigned* __restrict__ xhist){
  int gid = blockIdx.x * 256 + threadIdx.x;
  if (gid >= PH * NKP) return;
  int p = gid >> 12, k = gid & (NKP - 1);
  float gy, gx;
  traj_to_grid(traj[(p * 2 + 0) * NKP + k], traj[(p * 2 + 1) * NKP + k], gy, gx);
  atomicAdd(&xhist[p * WG + (int)floorf(gx)], 1u);
}

__global__ void k_kscan(const unsigned* __restrict__ xhist, unsigned* __restrict__ xcur,
                        unsigned* __restrict__ xbnd){
  int p = threadIdx.x;
  if (p < PH){
    unsigned acc = 0;
    for (int b = 0; b < WG; b++){ xcur[p * WG + b] = acc; xbnd[p * (WG + 1) + b] = acc; acc += xhist[p * WG + b]; }
    xbnd[p * (WG + 1) + WG] = acc;
  }
}

__global__ __launch_bounds__(256) void k_kperm(const float* __restrict__ traj, unsigned* __restrict__ xcur,
                                               float4* __restrict__ permx){
  int gid = blockIdx.x * 256 + threadIdx.x;
  if (gid >= PH * NKP) return;
  int p = gid >> 12, k = gid & (NKP - 1);
  float gy, gx;
  traj_to_grid(traj[(p * 2 + 0) * NKP + k], traj[(p * 2 + 1) * NKP + k], gy, gx);
  unsigned sx = atomicAdd(&xcur[p * WG + (int)floorf(gx)], 1u);
  permx[p * NKP + sx] = make_float4(__uint_as_float((unsigned)k), gy, gx, 0.f);
}

// ---------------- kernels ----------------
__global__ __launch_bounds__(256) void k_init(const float2* __restrict__ img0, float2* __restrict__ x, int n){
  int i = blockIdx.x * 256 + threadIdx.x;
  if (i < n){
    float2 v = img0[i];
    v.x = isnan(v.x) ? 0.f : fminf(fmaxf(v.x, -3.4028235e38f), 3.4028235e38f);
    v.y = isnan(v.y) ? 0.f : fminf(fmaxf(v.y, -3.4028235e38f), 3.4028235e38f);
    x[i] = v;
  }
}

// fused: warped = bilinear-warp(x, mvf); gtv = conj(TV-grad(x)); also zeroes dmax/fbcnt
// (block 0 thread 0; visible to subsequent kernels via kernel-boundary ordering)
__global__ __launch_bounds__(256) void k_warp_tv(const float2* __restrict__ x, const float* __restrict__ mvf,
                                                 float2* __restrict__ warped, float2* __restrict__ gtv,
                                                 unsigned int* __restrict__ dmax, unsigned int* __restrict__ fbcnt){
  if (blockIdx.x == 0 && threadIdx.x == 0){ *dmax = 0u; *fbcnt = 0u; }
  int gid = blockIdx.x * 256 + threadIdx.x;          // over PH*ZE*HW2
  int hw = gid % HW2;
  int pz = gid / HW2;
  int zz = pz % ZE, p = pz / ZE, z = zz + 1;
  int h = hw / WG, w = hw - h * WG;
  const float* mv = mvf + ((size_t)(p * 2 + 0) * ZT + z) * HW2;
  float fy = mv[hw];
  float fx = mv[(size_t)ZT * HW2 + hw];
  float gy = fminf(fmaxf((float)h + fy, 0.f), 319.f);
  float gx = fminf(fmaxf((float)w + fx, 0.f), 319.f);
  int y0, x0, y1, x1; float w00, w01, w10, w11;
  corners(gy, gx, y0, x0, y1, x1, w00, w01, w10, w11);
  const float2* xs = x + (size_t)(p * ZT + z) * HW2;
  float2 v00 = xs[y0 * WG + x0], v01 = xs[y0 * WG + x1];
  float2 v10 = xs[y1 * WG + x0], v11 = xs[y1 * WG + x1];
  float2 o;
  o.x = v00.x * w00 + v01.x * w01 + v10.x * w10 + v11.x * w11;
  o.y = v00.y * w00 + v01.y * w01 + v10.y * w10 + v11.y * w11;
  warped[gid] = o;
  // TV gradient
  float2 xc = xs[hw];
  float tre = 0.f, tim = 0.f;
  if (h > 0){
    float2 n = xs[hw - WG];
    float dr = xc.x - n.x, di = xc.y - n.y;
    float r = sqrtf(dr * dr + di * di + 1e-8f);
    tre += dr / r; tim += di / r;
  }
  if (h < HG - 1){
    float2 n = xs[hw + WG];
    float dr = n.x - xc.x, di = n.y - xc.y;
    float r = sqrtf(dr * dr + di * di + 1e-8f);
    tre -= dr / r; tim -= di / r;
  }
  if (w > 0){
    float2 n = xs[hw - 1];
    float dr = xc.x - n.x, di = xc.y - n.y;
    float r = sqrtf(dr * dr + di * di + 1e-8f);
    tre += dr / r; tim += di / r;
  }
  if (w < WG - 1){
    float2 n = xs[hw + 1];
    float dr = n.x - xc.x, di = n.y - xc.y;
    float r = sqrtf(dr * dr + di * di + 1e-8f);
    tre -= dr / r; tim -= di / r;
  }
  gtv[gid] = make_float2(tre, -tim);
}

// row FFT forward: 8 rows of one slice per block (8 waves); output written TRANSPOSED:
// FT_[sl][w][h] (addr = sl*HW2 + w*HG + h) so the column pass reads contiguously.
__global__ __launch_bounds__(512) void k_fft_row_fwd(const float2* __restrict__ warped, const float2* __restrict__ csm,
                                                     float2* __restrict__ FT_, int p0){
  __shared__ float2 seg[8 * LSTR];
  FT f = ft_init();
  int wid = threadIdx.x >> 6, l = f.lane;
  int hg = blockIdx.x % 40; int sl = blockIdx.x / 40;      // sl = (pp*CHN + c)*ZE + zz
  int zz = sl % ZE; int s2 = sl / ZE; int c = s2 % CHN; int pp = s2 / CHN;
  int p = p0 + pp; int z = zz + 1;
  int h = hg * 8 + wid;
  const float2* wr = warped + ((size_t)(p * ZE + zz)) * HW2 + (size_t)h * WG;
  const float2* cs = csm + ((size_t)(c * ZT + z)) * HW2 + (size_t)h * WG;
  float sgn = ((h + l) & 1) ? -1.f : 1.f;
  float2 a[5];
  #pragma unroll
  for (int q = 0; q < 5; q++){
    float2 v = cmul(wr[64 * q + l], cs[64 * q + l]);
    a[q] = make_float2(v.x * sgn, v.y * sgn);
  }
  fft320w(a, f, seg + wid * LSTR);
  __syncthreads();
  float2* out = FT_ + (size_t)sl * HW2 + hg * 8;           // + w*HG later
  for (int i = threadIdx.x; i < 8 * WG; i += 512){
    int w = i >> 3; int hh = i & 7;
    out[(size_t)w * HG + hh] = seg[hh * LSTR + w];
  }
}

// fused forward: per block, 8 owned F-columns + 1 overlap; ALL column inputs loaded to
// registers first (15 independent coalesced loads in flight), then FFT'd, spectrum to LDS,
// then sample k-points with x0 in [cbase, cbase+8) from LDS. est written raw in x-sorted order.
__global__ __launch_bounds__(256) void k_fft_col_sample(const float2* __restrict__ FT_, const float4* __restrict__ permx,
                                                        const unsigned* __restrict__ xbnd, float2* __restrict__ est,
                                                        unsigned int* __restrict__ dmax, int p0){
  __shared__ float2 seg[9 * LSTR];   // 23,112 B
  FT f = ft_init();
  int tid = threadIdx.x; int wid = tid >> 6, l = f.lane;
  int cg = blockIdx.x % 40; int sl = blockIdx.x / 40;       // local slice (pp*CHN+c)*ZE+zz
  int s2 = sl / ZE; int pp = s2 / CHN;
  int p = p0 + pp;
  int cbase = cg * 8;
  const int ncol = (cbase + 8 <= WG - 1) ? 9 : 8;
  const float2* Fs = FT_ + (size_t)sl * HW2 + (size_t)cbase * HG;
  // phase 1: issue ALL loads (up to 3 cols x 5 = 15 independent coalesced loads per lane)
  float2 areg[3][5];
  #pragma unroll
  for (int cc = 0; cc < 3; cc++){
    int col = cc * 4 + wid;
    if (col < ncol){
      const float2* src = Fs + (size_t)col * HG;
      #pragma unroll
      for (int q = 0; q < 5; q++) areg[cc][q] = src[64 * q + l];
    }
  }
  // phase 2: FFTs (loads already in flight / complete)
  #pragma unroll
  for (int cc = 0; cc < 3; cc++){
    int col = cc * 4 + wid;
    if (col < ncol) fft320w(areg[cc], f, seg + col * LSTR);
  }
  __syncthreads();
  // phase 3: sample from LDS
  int lo = (int)xbnd[p * (WG + 1) + cbase];
  int hi = (int)xbnd[p * (WG + 1) + min(cbase + 8, WG)];
  float2* eb = est + ((size_t)(p0 * CHN * ZE) + sl) * NKP;
  const float4* px = permx + p * NKP;
  float md2 = 0.f;
  for (int j = lo + tid; j < hi; j += 256){
    float4 e4 = px[j];
    int y0, x0, y1, x1; float w00, w01, w10, w11;
    corners(e4.y, e4.z, y0, x0, y1, x1, w00, w01, w10, w11);
    int lc0 = x0 - cbase, lc1 = x1 - cbase;
    float2 v00 = seg[lc0 * LSTR + y0], v01 = seg[lc1 * LSTR + y0];
    float2 v10 = seg[lc0 * LSTR + y1], v11 = seg[lc1 * LSTR + y1];
    float2 e;
    e.x = v00.x * w00 + v01.x * w01 + v10.x * w10 + v11.x * w11;
    e.y = v00.y * w00 + v01.y * w01 + v10.y * w10 + v11.y * w11;
    eb[j] = e;
    md2 = fmaxf(md2, e.x * e.x + e.y * e.y);
  }
  for (int off = 32; off > 0; off >>= 1) md2 = fmaxf(md2, __shfl_down(md2, off, 64));
  if ((tid & 63) == 0 && md2 > 0.f) atomicMax(dmax, __float_as_uint(md2));
}

// backward: fused { weights (est->G on the fly) + zero tile + x-bucketed corner scatter
// (LDS atomics) + per-wave column DFT^T }. F written in NORMAL layout (row_bwd reads rows).
// G = (w^2/N) * conj(est - y) computed in-register: est raw, kdata gathered via permx, dmax final.
__global__ __launch_bounds__(256) void k_fft_col_scatter(const float2* __restrict__ est, const float2* __restrict__ kdata,
                                                         const float4* __restrict__ permx,
                                                         const unsigned* __restrict__ xbnd,
                                                         const unsigned int* __restrict__ dmax,
                                                         float2* __restrict__ F, int p0){
  __shared__ float2 ld[16 * LSTR];
  FT f = ft_init();
  int tid = threadIdx.x; int wid = tid >> 6, l = f.lane;
  int cg = blockIdx.x % 20; int sl = blockIdx.x / 20;       // local slice
  int zz = sl % ZE; int s2 = sl / ZE; int c = s2 % CHN; int pp = s2 / CHN;
  int p = p0 + pp; int z = zz + 1;
  for (int i = tid; i < 16 * LSTR; i += 256) ld[i] = make_float2(0.f, 0.f);
  __syncthreads();
  float md = sqrtf(__uint_as_float(*dmax));
  int cbase = cg * 16;
  int lo = (cbase > 0) ? (int)xbnd[p * (WG + 1) + cbase - 1] : 0;
  int hi = (int)xbnd[p * (WG + 1) + min(cbase + 16, WG)];
  const float2* Es = est + ((size_t)(p0 * CHN * ZE) + sl) * NKP;
  const float2* kd = kdata + ((size_t)(p * CHN + c) * ZT + z) * NKP;
  const float4* px = permx + p * NKP;
  for (int j = lo + tid; j < hi; j += 256){
    float4 e4 = px[j];
    int k = (int)__float_as_uint(e4.x);
    int y0, x0, y1, x1; float w00, w01, w10, w11;
    corners(e4.y, e4.z, y0, x0, y1, x1, w00, w01, w10, w11);
    float2 e = Es[j];
    float det = sqrtf(e.x * e.x + e.y * e.y);
    float wv = 1.0f / (det / md + EPS_C);
    float sc = wv * wv * INV_N;
    float2 y = kd[k];
    float2 gv = make_float2(sc * (e.x - y.x), -sc * (e.y - y.y));
    int c0 = x0 - cbase, c1 = x1 - cbase;
    if ((unsigned)c0 < 16u){
      atomicAdd(&ld[c0 * LSTR + y0].x, gv.x * w00); atomicAdd(&ld[c0 * LSTR + y0].y, gv.y * w00);
      atomicAdd(&ld[c0 * LSTR + y1].x, gv.x * w10); atomicAdd(&ld[c0 * LSTR + y1].y, gv.y * w10);
    }
    if ((unsigned)c1 < 16u){
      atomicAdd(&ld[c1 * LSTR + y0].x, gv.x * w01); atomicAdd(&ld[c1 * LSTR + y0].y, gv.y * w01);
      atomicAdd(&ld[c1 * LSTR + y1].x, gv.x * w11); atomicAdd(&ld[c1 * LSTR + y1].y, gv.y * w11);
    }
  }
  __syncthreads();
  #pragma unroll
  for (int cc = 0; cc < 4; cc++){
    float2* base = ld + (wid * 4 + cc) * LSTR;
    float2 a[5];
    #pragma unroll
    for (int q = 0; q < 5; q++) a[q] = base[64 * q + l];
    fft320w(a, f, base);
  }
  __syncthreads();
  float2* Fs = F + (size_t)sl * HW2 + cbase;
  for (int i = tid; i < 5120; i += 256){ int h = i >> 4, col = i & 15; Fs[h * WG + col] = ld[col * LSTR + h]; }
}

// transpose row pass: 8 waves = 8 coils of one (pp,zz,h) row; epilogue *(-1)^(h+w), *csm, coil sum
__global__ __launch_bounds__(512) void k_fft_row_bwd(const float2* __restrict__ F, const float2* __restrict__ csm,
                                                     float2* __restrict__ gwarped, int p0){
  __shared__ float2 seg[8 * LSTR];
  FT f = ft_init();
  int tid = threadIdx.x; int c = tid >> 6, l = f.lane;
  int bid = blockIdx.x;                          // over np*ZE*HG
  int h = bid % HG; int b2 = bid / HG;
  int zz = b2 % ZE; int pp = b2 / ZE;
  int p = p0 + pp; int z = zz + 1;
  const float2* Fl = F + ((size_t)((pp * CHN + c) * ZE + zz)) * HW2 + (size_t)h * WG;
  float2 a[5];
  #pragma unroll
  for (int q = 0; q < 5; q++) a[q] = Fl[64 * q + l];
  fft320w(a, f, seg + c * LSTR);
  __syncthreads();
  if (tid < WG){
    int w = tid;
    float2 acc = make_float2(0.f, 0.f);
    #pragma unroll
    for (int cc = 0; cc < 8; cc++){
      cmac(acc, seg[cc * LSTR + w], csm[((size_t)(cc * ZT + z)) * HW2 + (size_t)h * WG + w]);
    }
    float sg = ((h + w) & 1) ? -1.f : 1.f;
    gwarped[((size_t)(p * ZE + zz)) * HW2 + (size_t)h * WG + w] = make_float2(acc.x * sg, acc.y * sg);
  }
}

// ---------------- gather-tiled warp adjoint + fused gradient update ----------------
#define TRG 8
#define HAG 8
__global__ __launch_bounds__(512) void k_warpadj_update(const float2* __restrict__ gw, const float* __restrict__ mvf,
                                                        const float2* __restrict__ gtv, const float* __restrict__ stdp,
                                                        float2* __restrict__ x,
                                                        uint4* __restrict__ fb, unsigned int* __restrict__ fbcnt){
  __shared__ float lt[TRG * WG * 2];   // 20480 B
  int tid = threadIdx.x;
  int bid = blockIdx.x;                    // pz*40 + tile
  int tile = bid % 40; int pz = bid / 40;
  int zz = pz % ZE, p = pz / ZE, z = zz + 1;
  int R = tile * TRG;
  for (int i = tid; i < TRG * WG * 2; i += 512) lt[i] = 0.f;
  __syncthreads();
  const float* mvy = mvf + ((size_t)(p * 2 + 0) * ZT + z) * HW2;
  const float* mvx = mvy + (size_t)ZT * HW2;
  const float2* g = gw + (size_t)pz * HW2;
  const size_t xbase = (size_t)(p * ZT + z) * HW2;
  int wlo = max(R - HAG, 0), whi = min(R + TRG + HAG, HG);
  int npx = (whi - wlo) * WG;
  int base0 = wlo * WG;
  int i = tid;
  float fy = 0.f, fx = 0.f; float2 gv = make_float2(0.f, 0.f);
  if (i < npx){ fy = mvy[base0 + i]; fx = mvx[base0 + i]; gv = g[base0 + i]; }
  while (i < npx){
    int inx = i + 512;
    float fy2 = 0.f, fx2 = 0.f; float2 gv2 = make_float2(0.f, 0.f);
    if (inx < npx){ fy2 = mvy[base0 + inx]; fx2 = mvx[base0 + inx]; gv2 = g[base0 + inx]; }
    int hh = i / WG; int w = i - hh * WG;
    int h = wlo + hh;
    float gy = fminf(fmaxf((float)h + fy, 0.f), 319.f);
    float gx = fminf(fmaxf((float)w + fx, 0.f), 319.f);
    int y0, x0, y1, x1; float w00, w01, w10, w11;
    corners(gy, gx, y0, x0, y1, x1, w00, w01, w10, w11);
    bool owner = (h >= R) && (h < R + TRG);
    #define PROC(Y, XC, WT) { \
      int ry = (Y) - R; \
      if ((unsigned)ry < (unsigned)TRG){ \
        atomicAdd(&lt[(ry * WG + (XC)) * 2 + 0], gv.x * (WT)); \
        atomicAdd(&lt[(ry * WG + (XC)) * 2 + 1], gv.y * (WT)); \
      } else if (owner){ \
        int Ry = (Y) & ~(TRG - 1); \
        if (h < Ry - HAG || h >= Ry + TRG + HAG){ \
          unsigned slot = atomicAdd(fbcnt, 1u); \
          if (slot < FBCAP) fb[slot] = make_uint4((unsigned)(xbase + (size_t)(Y) * WG + (XC)), \
                                                  __float_as_uint(gv.x * (WT)), __float_as_uint(gv.y * (WT)), 0u); \
        } \
      } \
    }
    PROC(y0, x0, w00); PROC(y0, x1, w01); PROC(y1, x0, w10); PROC(y1, x1, w11);
    #undef PROC
    i = inx; fy = fy2; fx = fx2; gv = gv2;
  }
  __syncthreads();
  float s = stdp[0];
  const float2* gt = gtv + (size_t)pz * HW2;
  for (int i2 = tid; i2 < TRG * WG; i2 += 512){
    int yy = i2 / WG; int w = i2 - yy * WG;
    int hw = (R + yy) * WG + w;
    float2 xv = x[xbase + hw];
    float2 tv = gt[hw];
    xv.x -= GAMMA_C * lt[i2 * 2 + 0] + TAU_C * s * tv.x;
    xv.y -= GAMMA_C * lt[i2 * 2 + 1] + TAU_C * s * tv.y;
    x[xbase + hw] = xv;
  }
}

// apply rare out-of-halo contributions: x[idx] -= GAMMA * val
__global__ __launch_bounds__(256) void k_fixup(const uint4* __restrict__ fb, const unsigned int* __restrict__ fbcnt,
                                               float2* __restrict__ x){
  unsigned n = *fbcnt; if (n > FBCAP) n = FBCAP;
  for (unsigned i = blockIdx.x * 256 + threadIdx.x; i < n; i += gridDim.x * 256){
    uint4 e = fb[i];
    atomicAdd(&x[e.x].x, -GAMMA_C * __uint_as_float(e.y));
    atomicAdd(&x[e.x].y, -GAMMA_C * __uint_as_float(e.z));
  }
}

// ---------------- host ----------------
extern "C" void kernel_launch(void* const* d_in, const int* in_sizes, int n_in,
                              void* d_out, int out_size, void* d_ws, size_t ws_size,
                              hipStream_t stream) {
  const float2* kdata = (const float2*)d_in[0];
  const float*  traj  = (const float*) d_in[1];
  const float2* img0  = (const float2*)d_in[2];
  const float*  mvf   = (const float*) d_in[3];
  const float2* csm   = (const float2*)d_in[4];
  const float*  stdp  = (const float*) d_in[5];
  float2* x = (float2*)d_out;

  const size_t F_B  = (size_t)CHN * ZE * HW2 * 8;        // 39,321,600
  const size_t W_B  = (size_t)PH * ZE * HW2 * 8;         // 19,660,800
  const size_t E_B  = (size_t)PH * CHN * ZE * NKP * 8;   //  6,291,456
  const size_t FB_B = (size_t)FBCAP * 16;                //  2,097,152
  const size_t P_B  = (size_t)PH * NKP * 16;             //    262,144
  const size_t SORT_B = P_B + 4 * 8192;

  size_t need_big = 4 * F_B + 2 * W_B + E_B + 512 + FB_B + SORT_B;   // ~186 MB
  const int NP = (ws_size >= need_big) ? 4 : 1;

  char* cur = (char*)d_ws;
  float2* F      = (float2*)cur;  cur += (size_t)NP * F_B;   // fwd: transposed; bwd: normal
  float2* warped = (float2*)cur;  cur += W_B;                // also holds gwarped
  float2* est    = (float2*)cur;  cur += E_B;
  float2* gtvb   = (float2*)cur;  cur += W_B;
  unsigned int* dmax  = (unsigned int*)cur; cur += 128;
  unsigned int* fbcnt = (unsigned int*)cur; cur += 128;
  uint4* fb           = (uint4*)cur;        cur += FB_B;
  float4* permx       = (float4*)cur;       cur += P_B;
  unsigned* xhist     = (unsigned*)cur;     cur += 8192;
  unsigned* xcur      = (unsigned*)cur;     cur += 8192;
  unsigned* xbnd      = (unsigned*)cur;     cur += 8192;

  k_init<<<12800, 256, 0, stream>>>(img0, x, PH * ZT * HW2);
  // build x-sorted k-point list (traj constant across iterations)
  hipMemsetAsync(xhist, 0, 8192, stream);
  k_khist<<<64, 256, 0, stream>>>(traj, xhist);
  k_kscan<<<1, 64, 0, stream>>>(xhist, xcur, xbnd);
  k_kperm<<<64, 256, 0, stream>>>(traj, xcur, permx);

  for (int it = 0; it < 3; it++){
    k_warp_tv<<<9600, 256, 0, stream>>>(x, mvf, warped, gtvb, dmax, fbcnt);
    for (int p0 = 0; p0 < PH; p0 += NP){
      k_fft_row_fwd   <<<NP * 1920, 512, 0, stream>>>(warped, csm, F, p0);
      k_fft_col_sample<<<NP * 1920, 256, 0, stream>>>(F, permx, xbnd, est, dmax, p0);
    }
    for (int p0 = 0; p0 < PH; p0 += NP){
      k_fft_col_scatter<<<NP *  960, 256, 0, stream>>>(est, kdata, permx, xbnd, dmax, F, p0);
      k_fft_row_bwd    <<<NP * 1920, 512, 0, stream>>>(F, csm, warped, p0);
    }
    k_warpadj_update<<<960, 512, 0, stream>>>(warped, mvf, gtvb, stdp, x, fb, fbcnt);
    k_fixup<<<16, 256, 0, stream>>>(fb, fbcnt, x);
  }
}